// Round 6
// baseline (909.388 us; speedup 1.0000x reference)
//
#include <hip/hip_runtime.h>
#include <hip/hip_bf16.h>
#include <math.h>

#define L_SEQ   2048
#define BATCH   2
#define DMODEL  2048
#define DINNER  4096
#define DSTATE  16
#define DTRANK  128
#define NTOK    (L_SEQ * BATCH)   // 4096
#define CHUNK   128
#define NCHUNK  (L_SEQ / CHUNK)   // 16

typedef __attribute__((ext_vector_type(8))) __bf16 bf16x8;
typedef __attribute__((ext_vector_type(4))) float f32x4;

__device__ __forceinline__ __bf16 f2bf(float f) {
    unsigned u = __builtin_bit_cast(unsigned, f);
    unsigned r = (u + 0x7FFFu + ((u >> 16) & 1u)) >> 16;
    return __builtin_bit_cast(__bf16, (unsigned short)r);
}

__device__ __forceinline__ void load_lds16(const void* gsrc, void* lds) {
    __builtin_amdgcn_global_load_lds(
        (const __attribute__((address_space(1))) unsigned int*)gsrc,
        (__attribute__((address_space(3))) unsigned int*)lds, 16, 0, 0);
}

// Stage one 128x64 bf16 half-tile (16 KiB) with 512 threads x 2 loads.
// LDS dest LINEAR; SOURCE column inverse-swizzled (rule 21: both-sides).
__device__ __forceinline__ void stage_half(const __bf16* g, int ld,
                                           __bf16* lh, int trow, int tcol8, int scol)
{
    load_lds16(g + (size_t)trow        * ld + scol, lh +  trow       * 64 + tcol8);
    load_lds16(g + (size_t)(trow + 64) * ld + scol, lh + (trow + 64) * 64 + tcol8);
}

// ---------------------------------------------------------------------------
// 256x256 bf16 MFMA GEMM, merged 2-phase dataflow.
// C[m][n] = sum_k A[m][k]*Bt[n][k].  512 thr = 8 waves (2M x 4N), wave owns
// 128x64 of C.  BK=64.  Per K-tile: phase0 {read B(8)+A-half0(8), stage Bh0,
// 32 MFMA}, phase1 {read A-half1(8), stage Bh1, 32 MFMA}, boundary {stage
// A(tt+2), vmcnt(4)}.  B-fragments held in registers across the K-tile.
// LDS: 2 x {A-h0,A-h1,B-h0,B-h1} x 16KiB = 128 KiB.
// Optional split-K: grid = ntile * nslice, Kper = K/nslice.
// MODE 0: m<DINNER -> C0 fp32; else C1b bf16 (ldc=DINNER)   [in_proj]
// MODE 1: plain store C0[n*ldc+m]                           [unused fallback]
// MODE 2: atomicAdd into C0[n*ldc+m] (C0 pre-zeroed)        [out_proj splitK]
// ---------------------------------------------------------------------------
template <int MODE>
__global__ __launch_bounds__(512, 1)
void gemm8(const __bf16* __restrict__ A, const __bf16* __restrict__ Bt,
           float* __restrict__ C0, __bf16* __restrict__ C1b,
           int Kper, int lda, int ldb, int ldc, int nbn, int ntile)
{
    __shared__ __align__(16) __bf16 lds8[2 * 4 * 8192];   // 128 KiB

    const int t = threadIdx.x;
    const int nwg = gridDim.x;                       // multiple of 8
    const int swz = ((int)blockIdx.x & 7) * (nwg >> 3) + ((int)blockIdx.x >> 3);
    const int kslice = swz / ntile;
    const int tl     = swz - kslice * ntile;
    const int m0 = (tl / nbn) * 256;
    const int n0 = (tl % nbn) * 256;
    const int kofs = kslice * Kper;

    const int l      = t & 63;
    const int w      = t >> 6;
    const int wm     = w >> 2;        // 0..1
    const int wn     = w & 3;         // 0..3
    const int lane15 = l & 15;
    const int lhi    = l >> 4;        // 0..3
    const int trow   = t >> 3;        // 0..63
    const int tcol8  = (t & 7) * 8;
    const int scol   = tcol8 ^ ((trow & 7) << 3);

    const __bf16* Ah0 = A  + (size_t)m0 * lda + kofs;
    const __bf16* Ah1 = A  + (size_t)(m0 + 128) * lda + kofs;
    const __bf16* Bh0 = Bt + (size_t)n0 * ldb + kofs;
    const __bf16* Bh1 = Bt + (size_t)(n0 + 128) * ldb + kofs;

    const int NT = Kper >> 6;

    f32x4 acc[8][4];
#pragma unroll
    for (int i = 0; i < 8; ++i)
#pragma unroll
        for (int j = 0; j < 4; ++j) acc[i][j] = (f32x4){0.f, 0.f, 0.f, 0.f};

    // ---- prologue: tile0 all 4 halves (8 ops), tile1 A-halves (4 ops)
    stage_half(Ah0,      lda, lds8 + 0 * 8192, trow, tcol8, scol);
    stage_half(Ah1,      lda, lds8 + 1 * 8192, trow, tcol8, scol);
    stage_half(Bh0,      ldb, lds8 + 2 * 8192, trow, tcol8, scol);
    stage_half(Bh1,      ldb, lds8 + 3 * 8192, trow, tcol8, scol);
    stage_half(Ah0 + 64, lda, lds8 + 4 * 8192, trow, tcol8, scol);
    stage_half(Ah1 + 64, lda, lds8 + 5 * 8192, trow, tcol8, scol);
    asm volatile("s_waitcnt vmcnt(4)" ::: "memory");
    __builtin_amdgcn_s_barrier();

    for (int tt = 0; tt < NT; ++tt) {
        const int cur = tt & 1;
        const __bf16* LA = lds8 + (cur * 4 + wm) * 8192;           // wave's 128 rows
        const __bf16* LB = lds8 + (cur * 4 + 2 + (wn >> 1)) * 8192;
        __bf16* nxt = lds8 + ((1 - cur) * 4) * 8192;
        const bool stg = (tt + 1 < NT);
        const int  knx = (tt + 1) << 6;

        // ---------- phase 0: B fragments (held for both phases) + A-half0
        bf16x8 b0[4], b1[4], a0[4], a1[4];
#pragma unroll
        for (int j = 0; j < 4; ++j) {
            const int lr = (wn & 1) * 64 + j * 16 + lane15;
            const int sw = (lr & 7) << 3;
            b0[j] = *(const bf16x8*)&LB[lr * 64 + ((lhi * 8) ^ sw)];
            b1[j] = *(const bf16x8*)&LB[lr * 64 + (((32 + lhi * 8)) ^ sw)];
        }
#pragma unroll
        for (int i = 0; i < 4; ++i) {
            const int lr = i * 16 + lane15;
            const int sw = (lr & 7) << 3;
            a0[i] = *(const bf16x8*)&LA[lr * 64 + ((lhi * 8) ^ sw)];
            a1[i] = *(const bf16x8*)&LA[lr * 64 + (((32 + lhi * 8)) ^ sw)];
        }
        if (stg) stage_half(Bh0 + knx, ldb, nxt + 2 * 8192, trow, tcol8, scol);

        __builtin_amdgcn_s_setprio(1);
#pragma unroll
        for (int i = 0; i < 4; ++i)
#pragma unroll
            for (int j = 0; j < 4; ++j) {
                acc[i][j] = __builtin_amdgcn_mfma_f32_16x16x32_bf16(
                    a0[i], b0[j], acc[i][j], 0, 0, 0);
                acc[i][j] = __builtin_amdgcn_mfma_f32_16x16x32_bf16(
                    a1[i], b1[j], acc[i][j], 0, 0, 0);
            }
        __builtin_amdgcn_s_setprio(0);
        __builtin_amdgcn_s_barrier();

        // ---------- phase 1: A-half1, reuse B fragments
#pragma unroll
        for (int i = 0; i < 4; ++i) {
            const int lr = 64 + i * 16 + lane15;
            const int sw = (lr & 7) << 3;
            a0[i] = *(const bf16x8*)&LA[lr * 64 + ((lhi * 8) ^ sw)];
            a1[i] = *(const bf16x8*)&LA[lr * 64 + (((32 + lhi * 8)) ^ sw)];
        }
        if (stg) stage_half(Bh1 + knx, ldb, nxt + 3 * 8192, trow, tcol8, scol);

        __builtin_amdgcn_s_setprio(1);
#pragma unroll
        for (int i = 0; i < 4; ++i)
#pragma unroll
            for (int j = 0; j < 4; ++j) {
                acc[4 + i][j] = __builtin_amdgcn_mfma_f32_16x16x32_bf16(
                    a0[i], b0[j], acc[4 + i][j], 0, 0, 0);
                acc[4 + i][j] = __builtin_amdgcn_mfma_f32_16x16x32_bf16(
                    a1[i], b1[j], acc[4 + i][j], 0, 0, 0);
            }
        __builtin_amdgcn_s_setprio(0);
        __builtin_amdgcn_s_barrier();

        // ---------- boundary into tile tt+1
        if (tt + 1 < NT) {
            if (tt + 2 < NT) {
                const int k2 = (tt + 2) << 6;
                __bf16* nn = lds8 + (cur * 4) * 8192;
                stage_half(Ah0 + k2, lda, nn + 0 * 8192, trow, tcol8, scol);
                stage_half(Ah1 + k2, lda, nn + 1 * 8192, trow, tcol8, scol);
                asm volatile("s_waitcnt vmcnt(4)" ::: "memory");
            } else {
                asm volatile("s_waitcnt vmcnt(0)" ::: "memory");
            }
            __builtin_amdgcn_s_barrier();
        }
    }

    // ---- epilogue
    const int rbase = lhi * 4;
#pragma unroll
    for (int fi = 0; fi < 8; ++fi) {
#pragma unroll
        for (int fj = 0; fj < 4; ++fj) {
#pragma unroll
            for (int r = 0; r < 4; ++r) {
                const int m = m0 + wm * 128 + fi * 16 + rbase + r;
                const int n = n0 + wn * 64 + fj * 16 + lane15;
                const float v = acc[fi][fj][r];
                if constexpr (MODE == 0) {
                    if (m < DINNER) C0[(size_t)n * DINNER + m] = v;
                    else            C1b[(size_t)n * DINNER + (m - DINNER)] = f2bf(v);
                } else if constexpr (MODE == 1) {
                    C0[(size_t)n * ldc + m] = v;
                } else {
                    atomicAdd(&C0[(size_t)n * ldc + m], v);
                }
            }
        }
    }
}

// ---------------------------------------------------------------------------
// m97-style 128x128 bf16 MFMA GEMM (small GEMMs: x_proj, dt_proj).
// MODE 2: softplus(v + bias[m]) -> C0[n*ldc+m] fp32          [dt_proj]
// MODE 3: m<128 -> C1b bf16 [n*128+m]; 128<=m<160 -> C0 fp32 [n*32+m-128]
// ---------------------------------------------------------------------------
template <int MODE>
__global__ __launch_bounds__(256)
void gemm_bf16(const __bf16* __restrict__ A, const __bf16* __restrict__ Bt,
               float* __restrict__ C0, __bf16* __restrict__ C1b,
               const float* __restrict__ bias,
               int Mvalid, int K, int lda, int ldb, int ldc)
{
    __shared__ __align__(16) __bf16 As[128 * 64];
    __shared__ __align__(16) __bf16 Bs[128 * 64];

    const int t  = threadIdx.x;
    const int m0 = blockIdx.y * 128;
    const int n0 = blockIdx.x * 128;
    const int l  = t & 63;
    const int w  = t >> 6;
    const int wr = (w >> 1) * 64;
    const int wc = (w & 1) * 64;
    const int lrow = t >> 3;
    const int lk   = (t & 7) * 8;

    f32x4 acc[4][4];
#pragma unroll
    for (int i = 0; i < 4; ++i)
#pragma unroll
        for (int j = 0; j < 4; ++j) acc[i][j] = (f32x4){0.f, 0.f, 0.f, 0.f};

    for (int k0 = 0; k0 < K; k0 += 64) {
#pragma unroll
        for (int q = 0; q < 4; ++q) {
            const int row = q * 32 + lrow;
            load_lds16(A  + (size_t)(m0 + row) * lda + k0 + lk, &As[row * 64 + lk]);
            load_lds16(Bt + (size_t)(n0 + row) * ldb + k0 + lk, &Bs[row * 64 + lk]);
        }
        __syncthreads();

#pragma unroll
        for (int kk = 0; kk < 2; ++kk) {
            const int krd = kk * 32 + (l >> 4) * 8;
            bf16x8 a[4], b[4];
#pragma unroll
            for (int i = 0; i < 4; ++i) {
                a[i] = *(const bf16x8*)&As[(wr + i * 16 + (l & 15)) * 64 + krd];
                b[i] = *(const bf16x8*)&Bs[(wc + i * 16 + (l & 15)) * 64 + krd];
            }
#pragma unroll
            for (int i = 0; i < 4; ++i)
#pragma unroll
                for (int j = 0; j < 4; ++j)
                    acc[i][j] = __builtin_amdgcn_mfma_f32_16x16x32_bf16(
                        a[i], b[j], acc[i][j], 0, 0, 0);
        }
        __syncthreads();
    }

    const int rbase = (l >> 4) * 4;
    const int cbase = l & 15;
#pragma unroll
    for (int i = 0; i < 4; ++i) {
#pragma unroll
        for (int j = 0; j < 4; ++j) {
#pragma unroll
            for (int r = 0; r < 4; ++r) {
                const int m = m0 + wr + i * 16 + rbase + r;
                const int n = n0 + wc + j * 16 + cbase;
                const float v = acc[i][j][r];
                if constexpr (MODE == 2) {
                    const float vb = v + bias[m];
                    const float sp = (vb > 20.f) ? vb : log1pf(__expf(vb));
                    C0[(size_t)n * ldc + m] = sp;
                } else {   // MODE 3
                    if (m < 128)      C1b[(size_t)n * 128 + m] = f2bf(v);
                    else if (m < 160) C0[(size_t)n * 32 + (m - 128)] = v;
                }
            }
        }
    }
}

// ---------------------------------------------------------------------------
__global__ __launch_bounds__(256)
void cvt_bf16(const float* __restrict__ in, __bf16* __restrict__ out, int n8)
{
    const int i = blockIdx.x * 256 + threadIdx.x;
    if (i >= n8) return;
    const size_t base = (size_t)i * 8;
    const float4 a = *(const float4*)&in[base];
    const float4 b = *(const float4*)&in[base + 4];
    __align__(16) __bf16 o[8];
    o[0] = f2bf(a.x); o[1] = f2bf(a.y); o[2] = f2bf(a.z); o[3] = f2bf(a.w);
    o[4] = f2bf(b.x); o[5] = f2bf(b.y); o[6] = f2bf(b.z); o[7] = f2bf(b.w);
    *(bf16x8*)&out[base] = *(const bf16x8*)o;
}

__global__ __launch_bounds__(256)
void cvt_xproj(const float* __restrict__ in, __bf16* __restrict__ out)
{
    const int i = blockIdx.x * 256 + threadIdx.x;
    const size_t base = (size_t)i * 8;
    const int row = (int)(base >> 12);
    __align__(16) __bf16 o[8];
    if (row < 160) {
        const float4 a = *(const float4*)&in[base];
        const float4 b = *(const float4*)&in[base + 4];
        o[0] = f2bf(a.x); o[1] = f2bf(a.y); o[2] = f2bf(a.z); o[3] = f2bf(a.w);
        o[4] = f2bf(b.x); o[5] = f2bf(b.y); o[6] = f2bf(b.z); o[7] = f2bf(b.w);
    } else {
#pragma unroll
        for (int k = 0; k < 8; ++k) o[k] = f2bf(0.f);
    }
    *(bf16x8*)&out[base] = *(const bf16x8*)o;
}

// ---------------------------------------------------------------------------
__global__ __launch_bounds__(256)
void conv_silu(const float* __restrict__ x, const float* __restrict__ conv_w,
               __bf16* __restrict__ xact_bf)
{
    const size_t idx = (size_t)blockIdx.x * 256 + threadIdx.x;
    const int e = (int)(idx & (DINNER - 1));
    const int n = (int)(idx >> 12);

    const float4 w = *(const float4*)&conv_w[e * 4];
    float s = w.w * x[idx];
    if (n >= 2) s += w.z * x[idx - (size_t)2 * DINNER];
    if (n >= 4) s += w.y * x[idx - (size_t)4 * DINNER];
    if (n >= 6) s += w.x * x[idx - (size_t)6 * DINNER];
    const float v = s / (1.f + __expf(-s));
    xact_bf[idx] = f2bf(v);
}

// ---------------------------------------------------------------------------
// Chunked selective scan (unchanged from R5).
// ---------------------------------------------------------------------------
__global__ __launch_bounds__(256)
void scan_partial(const float* __restrict__ delta, const __bf16* __restrict__ u,
                  const float* __restrict__ xbc, const float* __restrict__ A_log,
                  float2* __restrict__ PS)
{
    const int e     = blockIdx.x * 256 + threadIdx.x;
    const int chunk = blockIdx.y;
    const int b     = blockIdx.z;

    __shared__ float BC[CHUNK][32];
    for (int i = threadIdx.x; i < CHUNK * 32; i += 256) {
        const int ll = i >> 5, f = i & 31;
        BC[ll][f] = xbc[(size_t)((chunk * CHUNK + ll) * BATCH + b) * 32 + f];
    }

    float Av[16];
#pragma unroll
    for (int s = 0; s < 16; s += 4) {
        float4 tv = *(const float4*)&A_log[e * 16 + s];
        Av[s] = -__expf(tv.x); Av[s + 1] = -__expf(tv.y);
        Av[s + 2] = -__expf(tv.z); Av[s + 3] = -__expf(tv.w);
    }
    __syncthreads();

    float P[16], S[16];
#pragma unroll
    for (int s = 0; s < 16; ++s) { P[s] = 1.f; S[s] = 0.f; }

#pragma unroll 4
    for (int ll = 0; ll < CHUNK; ++ll) {
        const int tok = (chunk * CHUNK + ll) * BATCH + b;
        const size_t ce = (size_t)tok * DINNER + e;
        const float dl = delta[ce];
        const float du = dl * (float)u[ce];
#pragma unroll
        for (int s = 0; s < 16; ++s) {
            const float dA = __expf(dl * Av[s]);
            S[s] = fmaf(dA, S[s], du * BC[ll][s]);
            P[s] *= dA;
        }
    }

    float2* outp = PS + ((size_t)(chunk * BATCH + b) * DINNER + e) * 16;
#pragma unroll
    for (int s = 0; s < 16; ++s) outp[s] = make_float2(P[s], S[s]);
}

__global__ __launch_bounds__(256)
void scan_combine(const float2* __restrict__ PS, float* __restrict__ Hinit)
{
    const size_t pos = (size_t)blockIdx.x * 256 + threadIdx.x;
    const size_t stride = (size_t)BATCH * DINNER * 16;
    float h = 0.f;
#pragma unroll
    for (int c = 0; c < NCHUNK; ++c) {
        Hinit[c * stride + pos] = h;
        const float2 ps = PS[c * stride + pos];
        h = fmaf(ps.x, h, ps.y);
    }
}

__global__ __launch_bounds__(256)
void scan_final(const float* __restrict__ delta, const __bf16* __restrict__ u,
                const float* __restrict__ xbc, const float* __restrict__ Hinit,
                const __bf16* __restrict__ z_bf, __bf16* __restrict__ y_bf,
                const float* __restrict__ A_log, const float* __restrict__ Dvec)
{
    const int e     = blockIdx.x * 256 + threadIdx.x;
    const int chunk = blockIdx.y;
    const int b     = blockIdx.z;

    __shared__ float BC[CHUNK][32];
    for (int i = threadIdx.x; i < CHUNK * 32; i += 256) {
        const int ll = i >> 5, f = i & 31;
        BC[ll][f] = xbc[(size_t)((chunk * CHUNK + ll) * BATCH + b) * 32 + f];
    }

    float Av[16];
#pragma unroll
    for (int s = 0; s < 16; s += 4) {
        float4 tv = *(const float4*)&A_log[e * 16 + s];
        Av[s] = -__expf(tv.x); Av[s + 1] = -__expf(tv.y);
        Av[s + 2] = -__expf(tv.z); Av[s + 3] = -__expf(tv.w);
    }
    const float Dv = Dvec[e];

    float h[16];
    const float* hi = Hinit + (size_t)chunk * BATCH * DINNER * 16
                            + ((size_t)b * DINNER + e) * 16;
#pragma unroll
    for (int s = 0; s < 16; s += 4) *(float4*)&h[s] = *(const float4*)&hi[s];
    __syncthreads();

#pragma unroll 2
    for (int ll = 0; ll < CHUNK; ++ll) {
        const int tok = (chunk * CHUNK + ll) * BATCH + b;
        const size_t ce = (size_t)tok * DINNER + e;
        const float dl = delta[ce];
        const float ul = (float)u[ce];
        const float du = dl * ul;
        float y = 0.f;
#pragma unroll
        for (int s = 0; s < 16; ++s) {
            const float dA = __expf(dl * Av[s]);
            h[s] = fmaf(dA, h[s], du * BC[ll][s]);
            y = fmaf(h[s], BC[ll][16 + s], y);
        }
        const float zl = (float)z_bf[ce];
        const float sig = 1.f / (1.f + __expf(-zl));
        y_bf[ce] = f2bf((y + ul * Dv) * (zl * sig));
    }
}

// ---------------------------------------------------------------------------
extern "C" void kernel_launch(void* const* d_in, const int* in_sizes, int n_in,
                              void* d_out, int out_size, void* d_ws, size_t ws_size,
                              hipStream_t stream)
{
    const float* hidden    = (const float*)d_in[0];
    const float* in_proj_w = (const float*)d_in[1];
    const float* conv_w    = (const float*)d_in[2];
    const float* x_proj_w  = (const float*)d_in[3];
    const float* dt_proj_w = (const float*)d_in[4];
    const float* dt_proj_b = (const float*)d_in[5];
    const float* A_log     = (const float*)d_in[6];
    const float* Dvec      = (const float*)d_in[7];
    const float* out_proj_w= (const float*)d_in[8];
    float* out = (float*)d_out;

    // -------- workspace (identical layout/total to R5's passing run)
    char* p = (char*)d_ws;
    const size_t NBIG = (size_t)NTOK * DINNER;
    float*  xbuf    = (float*)p;    p += NBIG * 4;                        // x -> delta
    __bf16* z_bf    = (__bf16*)p;   p += NBIG * 2;                        // z
    __bf16* xact_bf = (__bf16*)p;   p += NBIG * 2;                        // u
    __bf16* dtr_bf  = (__bf16*)p;   p += (size_t)NTOK * 128 * 2;         // dt_r (bf16)
    float*  xbc     = (float*)p;    p += (size_t)NTOK * 32 * 4;          // B|C (fp32)
    __bf16* w_xp_bf = (__bf16*)p;   p += (size_t)256 * DINNER * 2;
    __bf16* w_out_bf= (__bf16*)p;   p += (size_t)DMODEL * DINNER * 2;
    char*   G       = p;            p += (size_t)2 * DINNER * DMODEL * 2; // w_in_bf / PS+Hinit
    __bf16* hid_bf  = (__bf16*)p;   p += (size_t)NTOK * DMODEL * 2;
    __bf16* y_bf    = (__bf16*)p;   p += NBIG * 2;
    __bf16* dtw_bf  = (__bf16*)p;   p += (size_t)DINNER * DTRANK * 2;
    const size_t required = (size_t)(p - (char*)d_ws);
    if (ws_size < required) return;

    __bf16* w_in_bf = (__bf16*)G;
    float2* PS      = (float2*)G;
    float*  Hinit   = (float*)(G + (size_t)NCHUNK * BATCH * DINNER * 16 * 8);

    // 0) conversions
    cvt_bf16<<<(int)(NTOK * DMODEL / 2048), 256, 0, stream>>>(hidden, hid_bf, NTOK * DMODEL / 8);
    cvt_bf16<<<(int)(2 * DINNER * DMODEL / 2048), 256, 0, stream>>>(in_proj_w, w_in_bf, 2 * DINNER * DMODEL / 8);
    cvt_bf16<<<(int)(DMODEL * DINNER / 2048), 256, 0, stream>>>(out_proj_w, w_out_bf, DMODEL * DINNER / 8);
    cvt_bf16<<<(int)(DINNER * DTRANK / 2048), 256, 0, stream>>>(dt_proj_w, dtw_bf, DINNER * DTRANK / 8);
    cvt_xproj<<<(int)(256 * DINNER / 2048), 256, 0, stream>>>(x_proj_w, w_xp_bf);

    // 1) in_proj (256^2 merged 2-phase): x (fp32) | z (bf16). grid 512 (%8==0)
    gemm8<0><<<(2 * DINNER / 256) * (NTOK / 256), 512, 0, stream>>>(
        w_in_bf, hid_bf, xbuf, z_bf, DMODEL, DMODEL, DMODEL, DINNER,
        NTOK / 256, (2 * DINNER / 256) * (NTOK / 256));

    // 2) conv + silu -> u (bf16)
    conv_silu<<<(int)(NBIG / 256), 256, 0, stream>>>(xbuf, conv_w, xact_bf);

    // 3) x_proj (128^2): dt_r -> bf16, B|C -> fp32 compact
    gemm_bf16<3><<<dim3(NTOK / 128, 2), 256, 0, stream>>>(
        w_xp_bf, xact_bf, xbc, dtr_bf, nullptr, 160, DINNER, DINNER, DINNER, 0);

    // 4) dt_proj (128^2, K=128) + softplus -> delta (over xbuf)
    gemm_bf16<2><<<dim3(NTOK / 128, DINNER / 128), 256, 0, stream>>>(
        dtw_bf, dtr_bf, xbuf, nullptr, dt_proj_b, DINNER, DTRANK, DTRANK, DTRANK, DINNER);

    // 5) chunked scan (PS/Hinit overwrite w_in_bf — dead after step 1)
    scan_partial<<<dim3(DINNER / 256, NCHUNK, BATCH), 256, 0, stream>>>(
        xbuf, xact_bf, xbc, A_log, PS);
    scan_combine<<<(BATCH * DINNER * 16) / 256, 256, 0, stream>>>(PS, Hinit);
    scan_final<<<dim3(DINNER / 256, NCHUNK, BATCH), 256, 0, stream>>>(
        xbuf, xact_bf, xbc, Hinit, z_bf, y_bf, A_log, Dvec);

    // 6) out_proj: split-K=2 with atomic accumulate. grid 256 (%8==0)
    hipMemsetAsync(out, 0, (size_t)NTOK * DMODEL * 4, stream);
    gemm8<2><<<(DMODEL / 256) * (NTOK / 256) * 2, 512, 0, stream>>>(
        w_out_bf, y_bf, out, nullptr, DINNER / 2, DINNER, DINNER, DMODEL,
        NTOK / 256, (DMODEL / 256) * (NTOK / 256));
}

// Round 7
// 723.063 us; speedup vs baseline: 1.2577x; 1.2577x over previous
//
#include <hip/hip_runtime.h>
#include <hip/hip_bf16.h>
#include <math.h>

#define L_SEQ   2048
#define BATCH   2
#define DMODEL  2048
#define DINNER  4096
#define DSTATE  16
#define DTRANK  128
#define NTOK    (L_SEQ * BATCH)   // 4096
#define CHUNK   128
#define NCHUNK  (L_SEQ / CHUNK)   // 16

typedef __attribute__((ext_vector_type(8))) __bf16 bf16x8;
typedef __attribute__((ext_vector_type(4))) float f32x4;

__device__ __forceinline__ __bf16 f2bf(float f) {
    unsigned u = __builtin_bit_cast(unsigned, f);
    unsigned r = (u + 0x7FFFu + ((u >> 16) & 1u)) >> 16;
    return __builtin_bit_cast(__bf16, (unsigned short)r);
}

__device__ __forceinline__ void load_lds16(const void* gsrc, void* lds) {
    __builtin_amdgcn_global_load_lds(
        (const __attribute__((address_space(1))) unsigned int*)gsrc,
        (__attribute__((address_space(3))) unsigned int*)lds, 16, 0, 0);
}

// Stage one 128x64 bf16 half-tile (16 KiB) with 512 threads x 2 loads.
// LDS dest LINEAR; SOURCE column inverse-swizzled (rule 21: both-sides).
__device__ __forceinline__ void stage_half(const __bf16* g, int ld,
                                           __bf16* lh, int trow, int tcol8, int scol)
{
    load_lds16(g + (size_t)trow        * ld + scol, lh +  trow       * 64 + tcol8);
    load_lds16(g + (size_t)(trow + 64) * ld + scol, lh + (trow + 64) * 64 + tcol8);
}

// ---------------------------------------------------------------------------
// 256x256 bf16 MFMA GEMM, merged 2-phase dataflow (B-fragments held in regs).
// C[m][n] = sum_k A[m][k]*Bt[n][k].  512 thr = 8 waves (2M x 4N), wave owns
// 128x64 of C.  BK=64.  Counted vmcnt(4) at boundaries; drain only pre-last.
// MODE 0: m<DINNER -> C0 fp32; else C1b bf16 (ldc=DINNER)            [in_proj]
// MODE 1: plain store C0[n*ldc+m]                                    [plain]
// MODE 3: split-K deterministic: kslice0 -> C0, kslice1 -> Cpart     [out_proj]
// ---------------------------------------------------------------------------
template <int MODE>
__global__ __launch_bounds__(512, 1)
void gemm8(const __bf16* __restrict__ A, const __bf16* __restrict__ Bt,
           float* __restrict__ C0, __bf16* __restrict__ C1b,
           float* __restrict__ Cpart,
           int Kper, int lda, int ldb, int ldc, int nbn, int ntile)
{
    __shared__ __align__(16) __bf16 lds8[2 * 4 * 8192];   // 128 KiB

    const int t = threadIdx.x;
    const int nwg = gridDim.x;                       // multiple of 8
    const int swz = ((int)blockIdx.x & 7) * (nwg >> 3) + ((int)blockIdx.x >> 3);
    const int kslice = swz / ntile;
    const int tl     = swz - kslice * ntile;
    const int m0 = (tl / nbn) * 256;
    const int n0 = (tl % nbn) * 256;
    const int kofs = kslice * Kper;

    const int l      = t & 63;
    const int w      = t >> 6;
    const int wm     = w >> 2;        // 0..1
    const int wn     = w & 3;         // 0..3
    const int lane15 = l & 15;
    const int lhi    = l >> 4;        // 0..3
    const int trow   = t >> 3;        // 0..63
    const int tcol8  = (t & 7) * 8;
    const int scol   = tcol8 ^ ((trow & 7) << 3);

    const __bf16* Ah0 = A  + (size_t)m0 * lda + kofs;
    const __bf16* Ah1 = A  + (size_t)(m0 + 128) * lda + kofs;
    const __bf16* Bh0 = Bt + (size_t)n0 * ldb + kofs;
    const __bf16* Bh1 = Bt + (size_t)(n0 + 128) * ldb + kofs;

    const int NT = Kper >> 6;

    f32x4 acc[8][4];
#pragma unroll
    for (int i = 0; i < 8; ++i)
#pragma unroll
        for (int j = 0; j < 4; ++j) acc[i][j] = (f32x4){0.f, 0.f, 0.f, 0.f};

    // ---- prologue: tile0 all 4 halves (8 ops), tile1 A-halves (4 ops)
    stage_half(Ah0,      lda, lds8 + 0 * 8192, trow, tcol8, scol);
    stage_half(Ah1,      lda, lds8 + 1 * 8192, trow, tcol8, scol);
    stage_half(Bh0,      ldb, lds8 + 2 * 8192, trow, tcol8, scol);
    stage_half(Bh1,      ldb, lds8 + 3 * 8192, trow, tcol8, scol);
    stage_half(Ah0 + 64, lda, lds8 + 4 * 8192, trow, tcol8, scol);
    stage_half(Ah1 + 64, lda, lds8 + 5 * 8192, trow, tcol8, scol);
    asm volatile("s_waitcnt vmcnt(4)" ::: "memory");
    __builtin_amdgcn_s_barrier();

    for (int tt = 0; tt < NT; ++tt) {
        const int cur = tt & 1;
        const __bf16* LA = lds8 + (cur * 4 + wm) * 8192;
        const __bf16* LB = lds8 + (cur * 4 + 2 + (wn >> 1)) * 8192;
        __bf16* nxt = lds8 + ((1 - cur) * 4) * 8192;
        const bool stg = (tt + 1 < NT);
        const int  knx = (tt + 1) << 6;

        // ---------- phase 0: B fragments (held for both phases) + A-half0
        bf16x8 b0[4], b1[4], a0[4], a1[4];
#pragma unroll
        for (int j = 0; j < 4; ++j) {
            const int lr = (wn & 1) * 64 + j * 16 + lane15;
            const int sw = (lr & 7) << 3;
            b0[j] = *(const bf16x8*)&LB[lr * 64 + ((lhi * 8) ^ sw)];
            b1[j] = *(const bf16x8*)&LB[lr * 64 + (((32 + lhi * 8)) ^ sw)];
        }
#pragma unroll
        for (int i = 0; i < 4; ++i) {
            const int lr = i * 16 + lane15;
            const int sw = (lr & 7) << 3;
            a0[i] = *(const bf16x8*)&LA[lr * 64 + ((lhi * 8) ^ sw)];
            a1[i] = *(const bf16x8*)&LA[lr * 64 + (((32 + lhi * 8)) ^ sw)];
        }
        if (stg) stage_half(Bh0 + knx, ldb, nxt + 2 * 8192, trow, tcol8, scol);

        __builtin_amdgcn_s_setprio(1);
#pragma unroll
        for (int i = 0; i < 4; ++i)
#pragma unroll
            for (int j = 0; j < 4; ++j) {
                acc[i][j] = __builtin_amdgcn_mfma_f32_16x16x32_bf16(
                    a0[i], b0[j], acc[i][j], 0, 0, 0);
                acc[i][j] = __builtin_amdgcn_mfma_f32_16x16x32_bf16(
                    a1[i], b1[j], acc[i][j], 0, 0, 0);
            }
        __builtin_amdgcn_s_setprio(0);
        __builtin_amdgcn_s_barrier();

        // ---------- phase 1: A-half1, reuse B fragments
#pragma unroll
        for (int i = 0; i < 4; ++i) {
            const int lr = 64 + i * 16 + lane15;
            const int sw = (lr & 7) << 3;
            a0[i] = *(const bf16x8*)&LA[lr * 64 + ((lhi * 8) ^ sw)];
            a1[i] = *(const bf16x8*)&LA[lr * 64 + (((32 + lhi * 8)) ^ sw)];
        }
        if (stg) stage_half(Bh1 + knx, ldb, nxt + 3 * 8192, trow, tcol8, scol);

        __builtin_amdgcn_s_setprio(1);
#pragma unroll
        for (int i = 0; i < 4; ++i)
#pragma unroll
            for (int j = 0; j < 4; ++j) {
                acc[4 + i][j] = __builtin_amdgcn_mfma_f32_16x16x32_bf16(
                    a0[i], b0[j], acc[4 + i][j], 0, 0, 0);
                acc[4 + i][j] = __builtin_amdgcn_mfma_f32_16x16x32_bf16(
                    a1[i], b1[j], acc[4 + i][j], 0, 0, 0);
            }
        __builtin_amdgcn_s_setprio(0);
        __builtin_amdgcn_s_barrier();

        // ---------- boundary into tile tt+1
        if (tt + 1 < NT) {
            if (tt + 2 < NT) {
                const int k2 = (tt + 2) << 6;
                __bf16* nn = lds8 + (cur * 4) * 8192;
                stage_half(Ah0 + k2, lda, nn + 0 * 8192, trow, tcol8, scol);
                stage_half(Ah1 + k2, lda, nn + 1 * 8192, trow, tcol8, scol);
                asm volatile("s_waitcnt vmcnt(4)" ::: "memory");
            } else {
                asm volatile("s_waitcnt vmcnt(0)" ::: "memory");
            }
            __builtin_amdgcn_s_barrier();
        }
    }

    // ---- epilogue
    const int rbase = lhi * 4;
    float* const dst = (MODE == 3) ? (kslice ? Cpart : C0) : C0;
#pragma unroll
    for (int fi = 0; fi < 8; ++fi) {
#pragma unroll
        for (int fj = 0; fj < 4; ++fj) {
#pragma unroll
            for (int r = 0; r < 4; ++r) {
                const int m = m0 + wm * 128 + fi * 16 + rbase + r;
                const int n = n0 + wn * 64 + fj * 16 + lane15;
                const float v = acc[fi][fj][r];
                if constexpr (MODE == 0) {
                    if (m < DINNER) C0[(size_t)n * DINNER + m] = v;
                    else            C1b[(size_t)n * DINNER + (m - DINNER)] = f2bf(v);
                } else {
                    dst[(size_t)n * ldc + m] = v;
                }
            }
        }
    }
}

// out += part  (split-K reduction, no atomics)
__global__ __launch_bounds__(256)
void addout(float* __restrict__ out, const float* __restrict__ part, int n4)
{
    const int i = blockIdx.x * 256 + threadIdx.x;
    if (i >= n4) return;
    float4 a = *(const float4*)&out[(size_t)i * 4];
    const float4 b = *(const float4*)&part[(size_t)i * 4];
    a.x += b.x; a.y += b.y; a.z += b.z; a.w += b.w;
    *(float4*)&out[(size_t)i * 4] = a;
}

// ---------------------------------------------------------------------------
// m97-style 128x128 bf16 MFMA GEMM (small GEMMs: x_proj, dt_proj).
// MODE 2: softplus(v + bias[m]) -> C0[n*ldc+m] fp32          [dt_proj]
// MODE 3: m<128 -> C1b bf16 [n*128+m]; 128<=m<160 -> C0 fp32 [n*32+m-128]
// ---------------------------------------------------------------------------
template <int MODE>
__global__ __launch_bounds__(256)
void gemm_bf16(const __bf16* __restrict__ A, const __bf16* __restrict__ Bt,
               float* __restrict__ C0, __bf16* __restrict__ C1b,
               const float* __restrict__ bias,
               int Mvalid, int K, int lda, int ldb, int ldc)
{
    __shared__ __align__(16) __bf16 As[128 * 64];
    __shared__ __align__(16) __bf16 Bs[128 * 64];

    const int t  = threadIdx.x;
    const int m0 = blockIdx.y * 128;
    const int n0 = blockIdx.x * 128;
    const int l  = t & 63;
    const int w  = t >> 6;
    const int wr = (w >> 1) * 64;
    const int wc = (w & 1) * 64;
    const int lrow = t >> 3;
    const int lk   = (t & 7) * 8;

    f32x4 acc[4][4];
#pragma unroll
    for (int i = 0; i < 4; ++i)
#pragma unroll
        for (int j = 0; j < 4; ++j) acc[i][j] = (f32x4){0.f, 0.f, 0.f, 0.f};

    for (int k0 = 0; k0 < K; k0 += 64) {
#pragma unroll
        for (int q = 0; q < 4; ++q) {
            const int row = q * 32 + lrow;
            load_lds16(A  + (size_t)(m0 + row) * lda + k0 + lk, &As[row * 64 + lk]);
            load_lds16(Bt + (size_t)(n0 + row) * ldb + k0 + lk, &Bs[row * 64 + lk]);
        }
        __syncthreads();

#pragma unroll
        for (int kk = 0; kk < 2; ++kk) {
            const int krd = kk * 32 + (l >> 4) * 8;
            bf16x8 a[4], b[4];
#pragma unroll
            for (int i = 0; i < 4; ++i) {
                a[i] = *(const bf16x8*)&As[(wr + i * 16 + (l & 15)) * 64 + krd];
                b[i] = *(const bf16x8*)&Bs[(wc + i * 16 + (l & 15)) * 64 + krd];
            }
#pragma unroll
            for (int i = 0; i < 4; ++i)
#pragma unroll
                for (int j = 0; j < 4; ++j)
                    acc[i][j] = __builtin_amdgcn_mfma_f32_16x16x32_bf16(
                        a[i], b[j], acc[i][j], 0, 0, 0);
        }
        __syncthreads();
    }

    const int rbase = (l >> 4) * 4;
    const int cbase = l & 15;
#pragma unroll
    for (int i = 0; i < 4; ++i) {
#pragma unroll
        for (int j = 0; j < 4; ++j) {
#pragma unroll
            for (int r = 0; r < 4; ++r) {
                const int m = m0 + wr + i * 16 + rbase + r;
                const int n = n0 + wc + j * 16 + cbase;
                const float v = acc[i][j][r];
                if constexpr (MODE == 2) {
                    const float vb = v + bias[m];
                    const float sp = (vb > 20.f) ? vb : log1pf(__expf(vb));
                    C0[(size_t)n * ldc + m] = sp;
                } else {   // MODE 3
                    if (m < 128)      C1b[(size_t)n * 128 + m] = f2bf(v);
                    else if (m < 160) C0[(size_t)n * 32 + (m - 128)] = v;
                }
            }
        }
    }
}

// ---------------------------------------------------------------------------
__global__ __launch_bounds__(256)
void cvt_bf16(const float* __restrict__ in, __bf16* __restrict__ out, int n8)
{
    const int i = blockIdx.x * 256 + threadIdx.x;
    if (i >= n8) return;
    const size_t base = (size_t)i * 8;
    const float4 a = *(const float4*)&in[base];
    const float4 b = *(const float4*)&in[base + 4];
    __align__(16) __bf16 o[8];
    o[0] = f2bf(a.x); o[1] = f2bf(a.y); o[2] = f2bf(a.z); o[3] = f2bf(a.w);
    o[4] = f2bf(b.x); o[5] = f2bf(b.y); o[6] = f2bf(b.z); o[7] = f2bf(b.w);
    *(bf16x8*)&out[base] = *(const bf16x8*)o;
}

__global__ __launch_bounds__(256)
void cvt_xproj(const float* __restrict__ in, __bf16* __restrict__ out)
{
    const int i = blockIdx.x * 256 + threadIdx.x;
    const size_t base = (size_t)i * 8;
    const int row = (int)(base >> 12);
    __align__(16) __bf16 o[8];
    if (row < 160) {
        const float4 a = *(const float4*)&in[base];
        const float4 b = *(const float4*)&in[base + 4];
        o[0] = f2bf(a.x); o[1] = f2bf(a.y); o[2] = f2bf(a.z); o[3] = f2bf(a.w);
        o[4] = f2bf(b.x); o[5] = f2bf(b.y); o[6] = f2bf(b.z); o[7] = f2bf(b.w);
    } else {
#pragma unroll
        for (int k = 0; k < 8; ++k) o[k] = f2bf(0.f);
    }
    *(bf16x8*)&out[base] = *(const bf16x8*)o;
}

// ---------------------------------------------------------------------------
__global__ __launch_bounds__(256)
void conv_silu(const float* __restrict__ x, const float* __restrict__ conv_w,
               __bf16* __restrict__ xact_bf)
{
    const size_t idx = (size_t)blockIdx.x * 256 + threadIdx.x;
    const int e = (int)(idx & (DINNER - 1));
    const int n = (int)(idx >> 12);

    const float4 w = *(const float4*)&conv_w[e * 4];
    float s = w.w * x[idx];
    if (n >= 2) s += w.z * x[idx - (size_t)2 * DINNER];
    if (n >= 4) s += w.y * x[idx - (size_t)4 * DINNER];
    if (n >= 6) s += w.x * x[idx - (size_t)6 * DINNER];
    const float v = s / (1.f + __expf(-s));
    xact_bf[idx] = f2bf(v);
}

// ---------------------------------------------------------------------------
// Chunked selective scan (unchanged).
// ---------------------------------------------------------------------------
__global__ __launch_bounds__(256)
void scan_partial(const float* __restrict__ delta, const __bf16* __restrict__ u,
                  const float* __restrict__ xbc, const float* __restrict__ A_log,
                  float2* __restrict__ PS)
{
    const int e     = blockIdx.x * 256 + threadIdx.x;
    const int chunk = blockIdx.y;
    const int b     = blockIdx.z;

    __shared__ float BC[CHUNK][32];
    for (int i = threadIdx.x; i < CHUNK * 32; i += 256) {
        const int ll = i >> 5, f = i & 31;
        BC[ll][f] = xbc[(size_t)((chunk * CHUNK + ll) * BATCH + b) * 32 + f];
    }

    float Av[16];
#pragma unroll
    for (int s = 0; s < 16; s += 4) {
        float4 tv = *(const float4*)&A_log[e * 16 + s];
        Av[s] = -__expf(tv.x); Av[s + 1] = -__expf(tv.y);
        Av[s + 2] = -__expf(tv.z); Av[s + 3] = -__expf(tv.w);
    }
    __syncthreads();

    float P[16], S[16];
#pragma unroll
    for (int s = 0; s < 16; ++s) { P[s] = 1.f; S[s] = 0.f; }

#pragma unroll 4
    for (int ll = 0; ll < CHUNK; ++ll) {
        const int tok = (chunk * CHUNK + ll) * BATCH + b;
        const size_t ce = (size_t)tok * DINNER + e;
        const float dl = delta[ce];
        const float du = dl * (float)u[ce];
#pragma unroll
        for (int s = 0; s < 16; ++s) {
            const float dA = __expf(dl * Av[s]);
            S[s] = fmaf(dA, S[s], du * BC[ll][s]);
            P[s] *= dA;
        }
    }

    float2* outp = PS + ((size_t)(chunk * BATCH + b) * DINNER + e) * 16;
#pragma unroll
    for (int s = 0; s < 16; ++s) outp[s] = make_float2(P[s], S[s]);
}

__global__ __launch_bounds__(256)
void scan_combine(const float2* __restrict__ PS, float* __restrict__ Hinit)
{
    const size_t pos = (size_t)blockIdx.x * 256 + threadIdx.x;
    const size_t stride = (size_t)BATCH * DINNER * 16;
    float h = 0.f;
#pragma unroll
    for (int c = 0; c < NCHUNK; ++c) {
        Hinit[c * stride + pos] = h;
        const float2 ps = PS[c * stride + pos];
        h = fmaf(ps.x, h, ps.y);
    }
}

__global__ __launch_bounds__(256)
void scan_final(const float* __restrict__ delta, const __bf16* __restrict__ u,
                const float* __restrict__ xbc, const float* __restrict__ Hinit,
                const __bf16* __restrict__ z_bf, __bf16* __restrict__ y_bf,
                const float* __restrict__ A_log, const float* __restrict__ Dvec)
{
    const int e     = blockIdx.x * 256 + threadIdx.x;
    const int chunk = blockIdx.y;
    const int b     = blockIdx.z;

    __shared__ float BC[CHUNK][32];
    for (int i = threadIdx.x; i < CHUNK * 32; i += 256) {
        const int ll = i >> 5, f = i & 31;
        BC[ll][f] = xbc[(size_t)((chunk * CHUNK + ll) * BATCH + b) * 32 + f];
    }

    float Av[16];
#pragma unroll
    for (int s = 0; s < 16; s += 4) {
        float4 tv = *(const float4*)&A_log[e * 16 + s];
        Av[s] = -__expf(tv.x); Av[s + 1] = -__expf(tv.y);
        Av[s + 2] = -__expf(tv.z); Av[s + 3] = -__expf(tv.w);
    }
    const float Dv = Dvec[e];

    float h[16];
    const float* hi = Hinit + (size_t)chunk * BATCH * DINNER * 16
                            + ((size_t)b * DINNER + e) * 16;
#pragma unroll
    for (int s = 0; s < 16; s += 4) *(float4*)&h[s] = *(const float4*)&hi[s];
    __syncthreads();

#pragma unroll 2
    for (int ll = 0; ll < CHUNK; ++ll) {
        const int tok = (chunk * CHUNK + ll) * BATCH + b;
        const size_t ce = (size_t)tok * DINNER + e;
        const float dl = delta[ce];
        const float ul = (float)u[ce];
        const float du = dl * ul;
        float y = 0.f;
#pragma unroll
        for (int s = 0; s < 16; ++s) {
            const float dA = __expf(dl * Av[s]);
            h[s] = fmaf(dA, h[s], du * BC[ll][s]);
            y = fmaf(h[s], BC[ll][16 + s], y);
        }
        const float zl = (float)z_bf[ce];
        const float sig = 1.f / (1.f + __expf(-zl));
        y_bf[ce] = f2bf((y + ul * Dv) * (zl * sig));
    }
}

// ---------------------------------------------------------------------------
extern "C" void kernel_launch(void* const* d_in, const int* in_sizes, int n_in,
                              void* d_out, int out_size, void* d_ws, size_t ws_size,
                              hipStream_t stream)
{
    const float* hidden    = (const float*)d_in[0];
    const float* in_proj_w = (const float*)d_in[1];
    const float* conv_w    = (const float*)d_in[2];
    const float* x_proj_w  = (const float*)d_in[3];
    const float* dt_proj_w = (const float*)d_in[4];
    const float* dt_proj_b = (const float*)d_in[5];
    const float* A_log     = (const float*)d_in[6];
    const float* Dvec      = (const float*)d_in[7];
    const float* out_proj_w= (const float*)d_in[8];
    float* out = (float*)d_out;

    // -------- workspace (identical layout/total to R5's passing run)
    char* p = (char*)d_ws;
    const size_t NBIG = (size_t)NTOK * DINNER;
    float*  xbuf    = (float*)p;    p += NBIG * 4;                        // x -> delta
    __bf16* z_bf    = (__bf16*)p;   p += NBIG * 2;                        // z
    __bf16* xact_bf = (__bf16*)p;   p += NBIG * 2;                        // u
    __bf16* dtr_bf  = (__bf16*)p;   p += (size_t)NTOK * 128 * 2;         // dt_r (bf16)
    float*  xbc     = (float*)p;    p += (size_t)NTOK * 32 * 4;          // B|C (fp32)
    __bf16* w_xp_bf = (__bf16*)p;   p += (size_t)256 * DINNER * 2;
    __bf16* w_out_bf= (__bf16*)p;   p += (size_t)DMODEL * DINNER * 2;
    char*   G       = p;            p += (size_t)2 * DINNER * DMODEL * 2; // 33.5 MB, multi-use
    __bf16* hid_bf  = (__bf16*)p;   p += (size_t)NTOK * DMODEL * 2;
    __bf16* y_bf    = (__bf16*)p;   p += NBIG * 2;
    __bf16* dtw_bf  = (__bf16*)p;   p += (size_t)DINNER * DTRANK * 2;
    const size_t required = (size_t)(p - (char*)d_ws);
    if (ws_size < required) return;

    // G region lifetime: w_in_bf (steps 0-1) -> PS+Hinit (step 5) -> Cpart (step 6)
    __bf16* w_in_bf = (__bf16*)G;
    float2* PS      = (float2*)G;
    float*  Hinit   = (float*)(G + (size_t)NCHUNK * BATCH * DINNER * 16 * 8);
    float*  Cpart   = (float*)G;                                          // 33.5 MB exactly

    // 0) conversions
    cvt_bf16<<<(int)(NTOK * DMODEL / 2048), 256, 0, stream>>>(hidden, hid_bf, NTOK * DMODEL / 8);
    cvt_bf16<<<(int)(2 * DINNER * DMODEL / 2048), 256, 0, stream>>>(in_proj_w, w_in_bf, 2 * DINNER * DMODEL / 8);
    cvt_bf16<<<(int)(DMODEL * DINNER / 2048), 256, 0, stream>>>(out_proj_w, w_out_bf, DMODEL * DINNER / 8);
    cvt_bf16<<<(int)(DINNER * DTRANK / 2048), 256, 0, stream>>>(dt_proj_w, dtw_bf, DINNER * DTRANK / 8);
    cvt_xproj<<<(int)(256 * DINNER / 2048), 256, 0, stream>>>(x_proj_w, w_xp_bf);

    // 1) in_proj (256^2 merged 2-phase): x (fp32) | z (bf16). grid 512 (%8==0)
    gemm8<0><<<(2 * DINNER / 256) * (NTOK / 256), 512, 0, stream>>>(
        w_in_bf, hid_bf, xbuf, z_bf, nullptr, DMODEL, DMODEL, DMODEL, DINNER,
        NTOK / 256, (2 * DINNER / 256) * (NTOK / 256));

    // 2) conv + silu -> u (bf16)
    conv_silu<<<(int)(NBIG / 256), 256, 0, stream>>>(xbuf, conv_w, xact_bf);

    // 3) x_proj (128^2): dt_r -> bf16, B|C -> fp32 compact
    gemm_bf16<3><<<dim3(NTOK / 128, 2), 256, 0, stream>>>(
        w_xp_bf, xact_bf, xbc, dtr_bf, nullptr, 160, DINNER, DINNER, DINNER, 0);

    // 4) dt_proj (128^2, K=128) + softplus -> delta (over xbuf)
    gemm_bf16<2><<<dim3(NTOK / 128, DINNER / 128), 256, 0, stream>>>(
        dtw_bf, dtr_bf, xbuf, nullptr, dt_proj_b, DINNER, DTRANK, DTRANK, DTRANK, DINNER);

    // 5) chunked scan (PS/Hinit overwrite w_in_bf — dead after step 1)
    scan_partial<<<dim3(DINNER / 256, NCHUNK, BATCH), 256, 0, stream>>>(
        xbuf, xact_bf, xbc, A_log, PS);
    scan_combine<<<(BATCH * DINNER * 16) / 256, 256, 0, stream>>>(PS, Hinit);
    scan_final<<<dim3(DINNER / 256, NCHUNK, BATCH), 256, 0, stream>>>(
        xbuf, xact_bf, xbc, Hinit, z_bf, y_bf, A_log, Dvec);

    // 6) out_proj: deterministic split-K=2 (slice0 -> out, slice1 -> Cpart),
    //    then out += Cpart.  grid 256 (%8==0), no atomics.
    gemm8<3><<<(DMODEL / 256) * (NTOK / 256) * 2, 512, 0, stream>>>(
        w_out_bf, y_bf, out, nullptr, Cpart, DINNER / 2, DINNER, DINNER, DMODEL,
        NTOK / 256, (DMODEL / 256) * (NTOK / 256));
    addout<<<(NTOK * DMODEL / 4 + 255) / 256, 256, 0, stream>>>(
        out, Cpart, NTOK * DMODEL / 4);
}

// Round 8
// 721.864 us; speedup vs baseline: 1.2598x; 1.0017x over previous
//
#include <hip/hip_runtime.h>
#include <hip/hip_bf16.h>
#include <math.h>

#define L_SEQ   2048
#define BATCH   2
#define DMODEL  2048
#define DINNER  4096
#define DSTATE  16
#define DTRANK  128
#define NTOK    (L_SEQ * BATCH)   // 4096
#define CHUNK   128
#define NCHUNK  (L_SEQ / CHUNK)   // 16

typedef __attribute__((ext_vector_type(8))) __bf16 bf16x8;
typedef __attribute__((ext_vector_type(4))) float f32x4;

__device__ __forceinline__ __bf16 f2bf(float f) {
    unsigned u = __builtin_bit_cast(unsigned, f);
    unsigned r = (u + 0x7FFFu + ((u >> 16) & 1u)) >> 16;
    return __builtin_bit_cast(__bf16, (unsigned short)r);
}

__device__ __forceinline__ void load_lds16(const void* gsrc, void* lds) {
    __builtin_amdgcn_global_load_lds(
        (const __attribute__((address_space(1))) unsigned int*)gsrc,
        (__attribute__((address_space(3))) unsigned int*)lds, 16, 0, 0);
}

// Stage one 128x64 bf16 half-tile (16 KiB) with 512 threads x 2 loads.
// LDS dest LINEAR; SOURCE column inverse-swizzled (rule 21: both-sides).
__device__ __forceinline__ void stage_half(const __bf16* g, int ld,
                                           __bf16* lh, int trow, int tcol8, int scol)
{
    load_lds16(g + (size_t)trow        * ld + scol, lh +  trow       * 64 + tcol8);
    load_lds16(g + (size_t)(trow + 64) * ld + scol, lh + (trow + 64) * 64 + tcol8);
}

// ---------------------------------------------------------------------------
// 256x256 bf16 MFMA GEMM, fine-grained 4-phase (16-MFMA) schedule.
// C[m][n] = sum_k A[m][k]*Bt[n][k].  512 thr = 8 waves (2M x 4N).
// Wave (wm,wn): rows wm*128..+127; cols {wn*32..+31} in EACH B-half.
// Per K-tile, 4 phases = quadrants (rows-half, B-half):
//   q0: read A-h0(8)+B0(4); stage Ah0';            16 MFMA acc[0..3][0..1]
//   q1: vmcnt(2);bar; read B1(4); stage Ah1';      16 MFMA acc[0..3][2..3]
//   q2: bar; read A-h1(8); stage Bh0';             16 MFMA acc[4..7][0..1]
//   q3: bar; (all held) stage Bh1';                16 MFMA acc[4..7][2..3]
//   boundary: vmcnt(2); bar   (guarantees next tile's Ah0,Ah1,Bh0;
//             its Bh1 is guaranteed by next tile's q1 vmcnt(2))
// Waits derived per-wave: each thread issues 2 loads/stage; outstanding at
// tile entry = 8 (4 halves), at q1 entry <= 4 with Bh1 oldest.  Last tile
// (no staging) uses vmcnt(0) at q1.  Never drains elsewhere.
// LDS: 2 x {A-h0,A-h1,B-h0,B-h1} x 16KiB = 128 KiB.
// MODE 0: m<DINNER -> C0 fp32; else C1b bf16 (ldc=DINNER)            [in_proj]
// MODE 3: split-K deterministic: kslice0 -> C0, kslice1 -> Cpart     [out_proj]
// ---------------------------------------------------------------------------
template <int MODE>
__global__ __launch_bounds__(512, 1)
void gemm8(const __bf16* __restrict__ A, const __bf16* __restrict__ Bt,
           float* __restrict__ C0, __bf16* __restrict__ C1b,
           float* __restrict__ Cpart,
           int Kper, int lda, int ldb, int ldc, int nbn, int ntile)
{
    __shared__ __align__(16) __bf16 lds8[2 * 4 * 8192];   // 128 KiB

    const int t = threadIdx.x;
    const int nwg = gridDim.x;                       // multiple of 8
    const int swz = ((int)blockIdx.x & 7) * (nwg >> 3) + ((int)blockIdx.x >> 3);
    const int kslice = swz / ntile;
    const int tl     = swz - kslice * ntile;
    const int m0 = (tl / nbn) * 256;
    const int n0 = (tl % nbn) * 256;
    const int kofs = kslice * Kper;

    const int l      = t & 63;
    const int w      = t >> 6;
    const int wm     = w >> 2;        // 0..1
    const int wn     = w & 3;         // 0..3
    const int lane15 = l & 15;
    const int lhi    = l >> 4;        // 0..3
    const int trow   = t >> 3;        // 0..63
    const int tcol8  = (t & 7) * 8;
    const int scol   = tcol8 ^ ((trow & 7) << 3);

    const __bf16* Ah0 = A  + (size_t)m0 * lda + kofs;
    const __bf16* Ah1 = A  + (size_t)(m0 + 128) * lda + kofs;
    const __bf16* Bh0 = Bt + (size_t)n0 * ldb + kofs;
    const __bf16* Bh1 = Bt + (size_t)(n0 + 128) * ldb + kofs;

    const int NT = Kper >> 6;

    f32x4 acc[8][4];
#pragma unroll
    for (int i = 0; i < 8; ++i)
#pragma unroll
        for (int j = 0; j < 4; ++j) acc[i][j] = (f32x4){0.f, 0.f, 0.f, 0.f};

    // ---- prologue: stage tile0's 4 halves (8 ops/thread)
    stage_half(Ah0, lda, lds8 + 0 * 8192, trow, tcol8, scol);
    stage_half(Ah1, lda, lds8 + 1 * 8192, trow, tcol8, scol);
    stage_half(Bh0, ldb, lds8 + 2 * 8192, trow, tcol8, scol);
    stage_half(Bh1, ldb, lds8 + 3 * 8192, trow, tcol8, scol);
    asm volatile("s_waitcnt vmcnt(2)" ::: "memory");   // Ah0,Ah1,Bh0 done
    __builtin_amdgcn_s_barrier();
    asm volatile("" ::: "memory");

    for (int tt = 0; tt < NT; ++tt) {
        const int cur = tt & 1;
        const __bf16* LA  = lds8 + (cur * 4 + wm) * 8192;
        const __bf16* LB0 = lds8 + (cur * 4 + 2) * 8192;
        const __bf16* LB1 = lds8 + (cur * 4 + 3) * 8192;
        __bf16* nxt = lds8 + ((1 - cur) * 4) * 8192;
        const bool stg = (tt + 1 < NT);
        const int  knx = (tt + 1) << 6;

        bf16x8 aK0[4], aK1[4], bK0[2][2], bK1[2][2];   // b[bhalf][j]

        // ---------- phase 0: A rows-half0 + B-half0 -> acc[0..3][0..1]
#pragma unroll
        for (int i = 0; i < 4; ++i) {
            const int lr = i * 16 + lane15;
            const int sw = (lr & 7) << 3;
            aK0[i] = *(const bf16x8*)&LA[lr * 64 + ((lhi * 8) ^ sw)];
            aK1[i] = *(const bf16x8*)&LA[lr * 64 + ((32 + lhi * 8) ^ sw)];
        }
#pragma unroll
        for (int j = 0; j < 2; ++j) {
            const int lr = wn * 32 + j * 16 + lane15;
            const int sw = (lr & 7) << 3;
            bK0[0][j] = *(const bf16x8*)&LB0[lr * 64 + ((lhi * 8) ^ sw)];
            bK1[0][j] = *(const bf16x8*)&LB0[lr * 64 + ((32 + lhi * 8) ^ sw)];
        }
        if (stg) stage_half(Ah0 + knx, lda, nxt + 0 * 8192, trow, tcol8, scol);
        __builtin_amdgcn_s_setprio(1);
#pragma unroll
        for (int i = 0; i < 4; ++i)
#pragma unroll
            for (int j = 0; j < 2; ++j) {
                acc[i][j] = __builtin_amdgcn_mfma_f32_16x16x32_bf16(
                    aK0[i], bK0[0][j], acc[i][j], 0, 0, 0);
                acc[i][j] = __builtin_amdgcn_mfma_f32_16x16x32_bf16(
                    aK1[i], bK1[0][j], acc[i][j], 0, 0, 0);
            }
        __builtin_amdgcn_s_setprio(0);

        // ---------- phase 1: ensure Bh1(tt) staged; B-half1 -> acc[0..3][2..3]
        if (stg) asm volatile("s_waitcnt vmcnt(2)" ::: "memory");
        else     asm volatile("s_waitcnt vmcnt(0)" ::: "memory");
        __builtin_amdgcn_s_barrier();
        asm volatile("" ::: "memory");
#pragma unroll
        for (int j = 0; j < 2; ++j) {
            const int lr = wn * 32 + j * 16 + lane15;
            const int sw = (lr & 7) << 3;
            bK0[1][j] = *(const bf16x8*)&LB1[lr * 64 + ((lhi * 8) ^ sw)];
            bK1[1][j] = *(const bf16x8*)&LB1[lr * 64 + ((32 + lhi * 8) ^ sw)];
        }
        if (stg) stage_half(Ah1 + knx, lda, nxt + 1 * 8192, trow, tcol8, scol);
        __builtin_amdgcn_s_setprio(1);
#pragma unroll
        for (int i = 0; i < 4; ++i)
#pragma unroll
            for (int j = 0; j < 2; ++j) {
                acc[i][2 + j] = __builtin_amdgcn_mfma_f32_16x16x32_bf16(
                    aK0[i], bK0[1][j], acc[i][2 + j], 0, 0, 0);
                acc[i][2 + j] = __builtin_amdgcn_mfma_f32_16x16x32_bf16(
                    aK1[i], bK1[1][j], acc[i][2 + j], 0, 0, 0);
            }
        __builtin_amdgcn_s_setprio(0);

        // ---------- phase 2: A rows-half1 (B0 held) -> acc[4..7][0..1]
        __builtin_amdgcn_s_barrier();
        asm volatile("" ::: "memory");
#pragma unroll
        for (int i = 0; i < 4; ++i) {
            const int lr = 64 + i * 16 + lane15;
            const int sw = (lr & 7) << 3;
            aK0[i] = *(const bf16x8*)&LA[lr * 64 + ((lhi * 8) ^ sw)];
            aK1[i] = *(const bf16x8*)&LA[lr * 64 + ((32 + lhi * 8) ^ sw)];
        }
        if (stg) stage_half(Bh0 + knx, ldb, nxt + 2 * 8192, trow, tcol8, scol);
        __builtin_amdgcn_s_setprio(1);
#pragma unroll
        for (int i = 0; i < 4; ++i)
#pragma unroll
            for (int j = 0; j < 2; ++j) {
                acc[4 + i][j] = __builtin_amdgcn_mfma_f32_16x16x32_bf16(
                    aK0[i], bK0[0][j], acc[4 + i][j], 0, 0, 0);
                acc[4 + i][j] = __builtin_amdgcn_mfma_f32_16x16x32_bf16(
                    aK1[i], bK1[0][j], acc[4 + i][j], 0, 0, 0);
            }
        __builtin_amdgcn_s_setprio(0);

        // ---------- phase 3: all operands held -> acc[4..7][2..3]
        __builtin_amdgcn_s_barrier();
        asm volatile("" ::: "memory");
        if (stg) stage_half(Bh1 + knx, ldb, nxt + 3 * 8192, trow, tcol8, scol);
        __builtin_amdgcn_s_setprio(1);
#pragma unroll
        for (int i = 0; i < 4; ++i)
#pragma unroll
            for (int j = 0; j < 2; ++j) {
                acc[4 + i][2 + j] = __builtin_amdgcn_mfma_f32_16x16x32_bf16(
                    aK0[i], bK0[1][j], acc[4 + i][2 + j], 0, 0, 0);
                acc[4 + i][2 + j] = __builtin_amdgcn_mfma_f32_16x16x32_bf16(
                    aK1[i], bK1[1][j], acc[4 + i][2 + j], 0, 0, 0);
            }
        __builtin_amdgcn_s_setprio(0);

        // ---------- tile boundary: next tile's Ah0,Ah1,Bh0 guaranteed
        if (tt + 1 < NT) {
            asm volatile("s_waitcnt vmcnt(2)" ::: "memory");
            __builtin_amdgcn_s_barrier();
            asm volatile("" ::: "memory");
        }
    }

    // ---- epilogue (cols: wave strip in each B-half)
    const int rbase = lhi * 4;
    float* const dst = (MODE == 3) ? (kslice ? Cpart : C0) : C0;
#pragma unroll
    for (int fi = 0; fi < 8; ++fi) {
#pragma unroll
        for (int fj = 0; fj < 4; ++fj) {
            const int n = n0 + (fj >> 1) * 128 + wn * 32 + (fj & 1) * 16 + lane15;
#pragma unroll
            for (int r = 0; r < 4; ++r) {
                const int m = m0 + wm * 128 + fi * 16 + rbase + r;
                const float v = acc[fi][fj][r];
                if constexpr (MODE == 0) {
                    if (m < DINNER) C0[(size_t)n * DINNER + m] = v;
                    else            C1b[(size_t)n * DINNER + (m - DINNER)] = f2bf(v);
                } else {
                    dst[(size_t)n * ldc + m] = v;
                }
            }
        }
    }
}

// out += part  (split-K reduction, no atomics)
__global__ __launch_bounds__(256)
void addout(float* __restrict__ out, const float* __restrict__ part, int n4)
{
    const int i = blockIdx.x * 256 + threadIdx.x;
    if (i >= n4) return;
    float4 a = *(const float4*)&out[(size_t)i * 4];
    const float4 b = *(const float4*)&part[(size_t)i * 4];
    a.x += b.x; a.y += b.y; a.z += b.z; a.w += b.w;
    *(float4*)&out[(size_t)i * 4] = a;
}

// ---------------------------------------------------------------------------
// m97-style 128x128 bf16 MFMA GEMM (small GEMMs: x_proj, dt_proj).
// MODE 2: softplus(v + bias[m]) -> C0[n*ldc+m] fp32          [dt_proj]
// MODE 3: m<128 -> C1b bf16 [n*128+m]; 128<=m<160 -> C0 fp32 [n*32+m-128]
// ---------------------------------------------------------------------------
template <int MODE>
__global__ __launch_bounds__(256)
void gemm_bf16(const __bf16* __restrict__ A, const __bf16* __restrict__ Bt,
               float* __restrict__ C0, __bf16* __restrict__ C1b,
               const float* __restrict__ bias,
               int Mvalid, int K, int lda, int ldb, int ldc)
{
    __shared__ __align__(16) __bf16 As[128 * 64];
    __shared__ __align__(16) __bf16 Bs[128 * 64];

    const int t  = threadIdx.x;
    const int m0 = blockIdx.y * 128;
    const int n0 = blockIdx.x * 128;
    const int l  = t & 63;
    const int w  = t >> 6;
    const int wr = (w >> 1) * 64;
    const int wc = (w & 1) * 64;
    const int lrow = t >> 3;
    const int lk   = (t & 7) * 8;

    f32x4 acc[4][4];
#pragma unroll
    for (int i = 0; i < 4; ++i)
#pragma unroll
        for (int j = 0; j < 4; ++j) acc[i][j] = (f32x4){0.f, 0.f, 0.f, 0.f};

    for (int k0 = 0; k0 < K; k0 += 64) {
#pragma unroll
        for (int q = 0; q < 4; ++q) {
            const int row = q * 32 + lrow;
            load_lds16(A  + (size_t)(m0 + row) * lda + k0 + lk, &As[row * 64 + lk]);
            load_lds16(Bt + (size_t)(n0 + row) * ldb + k0 + lk, &Bs[row * 64 + lk]);
        }
        __syncthreads();

#pragma unroll
        for (int kk = 0; kk < 2; ++kk) {
            const int krd = kk * 32 + (l >> 4) * 8;
            bf16x8 a[4], b[4];
#pragma unroll
            for (int i = 0; i < 4; ++i) {
                a[i] = *(const bf16x8*)&As[(wr + i * 16 + (l & 15)) * 64 + krd];
                b[i] = *(const bf16x8*)&Bs[(wc + i * 16 + (l & 15)) * 64 + krd];
            }
#pragma unroll
            for (int i = 0; i < 4; ++i)
#pragma unroll
                for (int j = 0; j < 4; ++j)
                    acc[i][j] = __builtin_amdgcn_mfma_f32_16x16x32_bf16(
                        a[i], b[j], acc[i][j], 0, 0, 0);
        }
        __syncthreads();
    }

    const int rbase = (l >> 4) * 4;
    const int cbase = l & 15;
#pragma unroll
    for (int i = 0; i < 4; ++i) {
#pragma unroll
        for (int j = 0; j < 4; ++j) {
#pragma unroll
            for (int r = 0; r < 4; ++r) {
                const int m = m0 + wr + i * 16 + rbase + r;
                const int n = n0 + wc + j * 16 + cbase;
                const float v = acc[i][j][r];
                if constexpr (MODE == 2) {
                    const float vb = v + bias[m];
                    const float sp = (vb > 20.f) ? vb : log1pf(__expf(vb));
                    C0[(size_t)n * ldc + m] = sp;
                } else {   // MODE 3
                    if (m < 128)      C1b[(size_t)n * 128 + m] = f2bf(v);
                    else if (m < 160) C0[(size_t)n * 32 + (m - 128)] = v;
                }
            }
        }
    }
}

// ---------------------------------------------------------------------------
__global__ __launch_bounds__(256)
void cvt_bf16(const float* __restrict__ in, __bf16* __restrict__ out, int n8)
{
    const int i = blockIdx.x * 256 + threadIdx.x;
    if (i >= n8) return;
    const size_t base = (size_t)i * 8;
    const float4 a = *(const float4*)&in[base];
    const float4 b = *(const float4*)&in[base + 4];
    __align__(16) __bf16 o[8];
    o[0] = f2bf(a.x); o[1] = f2bf(a.y); o[2] = f2bf(a.z); o[3] = f2bf(a.w);
    o[4] = f2bf(b.x); o[5] = f2bf(b.y); o[6] = f2bf(b.z); o[7] = f2bf(b.w);
    *(bf16x8*)&out[base] = *(const bf16x8*)o;
}

__global__ __launch_bounds__(256)
void cvt_xproj(const float* __restrict__ in, __bf16* __restrict__ out)
{
    const int i = blockIdx.x * 256 + threadIdx.x;
    const size_t base = (size_t)i * 8;
    const int row = (int)(base >> 12);
    __align__(16) __bf16 o[8];
    if (row < 160) {
        const float4 a = *(const float4*)&in[base];
        const float4 b = *(const float4*)&in[base + 4];
        o[0] = f2bf(a.x); o[1] = f2bf(a.y); o[2] = f2bf(a.z); o[3] = f2bf(a.w);
        o[4] = f2bf(b.x); o[5] = f2bf(b.y); o[6] = f2bf(b.z); o[7] = f2bf(b.w);
    } else {
#pragma unroll
        for (int k = 0; k < 8; ++k) o[k] = f2bf(0.f);
    }
    *(bf16x8*)&out[base] = *(const bf16x8*)o;
}

// ---------------------------------------------------------------------------
__global__ __launch_bounds__(256)
void conv_silu(const float* __restrict__ x, const float* __restrict__ conv_w,
               __bf16* __restrict__ xact_bf)
{
    const size_t idx = (size_t)blockIdx.x * 256 + threadIdx.x;
    const int e = (int)(idx & (DINNER - 1));
    const int n = (int)(idx >> 12);

    const float4 w = *(const float4*)&conv_w[e * 4];
    float s = w.w * x[idx];
    if (n >= 2) s += w.z * x[idx - (size_t)2 * DINNER];
    if (n >= 4) s += w.y * x[idx - (size_t)4 * DINNER];
    if (n >= 6) s += w.x * x[idx - (size_t)6 * DINNER];
    const float v = s / (1.f + __expf(-s));
    xact_bf[idx] = f2bf(v);
}

// ---------------------------------------------------------------------------
// Chunked selective scan (unchanged).
// ---------------------------------------------------------------------------
__global__ __launch_bounds__(256)
void scan_partial(const float* __restrict__ delta, const __bf16* __restrict__ u,
                  const float* __restrict__ xbc, const float* __restrict__ A_log,
                  float2* __restrict__ PS)
{
    const int e     = blockIdx.x * 256 + threadIdx.x;
    const int chunk = blockIdx.y;
    const int b     = blockIdx.z;

    __shared__ float BC[CHUNK][32];
    for (int i = threadIdx.x; i < CHUNK * 32; i += 256) {
        const int ll = i >> 5, f = i & 31;
        BC[ll][f] = xbc[(size_t)((chunk * CHUNK + ll) * BATCH + b) * 32 + f];
    }

    float Av[16];
#pragma unroll
    for (int s = 0; s < 16; s += 4) {
        float4 tv = *(const float4*)&A_log[e * 16 + s];
        Av[s] = -__expf(tv.x); Av[s + 1] = -__expf(tv.y);
        Av[s + 2] = -__expf(tv.z); Av[s + 3] = -__expf(tv.w);
    }
    __syncthreads();

    float P[16], S[16];
#pragma unroll
    for (int s = 0; s < 16; ++s) { P[s] = 1.f; S[s] = 0.f; }

#pragma unroll 4
    for (int ll = 0; ll < CHUNK; ++ll) {
        const int tok = (chunk * CHUNK + ll) * BATCH + b;
        const size_t ce = (size_t)tok * DINNER + e;
        const float dl = delta[ce];
        const float du = dl * (float)u[ce];
#pragma unroll
        for (int s = 0; s < 16; ++s) {
            const float dA = __expf(dl * Av[s]);
            S[s] = fmaf(dA, S[s], du * BC[ll][s]);
            P[s] *= dA;
        }
    }

    float2* outp = PS + ((size_t)(chunk * BATCH + b) * DINNER + e) * 16;
#pragma unroll
    for (int s = 0; s < 16; ++s) outp[s] = make_float2(P[s], S[s]);
}

__global__ __launch_bounds__(256)
void scan_combine(const float2* __restrict__ PS, float* __restrict__ Hinit)
{
    const size_t pos = (size_t)blockIdx.x * 256 + threadIdx.x;
    const size_t stride = (size_t)BATCH * DINNER * 16;
    float h = 0.f;
#pragma unroll
    for (int c = 0; c < NCHUNK; ++c) {
        Hinit[c * stride + pos] = h;
        const float2 ps = PS[c * stride + pos];
        h = fmaf(ps.x, h, ps.y);
    }
}

__global__ __launch_bounds__(256)
void scan_final(const float* __restrict__ delta, const __bf16* __restrict__ u,
                const float* __restrict__ xbc, const float* __restrict__ Hinit,
                const __bf16* __restrict__ z_bf, __bf16* __restrict__ y_bf,
                const float* __restrict__ A_log, const float* __restrict__ Dvec)
{
    const int e     = blockIdx.x * 256 + threadIdx.x;
    const int chunk = blockIdx.y;
    const int b     = blockIdx.z;

    __shared__ float BC[CHUNK][32];
    for (int i = threadIdx.x; i < CHUNK * 32; i += 256) {
        const int ll = i >> 5, f = i & 31;
        BC[ll][f] = xbc[(size_t)((chunk * CHUNK + ll) * BATCH + b) * 32 + f];
    }

    float Av[16];
#pragma unroll
    for (int s = 0; s < 16; s += 4) {
        float4 tv = *(const float4*)&A_log[e * 16 + s];
        Av[s] = -__expf(tv.x); Av[s + 1] = -__expf(tv.y);
        Av[s + 2] = -__expf(tv.z); Av[s + 3] = -__expf(tv.w);
    }
    const float Dv = Dvec[e];

    float h[16];
    const float* hi = Hinit + (size_t)chunk * BATCH * DINNER * 16
                            + ((size_t)b * DINNER + e) * 16;
#pragma unroll
    for (int s = 0; s < 16; s += 4) *(float4*)&h[s] = *(const float4*)&hi[s];
    __syncthreads();

#pragma unroll 2
    for (int ll = 0; ll < CHUNK; ++ll) {
        const int tok = (chunk * CHUNK + ll) * BATCH + b;
        const size_t ce = (size_t)tok * DINNER + e;
        const float dl = delta[ce];
        const float ul = (float)u[ce];
        const float du = dl * ul;
        float y = 0.f;
#pragma unroll
        for (int s = 0; s < 16; ++s) {
            const float dA = __expf(dl * Av[s]);
            h[s] = fmaf(dA, h[s], du * BC[ll][s]);
            y = fmaf(h[s], BC[ll][16 + s], y);
        }
        const float zl = (float)z_bf[ce];
        const float sig = 1.f / (1.f + __expf(-zl));
        y_bf[ce] = f2bf((y + ul * Dv) * (zl * sig));
    }
}

// ---------------------------------------------------------------------------
extern "C" void kernel_launch(void* const* d_in, const int* in_sizes, int n_in,
                              void* d_out, int out_size, void* d_ws, size_t ws_size,
                              hipStream_t stream)
{
    const float* hidden    = (const float*)d_in[0];
    const float* in_proj_w = (const float*)d_in[1];
    const float* conv_w    = (const float*)d_in[2];
    const float* x_proj_w  = (const float*)d_in[3];
    const float* dt_proj_w = (const float*)d_in[4];
    const float* dt_proj_b = (const float*)d_in[5];
    const float* A_log     = (const float*)d_in[6];
    const float* Dvec      = (const float*)d_in[7];
    const float* out_proj_w= (const float*)d_in[8];
    float* out = (float*)d_out;

    // -------- workspace (identical layout/total to R7's passing run)
    char* p = (char*)d_ws;
    const size_t NBIG = (size_t)NTOK * DINNER;
    float*  xbuf    = (float*)p;    p += NBIG * 4;                        // x -> delta
    __bf16* z_bf    = (__bf16*)p;   p += NBIG * 2;                        // z
    __bf16* xact_bf = (__bf16*)p;   p += NBIG * 2;                        // u
    __bf16* dtr_bf  = (__bf16*)p;   p += (size_t)NTOK * 128 * 2;         // dt_r (bf16)
    float*  xbc     = (float*)p;    p += (size_t)NTOK * 32 * 4;          // B|C (fp32)
    __bf16* w_xp_bf = (__bf16*)p;   p += (size_t)256 * DINNER * 2;
    __bf16* w_out_bf= (__bf16*)p;   p += (size_t)DMODEL * DINNER * 2;
    char*   G       = p;            p += (size_t)2 * DINNER * DMODEL * 2; // 33.5 MB, multi-use
    __bf16* hid_bf  = (__bf16*)p;   p += (size_t)NTOK * DMODEL * 2;
    __bf16* y_bf    = (__bf16*)p;   p += NBIG * 2;
    __bf16* dtw_bf  = (__bf16*)p;   p += (size_t)DINNER * DTRANK * 2;
    const size_t required = (size_t)(p - (char*)d_ws);
    if (ws_size < required) return;

    // G region lifetime: w_in_bf (steps 0-1) -> PS+Hinit (step 5) -> Cpart (step 6)
    __bf16* w_in_bf = (__bf16*)G;
    float2* PS      = (float2*)G;
    float*  Hinit   = (float*)(G + (size_t)NCHUNK * BATCH * DINNER * 16 * 8);
    float*  Cpart   = (float*)G;                                          // 33.5 MB exactly

    // 0) conversions
    cvt_bf16<<<(int)(NTOK * DMODEL / 2048), 256, 0, stream>>>(hidden, hid_bf, NTOK * DMODEL / 8);
    cvt_bf16<<<(int)(2 * DINNER * DMODEL / 2048), 256, 0, stream>>>(in_proj_w, w_in_bf, 2 * DINNER * DMODEL / 8);
    cvt_bf16<<<(int)(DMODEL * DINNER / 2048), 256, 0, stream>>>(out_proj_w, w_out_bf, DMODEL * DINNER / 8);
    cvt_bf16<<<(int)(DINNER * DTRANK / 2048), 256, 0, stream>>>(dt_proj_w, dtw_bf, DINNER * DTRANK / 8);
    cvt_xproj<<<(int)(256 * DINNER / 2048), 256, 0, stream>>>(x_proj_w, w_xp_bf);

    // 1) in_proj (256^2 fine-grained 4-phase): x (fp32) | z (bf16). grid 512 (%8==0)
    gemm8<0><<<(2 * DINNER / 256) * (NTOK / 256), 512, 0, stream>>>(
        w_in_bf, hid_bf, xbuf, z_bf, nullptr, DMODEL, DMODEL, DMODEL, DINNER,
        NTOK / 256, (2 * DINNER / 256) * (NTOK / 256));

    // 2) conv + silu -> u (bf16)
    conv_silu<<<(int)(NBIG / 256), 256, 0, stream>>>(xbuf, conv_w, xact_bf);

    // 3) x_proj (128^2): dt_r -> bf16, B|C -> fp32 compact
    gemm_bf16<3><<<dim3(NTOK / 128, 2), 256, 0, stream>>>(
        w_xp_bf, xact_bf, xbc, dtr_bf, nullptr, 160, DINNER, DINNER, DINNER, 0);

    // 4) dt_proj (128^2, K=128) + softplus -> delta (over xbuf)
    gemm_bf16<2><<<dim3(NTOK / 128, DINNER / 128), 256, 0, stream>>>(
        dtw_bf, dtr_bf, xbuf, nullptr, dt_proj_b, DINNER, DTRANK, DTRANK, DTRANK, DINNER);

    // 5) chunked scan (PS/Hinit overwrite w_in_bf — dead after step 1)
    scan_partial<<<dim3(DINNER / 256, NCHUNK, BATCH), 256, 0, stream>>>(
        xbuf, xact_bf, xbc, A_log, PS);
    scan_combine<<<(BATCH * DINNER * 16) / 256, 256, 0, stream>>>(PS, Hinit);
    scan_final<<<dim3(DINNER / 256, NCHUNK, BATCH), 256, 0, stream>>>(
        xbuf, xact_bf, xbc, Hinit, z_bf, y_bf, A_log, Dvec);

    // 6) out_proj: deterministic split-K=2 (slice0 -> out, slice1 -> Cpart),
    //    then out += Cpart.  grid 256 (%8==0), no atomics.
    gemm8<3><<<(DMODEL / 256) * (NTOK / 256) * 2, 512, 0, stream>>>(
        w_out_bf, y_bf, out, nullptr, Cpart, DINNER / 2, DINNER, DINNER, DMODEL,
        NTOK / 256, (DMODEL / 256) * (NTOK / 256));
    addout<<<(NTOK * DMODEL / 4 + 255) / 256, 256, 0, stream>>>(
        out, Cpart, NTOK * DMODEL / 4);
}

// Round 9
// 718.208 us; speedup vs baseline: 1.2662x; 1.0051x over previous
//
#include <hip/hip_runtime.h>
#include <hip/hip_bf16.h>
#include <math.h>

#define L_SEQ   2048
#define BATCH   2
#define DMODEL  2048
#define DINNER  4096
#define DSTATE  16
#define DTRANK  128
#define NTOK    (L_SEQ * BATCH)   // 4096
#define CHUNK   128
#define NCHUNK  (L_SEQ / CHUNK)   // 16

typedef __attribute__((ext_vector_type(8))) __bf16 bf16x8;
typedef __attribute__((ext_vector_type(4))) float f32x4;

__device__ __forceinline__ __bf16 f2bf(float f) {
    unsigned u = __builtin_bit_cast(unsigned, f);
    unsigned r = (u + 0x7FFFu + ((u >> 16) & 1u)) >> 16;
    return __builtin_bit_cast(__bf16, (unsigned short)r);
}

__device__ __forceinline__ void load_lds16(const void* gsrc, void* lds) {
    __builtin_amdgcn_global_load_lds(
        (const __attribute__((address_space(1))) unsigned int*)gsrc,
        (__attribute__((address_space(3))) unsigned int*)lds, 16, 0, 0);
}

// Stage one 128x64 bf16 half-tile (16 KiB) with 512 threads x 2 loads.
// LDS dest LINEAR; SOURCE column inverse-swizzled (rule 21: both-sides).
__device__ __forceinline__ void stage_half(const __bf16* g, int ld,
                                           __bf16* lh, int trow, int tcol8, int scol)
{
    load_lds16(g + (size_t)trow        * ld + scol, lh +  trow       * 64 + tcol8);
    load_lds16(g + (size_t)(trow + 64) * ld + scol, lh + (trow + 64) * 64 + tcol8);
}

// ---------------------------------------------------------------------------
// 256x256 bf16 MFMA GEMM, 4-phase schedule with EARLY staging.
// C[m][n] = sum_k A[m][k]*Bt[n][k].  512 thr = 8 waves (2M x 4N).
// Wave (wm,wn): rows wm*128..+127; cols {wn*32..+31} in EACH B-half.
// Per K-tile tt (buffer cur=tt&1):
//   q0: read A-h0(8)+B0(4); stage Ah0',Ah1' (tt+1);  16 MFMA acc[0..3][0..1]
//   q1: bar; read B1(4);    stage Bh0',Bh1' (tt+1);  16 MFMA acc[0..3][2..3]
//   q2: bar; read A-h1(8);                           16 MFMA acc[4..7][0..1]
//   q3: bar;                (all held)               16 MFMA acc[4..7][2..3]
//   boundary: vmcnt(0); bar  -- youngest outstanding load was issued at q1,
//   ~2.5 phases (>1200cyc) earlier: HBM latency fully covered, no drain harm.
// Buffer hazard: tt+1's stages write buf(1-cur), last read by tile tt-1 and
// fenced by the previous boundary barrier.
// LDS: 2 x {A-h0,A-h1,B-h0,B-h1} x 16KiB = 128 KiB.
// MODE 0: m<DINNER -> C0 fp32; else C1b bf16 (ldc=DINNER)            [in_proj]
// MODE 3: split-K deterministic: kslice0 -> C0, kslice1 -> Cpart     [out_proj]
// ---------------------------------------------------------------------------
template <int MODE>
__global__ __launch_bounds__(512, 1)
void gemm8(const __bf16* __restrict__ A, const __bf16* __restrict__ Bt,
           float* __restrict__ C0, __bf16* __restrict__ C1b,
           float* __restrict__ Cpart,
           int Kper, int lda, int ldb, int ldc, int nbn, int ntile)
{
    __shared__ __align__(16) __bf16 lds8[2 * 4 * 8192];   // 128 KiB

    const int t = threadIdx.x;
    const int nwg = gridDim.x;                       // multiple of 8
    const int swz = ((int)blockIdx.x & 7) * (nwg >> 3) + ((int)blockIdx.x >> 3);
    const int kslice = swz / ntile;
    const int tl     = swz - kslice * ntile;
    const int m0 = (tl / nbn) * 256;
    const int n0 = (tl % nbn) * 256;
    const int kofs = kslice * Kper;

    const int l      = t & 63;
    const int w      = t >> 6;
    const int wm     = w >> 2;        // 0..1
    const int wn     = w & 3;         // 0..3
    const int lane15 = l & 15;
    const int lhi    = l >> 4;        // 0..3
    const int trow   = t >> 3;        // 0..63
    const int tcol8  = (t & 7) * 8;
    const int scol   = tcol8 ^ ((trow & 7) << 3);

    const __bf16* Ah0 = A  + (size_t)m0 * lda + kofs;
    const __bf16* Ah1 = A  + (size_t)(m0 + 128) * lda + kofs;
    const __bf16* Bh0 = Bt + (size_t)n0 * ldb + kofs;
    const __bf16* Bh1 = Bt + (size_t)(n0 + 128) * ldb + kofs;

    const int NT = Kper >> 6;

    f32x4 acc[8][4];
#pragma unroll
    for (int i = 0; i < 8; ++i)
#pragma unroll
        for (int j = 0; j < 4; ++j) acc[i][j] = (f32x4){0.f, 0.f, 0.f, 0.f};

    // ---- prologue: stage tile0's 4 halves (8 ops/thread)
    stage_half(Ah0, lda, lds8 + 0 * 8192, trow, tcol8, scol);
    stage_half(Ah1, lda, lds8 + 1 * 8192, trow, tcol8, scol);
    stage_half(Bh0, ldb, lds8 + 2 * 8192, trow, tcol8, scol);
    stage_half(Bh1, ldb, lds8 + 3 * 8192, trow, tcol8, scol);
    asm volatile("s_waitcnt vmcnt(0)" ::: "memory");
    __builtin_amdgcn_s_barrier();
    asm volatile("" ::: "memory");

    for (int tt = 0; tt < NT; ++tt) {
        const int cur = tt & 1;
        const __bf16* LA  = lds8 + (cur * 4 + wm) * 8192;
        const __bf16* LB0 = lds8 + (cur * 4 + 2) * 8192;
        const __bf16* LB1 = lds8 + (cur * 4 + 3) * 8192;
        __bf16* nxt = lds8 + ((1 - cur) * 4) * 8192;
        const bool stg = (tt + 1 < NT);
        const int  knx = (tt + 1) << 6;

        bf16x8 aK0[4], aK1[4], bK0[2][2], bK1[2][2];   // b[bhalf][j]

        // ---------- phase 0: A rows-half0 + B-half0 -> acc[0..3][0..1]
#pragma unroll
        for (int i = 0; i < 4; ++i) {
            const int lr = i * 16 + lane15;
            const int sw = (lr & 7) << 3;
            aK0[i] = *(const bf16x8*)&LA[lr * 64 + ((lhi * 8) ^ sw)];
            aK1[i] = *(const bf16x8*)&LA[lr * 64 + ((32 + lhi * 8) ^ sw)];
        }
#pragma unroll
        for (int j = 0; j < 2; ++j) {
            const int lr = wn * 32 + j * 16 + lane15;
            const int sw = (lr & 7) << 3;
            bK0[0][j] = *(const bf16x8*)&LB0[lr * 64 + ((lhi * 8) ^ sw)];
            bK1[0][j] = *(const bf16x8*)&LB0[lr * 64 + ((32 + lhi * 8) ^ sw)];
        }
        if (stg) {   // EARLY: tile tt+1's A-halves
            stage_half(Ah0 + knx, lda, nxt + 0 * 8192, trow, tcol8, scol);
            stage_half(Ah1 + knx, lda, nxt + 1 * 8192, trow, tcol8, scol);
        }
        __builtin_amdgcn_s_setprio(1);
#pragma unroll
        for (int i = 0; i < 4; ++i)
#pragma unroll
            for (int j = 0; j < 2; ++j) {
                acc[i][j] = __builtin_amdgcn_mfma_f32_16x16x32_bf16(
                    aK0[i], bK0[0][j], acc[i][j], 0, 0, 0);
                acc[i][j] = __builtin_amdgcn_mfma_f32_16x16x32_bf16(
                    aK1[i], bK1[0][j], acc[i][j], 0, 0, 0);
            }
        __builtin_amdgcn_s_setprio(0);

        // ---------- phase 1: B-half1 -> acc[0..3][2..3]
        __builtin_amdgcn_s_barrier();
        asm volatile("" ::: "memory");
#pragma unroll
        for (int j = 0; j < 2; ++j) {
            const int lr = wn * 32 + j * 16 + lane15;
            const int sw = (lr & 7) << 3;
            bK0[1][j] = *(const bf16x8*)&LB1[lr * 64 + ((lhi * 8) ^ sw)];
            bK1[1][j] = *(const bf16x8*)&LB1[lr * 64 + ((32 + lhi * 8) ^ sw)];
        }
        if (stg) {   // EARLY: tile tt+1's B-halves
            stage_half(Bh0 + knx, ldb, nxt + 2 * 8192, trow, tcol8, scol);
            stage_half(Bh1 + knx, ldb, nxt + 3 * 8192, trow, tcol8, scol);
        }
        __builtin_amdgcn_s_setprio(1);
#pragma unroll
        for (int i = 0; i < 4; ++i)
#pragma unroll
            for (int j = 0; j < 2; ++j) {
                acc[i][2 + j] = __builtin_amdgcn_mfma_f32_16x16x32_bf16(
                    aK0[i], bK0[1][j], acc[i][2 + j], 0, 0, 0);
                acc[i][2 + j] = __builtin_amdgcn_mfma_f32_16x16x32_bf16(
                    aK1[i], bK1[1][j], acc[i][2 + j], 0, 0, 0);
            }
        __builtin_amdgcn_s_setprio(0);

        // ---------- phase 2: A rows-half1 (B0 held) -> acc[4..7][0..1]
        __builtin_amdgcn_s_barrier();
        asm volatile("" ::: "memory");
#pragma unroll
        for (int i = 0; i < 4; ++i) {
            const int lr = 64 + i * 16 + lane15;
            const int sw = (lr & 7) << 3;
            aK0[i] = *(const bf16x8*)&LA[lr * 64 + ((lhi * 8) ^ sw)];
            aK1[i] = *(const bf16x8*)&LA[lr * 64 + ((32 + lhi * 8) ^ sw)];
        }
        __builtin_amdgcn_s_setprio(1);
#pragma unroll
        for (int i = 0; i < 4; ++i)
#pragma unroll
            for (int j = 0; j < 2; ++j) {
                acc[4 + i][j] = __builtin_amdgcn_mfma_f32_16x16x32_bf16(
                    aK0[i], bK0[0][j], acc[4 + i][j], 0, 0, 0);
                acc[4 + i][j] = __builtin_amdgcn_mfma_f32_16x16x32_bf16(
                    aK1[i], bK1[0][j], acc[4 + i][j], 0, 0, 0);
            }
        __builtin_amdgcn_s_setprio(0);

        // ---------- phase 3: all operands held -> acc[4..7][2..3]
        __builtin_amdgcn_s_barrier();
        asm volatile("" ::: "memory");
        __builtin_amdgcn_s_setprio(1);
#pragma unroll
        for (int i = 0; i < 4; ++i)
#pragma unroll
            for (int j = 0; j < 2; ++j) {
                acc[4 + i][2 + j] = __builtin_amdgcn_mfma_f32_16x16x32_bf16(
                    aK0[i], bK0[1][j], acc[4 + i][2 + j], 0, 0, 0);
                acc[4 + i][2 + j] = __builtin_amdgcn_mfma_f32_16x16x32_bf16(
                    aK1[i], bK1[1][j], acc[4 + i][2 + j], 0, 0, 0);
            }
        __builtin_amdgcn_s_setprio(0);

        // ---------- tile boundary: all of tile tt+1 staged long ago
        if (tt + 1 < NT) {
            asm volatile("s_waitcnt vmcnt(0)" ::: "memory");
            __builtin_amdgcn_s_barrier();
            asm volatile("" ::: "memory");
        }
    }

    // ---- epilogue (cols: wave strip in each B-half)
    const int rbase = lhi * 4;
    float* const dst = (MODE == 3) ? (kslice ? Cpart : C0) : C0;
#pragma unroll
    for (int fi = 0; fi < 8; ++fi) {
#pragma unroll
        for (int fj = 0; fj < 4; ++fj) {
            const int n = n0 + (fj >> 1) * 128 + wn * 32 + (fj & 1) * 16 + lane15;
#pragma unroll
            for (int r = 0; r < 4; ++r) {
                const int m = m0 + wm * 128 + fi * 16 + rbase + r;
                const float v = acc[fi][fj][r];
                if constexpr (MODE == 0) {
                    if (m < DINNER) C0[(size_t)n * DINNER + m] = v;
                    else            C1b[(size_t)n * DINNER + (m - DINNER)] = f2bf(v);
                } else {
                    dst[(size_t)n * ldc + m] = v;
                }
            }
        }
    }
}

// out += part  (split-K reduction, no atomics)
__global__ __launch_bounds__(256)
void addout(float* __restrict__ out, const float* __restrict__ part, int n4)
{
    const int i = blockIdx.x * 256 + threadIdx.x;
    if (i >= n4) return;
    float4 a = *(const float4*)&out[(size_t)i * 4];
    const float4 b = *(const float4*)&part[(size_t)i * 4];
    a.x += b.x; a.y += b.y; a.z += b.z; a.w += b.w;
    *(float4*)&out[(size_t)i * 4] = a;
}

// ---------------------------------------------------------------------------
// m97-style 128x128 bf16 MFMA GEMM (small GEMMs: x_proj, dt_proj).
// MODE 2: softplus(v + bias[m]) -> C1b bf16 [n*ldc+m]        [dt_proj]
// MODE 3: m<128 -> C1b bf16 [n*128+m]; 128<=m<160 -> C0 fp32 [n*32+m-128]
// ---------------------------------------------------------------------------
template <int MODE>
__global__ __launch_bounds__(256)
void gemm_bf16(const __bf16* __restrict__ A, const __bf16* __restrict__ Bt,
               float* __restrict__ C0, __bf16* __restrict__ C1b,
               const float* __restrict__ bias,
               int Mvalid, int K, int lda, int ldb, int ldc)
{
    __shared__ __align__(16) __bf16 As[128 * 64];
    __shared__ __align__(16) __bf16 Bs[128 * 64];

    const int t  = threadIdx.x;
    const int m0 = blockIdx.y * 128;
    const int n0 = blockIdx.x * 128;
    const int l  = t & 63;
    const int w  = t >> 6;
    const int wr = (w >> 1) * 64;
    const int wc = (w & 1) * 64;
    const int lrow = t >> 3;
    const int lk   = (t & 7) * 8;

    f32x4 acc[4][4];
#pragma unroll
    for (int i = 0; i < 4; ++i)
#pragma unroll
        for (int j = 0; j < 4; ++j) acc[i][j] = (f32x4){0.f, 0.f, 0.f, 0.f};

    for (int k0 = 0; k0 < K; k0 += 64) {
#pragma unroll
        for (int q = 0; q < 4; ++q) {
            const int row = q * 32 + lrow;
            load_lds16(A  + (size_t)(m0 + row) * lda + k0 + lk, &As[row * 64 + lk]);
            load_lds16(Bt + (size_t)(n0 + row) * ldb + k0 + lk, &Bs[row * 64 + lk]);
        }
        __syncthreads();

#pragma unroll
        for (int kk = 0; kk < 2; ++kk) {
            const int krd = kk * 32 + (l >> 4) * 8;
            bf16x8 a[4], b[4];
#pragma unroll
            for (int i = 0; i < 4; ++i) {
                a[i] = *(const bf16x8*)&As[(wr + i * 16 + (l & 15)) * 64 + krd];
                b[i] = *(const bf16x8*)&Bs[(wc + i * 16 + (l & 15)) * 64 + krd];
            }
#pragma unroll
            for (int i = 0; i < 4; ++i)
#pragma unroll
                for (int j = 0; j < 4; ++j)
                    acc[i][j] = __builtin_amdgcn_mfma_f32_16x16x32_bf16(
                        a[i], b[j], acc[i][j], 0, 0, 0);
        }
        __syncthreads();
    }

    const int rbase = (l >> 4) * 4;
    const int cbase = l & 15;
#pragma unroll
    for (int i = 0; i < 4; ++i) {
#pragma unroll
        for (int j = 0; j < 4; ++j) {
#pragma unroll
            for (int r = 0; r < 4; ++r) {
                const int m = m0 + wr + i * 16 + rbase + r;
                const int n = n0 + wc + j * 16 + cbase;
                const float v = acc[i][j][r];
                if constexpr (MODE == 2) {
                    const float vb = v + bias[m];
                    const float sp = (vb > 20.f) ? vb : log1pf(__expf(vb));
                    C1b[(size_t)n * ldc + m] = f2bf(sp);
                } else {   // MODE 3
                    if (m < 128)      C1b[(size_t)n * 128 + m] = f2bf(v);
                    else if (m < 160) C0[(size_t)n * 32 + (m - 128)] = v;
                }
            }
        }
    }
}

// ---------------------------------------------------------------------------
// Fused fp32->bf16 conversions for all 5 buffers (one launch).
// Segment sizes in 8-elem units; all segment boundaries are block-aligned.
// ---------------------------------------------------------------------------
#define CS0 (NTOK * DMODEL / 8)        // hidden      1048576
#define CS1 (2 * DINNER * DMODEL / 8)  // in_proj_w   2097152
#define CS2 (DMODEL * DINNER / 8)      // out_proj_w  1048576
#define CS3 (DINNER * DTRANK / 8)      // dt_proj_w     65536
#define CS4 (256 * DINNER / 8)         // x_proj pad   131072
#define CTOT (CS0 + CS1 + CS2 + CS3 + CS4)

__global__ __launch_bounds__(256)
void cvt_all(const float* __restrict__ hidden, const float* __restrict__ w_in,
             const float* __restrict__ w_out, const float* __restrict__ w_dt,
             const float* __restrict__ w_xp,
             __bf16* __restrict__ hid_bf, __bf16* __restrict__ w_in_bf,
             __bf16* __restrict__ w_out_bf, __bf16* __restrict__ dtw_bf,
             __bf16* __restrict__ w_xp_bf)
{
    const int i = blockIdx.x * 256 + threadIdx.x;
    const float* src; __bf16* dst; int off;
    if (i < CS0)                    { src = hidden; dst = hid_bf;  off = i; }
    else if (i < CS0 + CS1)         { src = w_in;   dst = w_in_bf; off = i - CS0; }
    else if (i < CS0 + CS1 + CS2)   { src = w_out;  dst = w_out_bf; off = i - (CS0 + CS1); }
    else if (i < CS0 + CS1 + CS2 + CS3) { src = w_dt; dst = dtw_bf; off = i - (CS0 + CS1 + CS2); }
    else {
        off = i - (CS0 + CS1 + CS2 + CS3);
        const int row = off >> 9;                    // off*8 / 4096
        __align__(16) __bf16 o[8];
        if (row < 160) {
            const size_t base = (size_t)off * 8;
            const float4 a = *(const float4*)&w_xp[base];
            const float4 b = *(const float4*)&w_xp[base + 4];
            o[0] = f2bf(a.x); o[1] = f2bf(a.y); o[2] = f2bf(a.z); o[3] = f2bf(a.w);
            o[4] = f2bf(b.x); o[5] = f2bf(b.y); o[6] = f2bf(b.z); o[7] = f2bf(b.w);
        } else {
#pragma unroll
            for (int k = 0; k < 8; ++k) o[k] = f2bf(0.f);
        }
        *(bf16x8*)&w_xp_bf[(size_t)off * 8] = *(const bf16x8*)o;
        return;
    }
    const size_t base = (size_t)off * 8;
    const float4 a = *(const float4*)&src[base];
    const float4 b = *(const float4*)&src[base + 4];
    __align__(16) __bf16 o[8];
    o[0] = f2bf(a.x); o[1] = f2bf(a.y); o[2] = f2bf(a.z); o[3] = f2bf(a.w);
    o[4] = f2bf(b.x); o[5] = f2bf(b.y); o[6] = f2bf(b.z); o[7] = f2bf(b.w);
    *(bf16x8*)&dst[base] = *(const bf16x8*)o;
}

// ---------------------------------------------------------------------------
__global__ __launch_bounds__(256)
void conv_silu(const float* __restrict__ x, const float* __restrict__ conv_w,
               __bf16* __restrict__ xact_bf)
{
    const size_t idx = (size_t)blockIdx.x * 256 + threadIdx.x;
    const int e = (int)(idx & (DINNER - 1));
    const int n = (int)(idx >> 12);

    const float4 w = *(const float4*)&conv_w[e * 4];
    float s = w.w * x[idx];
    if (n >= 2) s += w.z * x[idx - (size_t)2 * DINNER];
    if (n >= 4) s += w.y * x[idx - (size_t)4 * DINNER];
    if (n >= 6) s += w.x * x[idx - (size_t)6 * DINNER];
    const float v = s / (1.f + __expf(-s));
    xact_bf[idx] = f2bf(v);
}

// ---------------------------------------------------------------------------
// Chunked selective scan (delta now bf16).
// ---------------------------------------------------------------------------
__global__ __launch_bounds__(256)
void scan_partial(const __bf16* __restrict__ delta, const __bf16* __restrict__ u,
                  const float* __restrict__ xbc, const float* __restrict__ A_log,
                  float2* __restrict__ PS)
{
    const int e     = blockIdx.x * 256 + threadIdx.x;
    const int chunk = blockIdx.y;
    const int b     = blockIdx.z;

    __shared__ float BC[CHUNK][32];
    for (int i = threadIdx.x; i < CHUNK * 32; i += 256) {
        const int ll = i >> 5, f = i & 31;
        BC[ll][f] = xbc[(size_t)((chunk * CHUNK + ll) * BATCH + b) * 32 + f];
    }

    float Av[16];
#pragma unroll
    for (int s = 0; s < 16; s += 4) {
        float4 tv = *(const float4*)&A_log[e * 16 + s];
        Av[s] = -__expf(tv.x); Av[s + 1] = -__expf(tv.y);
        Av[s + 2] = -__expf(tv.z); Av[s + 3] = -__expf(tv.w);
    }
    __syncthreads();

    float P[16], S[16];
#pragma unroll
    for (int s = 0; s < 16; ++s) { P[s] = 1.f; S[s] = 0.f; }

#pragma unroll 4
    for (int ll = 0; ll < CHUNK; ++ll) {
        const int tok = (chunk * CHUNK + ll) * BATCH + b;
        const size_t ce = (size_t)tok * DINNER + e;
        const float dl = (float)delta[ce];
        const float du = dl * (float)u[ce];
#pragma unroll
        for (int s = 0; s < 16; ++s) {
            const float dA = __expf(dl * Av[s]);
            S[s] = fmaf(dA, S[s], du * BC[ll][s]);
            P[s] *= dA;
        }
    }

    float2* outp = PS + ((size_t)(chunk * BATCH + b) * DINNER + e) * 16;
#pragma unroll
    for (int s = 0; s < 16; ++s) outp[s] = make_float2(P[s], S[s]);
}

__global__ __launch_bounds__(256)
void scan_combine(const float2* __restrict__ PS, float* __restrict__ Hinit)
{
    const size_t pos = (size_t)blockIdx.x * 256 + threadIdx.x;
    const size_t stride = (size_t)BATCH * DINNER * 16;
    float h = 0.f;
#pragma unroll
    for (int c = 0; c < NCHUNK; ++c) {
        Hinit[c * stride + pos] = h;
        const float2 ps = PS[c * stride + pos];
        h = fmaf(ps.x, h, ps.y);
    }
}

__global__ __launch_bounds__(256)
void scan_final(const __bf16* __restrict__ delta, const __bf16* __restrict__ u,
                const float* __restrict__ xbc, const float* __restrict__ Hinit,
                const __bf16* __restrict__ z_bf, __bf16* __restrict__ y_bf,
                const float* __restrict__ A_log, const float* __restrict__ Dvec)
{
    const int e     = blockIdx.x * 256 + threadIdx.x;
    const int chunk = blockIdx.y;
    const int b     = blockIdx.z;

    __shared__ float BC[CHUNK][32];
    for (int i = threadIdx.x; i < CHUNK * 32; i += 256) {
        const int ll = i >> 5, f = i & 31;
        BC[ll][f] = xbc[(size_t)((chunk * CHUNK + ll) * BATCH + b) * 32 + f];
    }

    float Av[16];
#pragma unroll
    for (int s = 0; s < 16; s += 4) {
        float4 tv = *(const float4*)&A_log[e * 16 + s];
        Av[s] = -__expf(tv.x); Av[s + 1] = -__expf(tv.y);
        Av[s + 2] = -__expf(tv.z); Av[s + 3] = -__expf(tv.w);
    }
    const float Dv = Dvec[e];

    float h[16];
    const float* hi = Hinit + (size_t)chunk * BATCH * DINNER * 16
                            + ((size_t)b * DINNER + e) * 16;
#pragma unroll
    for (int s = 0; s < 16; s += 4) *(float4*)&h[s] = *(const float4*)&hi[s];
    __syncthreads();

#pragma unroll 2
    for (int ll = 0; ll < CHUNK; ++ll) {
        const int tok = (chunk * CHUNK + ll) * BATCH + b;
        const size_t ce = (size_t)tok * DINNER + e;
        const float dl = (float)delta[ce];
        const float ul = (float)u[ce];
        const float du = dl * ul;
        float y = 0.f;
#pragma unroll
        for (int s = 0; s < 16; ++s) {
            const float dA = __expf(dl * Av[s]);
            h[s] = fmaf(dA, h[s], du * BC[ll][s]);
            y = fmaf(h[s], BC[ll][16 + s], y);
        }
        const float zl = (float)z_bf[ce];
        const float sig = 1.f / (1.f + __expf(-zl));
        y_bf[ce] = f2bf((y + ul * Dv) * (zl * sig));
    }
}

// ---------------------------------------------------------------------------
extern "C" void kernel_launch(void* const* d_in, const int* in_sizes, int n_in,
                              void* d_out, int out_size, void* d_ws, size_t ws_size,
                              hipStream_t stream)
{
    const float* hidden    = (const float*)d_in[0];
    const float* in_proj_w = (const float*)d_in[1];
    const float* conv_w    = (const float*)d_in[2];
    const float* x_proj_w  = (const float*)d_in[3];
    const float* dt_proj_w = (const float*)d_in[4];
    const float* dt_proj_b = (const float*)d_in[5];
    const float* A_log     = (const float*)d_in[6];
    const float* Dvec      = (const float*)d_in[7];
    const float* out_proj_w= (const float*)d_in[8];
    float* out = (float*)d_out;

    // -------- workspace (identical layout/total to R7/R8 passing runs)
    char* p = (char*)d_ws;
    const size_t NBIG = (size_t)NTOK * DINNER;
    float*  xbuf    = (float*)p;    p += NBIG * 4;                        // x -> delta(bf16)
    __bf16* z_bf    = (__bf16*)p;   p += NBIG * 2;                        // z
    __bf16* xact_bf = (__bf16*)p;   p += NBIG * 2;                        // u
    __bf16* dtr_bf  = (__bf16*)p;   p += (size_t)NTOK * 128 * 2;         // dt_r (bf16)
    float*  xbc     = (float*)p;    p += (size_t)NTOK * 32 * 4;          // B|C (fp32)
    __bf16* w_xp_bf = (__bf16*)p;   p += (size_t)256 * DINNER * 2;
    __bf16* w_out_bf= (__bf16*)p;   p += (size_t)DMODEL * DINNER * 2;
    char*   G       = p;            p += (size_t)2 * DINNER * DMODEL * 2; // 33.5 MB, multi-use
    __bf16* hid_bf  = (__bf16*)p;   p += (size_t)NTOK * DMODEL * 2;
    __bf16* y_bf    = (__bf16*)p;   p += NBIG * 2;
    __bf16* dtw_bf  = (__bf16*)p;   p += (size_t)DINNER * DTRANK * 2;
    const size_t required = (size_t)(p - (char*)d_ws);
    if (ws_size < required) return;

    // G region lifetime: w_in_bf (steps 0-1) -> PS+Hinit (step 5) -> Cpart (step 6)
    __bf16* w_in_bf = (__bf16*)G;
    float2* PS      = (float2*)G;
    float*  Hinit   = (float*)(G + (size_t)NCHUNK * BATCH * DINNER * 16 * 8);
    float*  Cpart   = (float*)G;
    __bf16* delta_bf= (__bf16*)xbuf;   // dt_proj output overwrites x (dead after conv)

    // 0) fused conversions (single launch)
    cvt_all<<<CTOT / 256, 256, 0, stream>>>(
        hidden, in_proj_w, out_proj_w, dt_proj_w, x_proj_w,
        hid_bf, w_in_bf, w_out_bf, dtw_bf, w_xp_bf);

    // 1) in_proj (256^2, early-staged 4-phase): x (fp32) | z (bf16). grid 512
    gemm8<0><<<(2 * DINNER / 256) * (NTOK / 256), 512, 0, stream>>>(
        w_in_bf, hid_bf, xbuf, z_bf, nullptr, DMODEL, DMODEL, DMODEL, DINNER,
        NTOK / 256, (2 * DINNER / 256) * (NTOK / 256));

    // 2) conv + silu -> u (bf16)
    conv_silu<<<(int)(NBIG / 256), 256, 0, stream>>>(xbuf, conv_w, xact_bf);

    // 3) x_proj (128^2): dt_r -> bf16, B|C -> fp32 compact
    gemm_bf16<3><<<dim3(NTOK / 128, 2), 256, 0, stream>>>(
        w_xp_bf, xact_bf, xbc, dtr_bf, nullptr, 160, DINNER, DINNER, DINNER, 0);

    // 4) dt_proj (128^2, K=128) + softplus -> delta (bf16, over xbuf)
    gemm_bf16<2><<<dim3(NTOK / 128, DINNER / 128), 256, 0, stream>>>(
        dtw_bf, dtr_bf, nullptr, delta_bf, dt_proj_b, DINNER, DTRANK, DTRANK, DTRANK, DINNER);

    // 5) chunked scan (PS/Hinit overwrite w_in_bf — dead after step 1)
    scan_partial<<<dim3(DINNER / 256, NCHUNK, BATCH), 256, 0, stream>>>(
        delta_bf, xact_bf, xbc, A_log, PS);
    scan_combine<<<(BATCH * DINNER * 16) / 256, 256, 0, stream>>>(PS, Hinit);
    scan_final<<<dim3(DINNER / 256, NCHUNK, BATCH), 256, 0, stream>>>(
        delta_bf, xact_bf, xbc, Hinit, z_bf, y_bf, A_log, Dvec);

    // 6) out_proj: deterministic split-K=2 + addout. grid 256, no atomics.
    gemm8<3><<<(DMODEL / 256) * (NTOK / 256) * 2, 512, 0, stream>>>(
        w_out_bf, y_bf, out, nullptr, Cpart, DINNER / 2, DINNER, DINNER, DMODEL,
        NTOK / 256, (DMODEL / 256) * (NTOK / 256));
    addout<<<(NTOK * DMODEL / 4 + 255) / 256, 256, 0, stream>>>(
        out, Cpart, NTOK * DMODEL / 4);
}

// Round 10
// 666.532 us; speedup vs baseline: 1.3644x; 1.0775x over previous
//
#include <hip/hip_runtime.h>
#include <hip/hip_bf16.h>
#include <math.h>

#define L_SEQ   2048
#define BATCH   2
#define DMODEL  2048
#define DINNER  4096
#define DSTATE  16
#define DTRANK  128
#define NTOK    (L_SEQ * BATCH)   // 4096
#define CHUNK   128
#define NCHUNK  (L_SEQ / CHUNK)   // 16

typedef __attribute__((ext_vector_type(8))) __bf16 bf16x8;
typedef __attribute__((ext_vector_type(4))) __bf16 bf16x4;
typedef __attribute__((ext_vector_type(4))) float f32x4;

__device__ __forceinline__ __bf16 f2bf(float f) {
    unsigned u = __builtin_bit_cast(unsigned, f);
    unsigned r = (u + 0x7FFFu + ((u >> 16) & 1u)) >> 16;
    return __builtin_bit_cast(__bf16, (unsigned short)r);
}

__device__ __forceinline__ void load_lds16(const void* gsrc, void* lds) {
    __builtin_amdgcn_global_load_lds(
        (const __attribute__((address_space(1))) unsigned int*)gsrc,
        (__attribute__((address_space(3))) unsigned int*)lds, 16, 0, 0);
}

// Stage one 128x64 bf16 half-tile (16 KiB) with 512 threads x 2 loads.
// LDS dest LINEAR; SOURCE column inverse-swizzled (rule 21: both-sides).
__device__ __forceinline__ void stage_half(const __bf16* g, int ld,
                                           __bf16* lh, int trow, int tcol8, int scol)
{
    load_lds16(g + (size_t)trow        * ld + scol, lh +  trow       * 64 + tcol8);
    load_lds16(g + (size_t)(trow + 64) * ld + scol, lh + (trow + 64) * 64 + tcol8);
}

// ---------------------------------------------------------------------------
// 256x256 bf16 MFMA GEMM, 4-phase early-staged schedule (unchanged from R9)
// with PER-XCD 8m x 4n BLOCK SWIZZLE: wg bid runs on XCD (bid&7) [T1 base];
// each XCD batch of 32 wgs covers one contiguous 8x4 tile-block, so its
// A-slice (8.4 MB) + B-slice (4.2 MB) are shared via L2/L3 instead of an
// 18.8 MB strip.  Requires nwg%256==0, ntile%32==0, nbn%4==0, (M/256)%8==0
// or covered by block decomposition (all call sites verified).
// MODE 0: m<DINNER -> C0b bf16 (x); else C1b bf16 (z); ldc=DINNER   [in_proj]
// MODE 3: split-K deterministic: kslice0 -> C0, kslice1 -> Cpart    [out_proj]
// ---------------------------------------------------------------------------
template <int MODE>
__global__ __launch_bounds__(512, 1)
void gemm8(const __bf16* __restrict__ A, const __bf16* __restrict__ Bt,
           float* __restrict__ C0, __bf16* __restrict__ C0b, __bf16* __restrict__ C1b,
           float* __restrict__ Cpart,
           int Kper, int lda, int ldb, int ldc, int nbn, int ntile)
{
    __shared__ __align__(16) __bf16 lds8[2 * 4 * 8192];   // 128 KiB

    const int t = threadIdx.x;
    // ---- XCD-block decomposition: block = 8m x 4n = 32 wgs on ONE XCD
    const int bid = (int)blockIdx.x;
    const int x   = bid & 7;            // XCD (round-robin dispatch)
    const int k   = bid >> 3;           // per-XCD sequence
    const int b   = (k >> 5) * 8 + x;   // block id (32 wgs each)
    const int sub = k & 31;             // position within block
    const int pslice = ntile >> 5;      // blocks per k-slice
    const int kslice = b / pslice;
    const int bp     = b - kslice * pslice;
    const int nblkn  = nbn >> 2;
    const int mb = bp / nblkn, nb = bp - mb * nblkn;
    const int m0 = (mb * 8 + (sub >> 2)) * 256;
    const int n0 = (nb * 4 + (sub & 3)) * 256;
    const int kofs = kslice * Kper;

    const int l      = t & 63;
    const int w      = t >> 6;
    const int wm     = w >> 2;        // 0..1
    const int wn     = w & 3;         // 0..3
    const int lane15 = l & 15;
    const int lhi    = l >> 4;        // 0..3
    const int trow   = t >> 3;        // 0..63
    const int tcol8  = (t & 7) * 8;
    const int scol   = tcol8 ^ ((trow & 7) << 3);

    const __bf16* Ah0 = A  + (size_t)m0 * lda + kofs;
    const __bf16* Ah1 = A  + (size_t)(m0 + 128) * lda + kofs;
    const __bf16* Bh0 = Bt + (size_t)n0 * ldb + kofs;
    const __bf16* Bh1 = Bt + (size_t)(n0 + 128) * ldb + kofs;

    const int NT = Kper >> 6;

    f32x4 acc[8][4];
#pragma unroll
    for (int i = 0; i < 8; ++i)
#pragma unroll
        for (int j = 0; j < 4; ++j) acc[i][j] = (f32x4){0.f, 0.f, 0.f, 0.f};

    // ---- prologue: stage tile0's 4 halves (8 ops/thread)
    stage_half(Ah0, lda, lds8 + 0 * 8192, trow, tcol8, scol);
    stage_half(Ah1, lda, lds8 + 1 * 8192, trow, tcol8, scol);
    stage_half(Bh0, ldb, lds8 + 2 * 8192, trow, tcol8, scol);
    stage_half(Bh1, ldb, lds8 + 3 * 8192, trow, tcol8, scol);
    asm volatile("s_waitcnt vmcnt(0)" ::: "memory");
    __builtin_amdgcn_s_barrier();
    asm volatile("" ::: "memory");

    for (int tt = 0; tt < NT; ++tt) {
        const int cur = tt & 1;
        const __bf16* LA  = lds8 + (cur * 4 + wm) * 8192;
        const __bf16* LB0 = lds8 + (cur * 4 + 2) * 8192;
        const __bf16* LB1 = lds8 + (cur * 4 + 3) * 8192;
        __bf16* nxt = lds8 + ((1 - cur) * 4) * 8192;
        const bool stg = (tt + 1 < NT);
        const int  knx = (tt + 1) << 6;

        bf16x8 aK0[4], aK1[4], bK0[2][2], bK1[2][2];   // b[bhalf][j]

        // ---------- phase 0: A rows-half0 + B-half0 -> acc[0..3][0..1]
#pragma unroll
        for (int i = 0; i < 4; ++i) {
            const int lr = i * 16 + lane15;
            const int sw = (lr & 7) << 3;
            aK0[i] = *(const bf16x8*)&LA[lr * 64 + ((lhi * 8) ^ sw)];
            aK1[i] = *(const bf16x8*)&LA[lr * 64 + ((32 + lhi * 8) ^ sw)];
        }
#pragma unroll
        for (int j = 0; j < 2; ++j) {
            const int lr = wn * 32 + j * 16 + lane15;
            const int sw = (lr & 7) << 3;
            bK0[0][j] = *(const bf16x8*)&LB0[lr * 64 + ((lhi * 8) ^ sw)];
            bK1[0][j] = *(const bf16x8*)&LB0[lr * 64 + ((32 + lhi * 8) ^ sw)];
        }
        if (stg) {   // EARLY: tile tt+1's A-halves
            stage_half(Ah0 + knx, lda, nxt + 0 * 8192, trow, tcol8, scol);
            stage_half(Ah1 + knx, lda, nxt + 1 * 8192, trow, tcol8, scol);
        }
        __builtin_amdgcn_s_setprio(1);
#pragma unroll
        for (int i = 0; i < 4; ++i)
#pragma unroll
            for (int j = 0; j < 2; ++j) {
                acc[i][j] = __builtin_amdgcn_mfma_f32_16x16x32_bf16(
                    aK0[i], bK0[0][j], acc[i][j], 0, 0, 0);
                acc[i][j] = __builtin_amdgcn_mfma_f32_16x16x32_bf16(
                    aK1[i], bK1[0][j], acc[i][j], 0, 0, 0);
            }
        __builtin_amdgcn_s_setprio(0);

        // ---------- phase 1: B-half1 -> acc[0..3][2..3]
        __builtin_amdgcn_s_barrier();
        asm volatile("" ::: "memory");
#pragma unroll
        for (int j = 0; j < 2; ++j) {
            const int lr = wn * 32 + j * 16 + lane15;
            const int sw = (lr & 7) << 3;
            bK0[1][j] = *(const bf16x8*)&LB1[lr * 64 + ((lhi * 8) ^ sw)];
            bK1[1][j] = *(const bf16x8*)&LB1[lr * 64 + ((32 + lhi * 8) ^ sw)];
        }
        if (stg) {   // EARLY: tile tt+1's B-halves
            stage_half(Bh0 + knx, ldb, nxt + 2 * 8192, trow, tcol8, scol);
            stage_half(Bh1 + knx, ldb, nxt + 3 * 8192, trow, tcol8, scol);
        }
        __builtin_amdgcn_s_setprio(1);
#pragma unroll
        for (int i = 0; i < 4; ++i)
#pragma unroll
            for (int j = 0; j < 2; ++j) {
                acc[i][2 + j] = __builtin_amdgcn_mfma_f32_16x16x32_bf16(
                    aK0[i], bK0[1][j], acc[i][2 + j], 0, 0, 0);
                acc[i][2 + j] = __builtin_amdgcn_mfma_f32_16x16x32_bf16(
                    aK1[i], bK1[1][j], acc[i][2 + j], 0, 0, 0);
            }
        __builtin_amdgcn_s_setprio(0);

        // ---------- phase 2: A rows-half1 (B0 held) -> acc[4..7][0..1]
        __builtin_amdgcn_s_barrier();
        asm volatile("" ::: "memory");
#pragma unroll
        for (int i = 0; i < 4; ++i) {
            const int lr = 64 + i * 16 + lane15;
            const int sw = (lr & 7) << 3;
            aK0[i] = *(const bf16x8*)&LA[lr * 64 + ((lhi * 8) ^ sw)];
            aK1[i] = *(const bf16x8*)&LA[lr * 64 + ((32 + lhi * 8) ^ sw)];
        }
        __builtin_amdgcn_s_setprio(1);
#pragma unroll
        for (int i = 0; i < 4; ++i)
#pragma unroll
            for (int j = 0; j < 2; ++j) {
                acc[4 + i][j] = __builtin_amdgcn_mfma_f32_16x16x32_bf16(
                    aK0[i], bK0[0][j], acc[4 + i][j], 0, 0, 0);
                acc[4 + i][j] = __builtin_amdgcn_mfma_f32_16x16x32_bf16(
                    aK1[i], bK1[0][j], acc[4 + i][j], 0, 0, 0);
            }
        __builtin_amdgcn_s_setprio(0);

        // ---------- phase 3: all operands held -> acc[4..7][2..3]
        __builtin_amdgcn_s_barrier();
        asm volatile("" ::: "memory");
        __builtin_amdgcn_s_setprio(1);
#pragma unroll
        for (int i = 0; i < 4; ++i)
#pragma unroll
            for (int j = 0; j < 2; ++j) {
                acc[4 + i][2 + j] = __builtin_amdgcn_mfma_f32_16x16x32_bf16(
                    aK0[i], bK0[1][j], acc[4 + i][2 + j], 0, 0, 0);
                acc[4 + i][2 + j] = __builtin_amdgcn_mfma_f32_16x16x32_bf16(
                    aK1[i], bK1[1][j], acc[4 + i][2 + j], 0, 0, 0);
            }
        __builtin_amdgcn_s_setprio(0);

        // ---------- tile boundary
        if (tt + 1 < NT) {
            asm volatile("s_waitcnt vmcnt(0)" ::: "memory");
            __builtin_amdgcn_s_barrier();
            asm volatile("" ::: "memory");
        }
    }

    // ---- epilogue, vectorized: r-dim (4 consecutive m) per store
    const int rbase = lhi * 4;
    float* const dst = (MODE == 3) ? (kslice ? Cpart : C0) : C0;
#pragma unroll
    for (int fi = 0; fi < 8; ++fi) {
#pragma unroll
        for (int fj = 0; fj < 4; ++fj) {
            const int n = n0 + (fj >> 1) * 128 + wn * 32 + (fj & 1) * 16 + lane15;
            const int m = m0 + wm * 128 + fi * 16 + rbase;   // 4 consecutive
            if constexpr (MODE == 0) {
                __align__(8) __bf16 ob[4];
#pragma unroll
                for (int r = 0; r < 4; ++r) ob[r] = f2bf(acc[fi][fj][r]);
                if (m < DINNER)
                    *(bf16x4*)&C0b[(size_t)n * DINNER + m] = *(const bf16x4*)ob;
                else
                    *(bf16x4*)&C1b[(size_t)n * DINNER + (m - DINNER)] = *(const bf16x4*)ob;
            } else {
                *(float4*)&dst[(size_t)n * ldc + m] = *(const float4*)&acc[fi][fj];
            }
        }
    }
}

// out += part  (split-K reduction, no atomics)
__global__ __launch_bounds__(256)
void addout(float* __restrict__ out, const float* __restrict__ part, int n4)
{
    const int i = blockIdx.x * 256 + threadIdx.x;
    if (i >= n4) return;
    float4 a = *(const float4*)&out[(size_t)i * 4];
    const float4 b = *(const float4*)&part[(size_t)i * 4];
    a.x += b.x; a.y += b.y; a.z += b.z; a.w += b.w;
    *(float4*)&out[(size_t)i * 4] = a;
}

// ---------------------------------------------------------------------------
// m97-style 128x128 bf16 MFMA GEMM (small GEMMs: x_proj, dt_proj).
// MODE 2: softplus(v + bias[m]) -> C1b bf16 [n*ldc+m]        [dt_proj]
// MODE 3: m<128 -> C1b bf16 [n*128+m]; 128<=m<160 -> C0 fp32 [n*32+m-128]
// ---------------------------------------------------------------------------
template <int MODE>
__global__ __launch_bounds__(256)
void gemm_bf16(const __bf16* __restrict__ A, const __bf16* __restrict__ Bt,
               float* __restrict__ C0, __bf16* __restrict__ C1b,
               const float* __restrict__ bias,
               int Mvalid, int K, int lda, int ldb, int ldc)
{
    __shared__ __align__(16) __bf16 As[128 * 64];
    __shared__ __align__(16) __bf16 Bs[128 * 64];

    const int t  = threadIdx.x;
    const int m0 = blockIdx.y * 128;
    const int n0 = blockIdx.x * 128;
    const int l  = t & 63;
    const int w  = t >> 6;
    const int wr = (w >> 1) * 64;
    const int wc = (w & 1) * 64;
    const int lrow = t >> 3;
    const int lk   = (t & 7) * 8;

    f32x4 acc[4][4];
#pragma unroll
    for (int i = 0; i < 4; ++i)
#pragma unroll
        for (int j = 0; j < 4; ++j) acc[i][j] = (f32x4){0.f, 0.f, 0.f, 0.f};

    for (int k0 = 0; k0 < K; k0 += 64) {
#pragma unroll
        for (int q = 0; q < 4; ++q) {
            const int row = q * 32 + lrow;
            load_lds16(A  + (size_t)(m0 + row) * lda + k0 + lk, &As[row * 64 + lk]);
            load_lds16(Bt + (size_t)(n0 + row) * ldb + k0 + lk, &Bs[row * 64 + lk]);
        }
        __syncthreads();

#pragma unroll
        for (int kk = 0; kk < 2; ++kk) {
            const int krd = kk * 32 + (l >> 4) * 8;
            bf16x8 a[4], b[4];
#pragma unroll
            for (int i = 0; i < 4; ++i) {
                a[i] = *(const bf16x8*)&As[(wr + i * 16 + (l & 15)) * 64 + krd];
                b[i] = *(const bf16x8*)&Bs[(wc + i * 16 + (l & 15)) * 64 + krd];
            }
#pragma unroll
            for (int i = 0; i < 4; ++i)
#pragma unroll
                for (int j = 0; j < 4; ++j)
                    acc[i][j] = __builtin_amdgcn_mfma_f32_16x16x32_bf16(
                        a[i], b[j], acc[i][j], 0, 0, 0);
        }
        __syncthreads();
    }

    const int rbase = (l >> 4) * 4;
    const int cbase = l & 15;
#pragma unroll
    for (int i = 0; i < 4; ++i) {
#pragma unroll
        for (int j = 0; j < 4; ++j) {
#pragma unroll
            for (int r = 0; r < 4; ++r) {
                const int m = m0 + wr + i * 16 + rbase + r;
                const int n = n0 + wc + j * 16 + cbase;
                const float v = acc[i][j][r];
                if constexpr (MODE == 2) {
                    const float vb = v + bias[m];
                    const float sp = (vb > 20.f) ? vb : log1pf(__expf(vb));
                    C1b[(size_t)n * ldc + m] = f2bf(sp);
                } else {   // MODE 3
                    if (m < 128)      C1b[(size_t)n * 128 + m] = f2bf(v);
                    else if (m < 160) C0[(size_t)n * 32 + (m - 128)] = v;
                }
            }
        }
    }
}

// ---------------------------------------------------------------------------
// Fused fp32->bf16 conversions for all 5 buffers (one launch).
// ---------------------------------------------------------------------------
#define CS0 (NTOK * DMODEL / 8)        // hidden      1048576
#define CS1 (2 * DINNER * DMODEL / 8)  // in_proj_w   2097152
#define CS2 (DMODEL * DINNER / 8)      // out_proj_w  1048576
#define CS3 (DINNER * DTRANK / 8)      // dt_proj_w     65536
#define CS4 (256 * DINNER / 8)         // x_proj pad   131072
#define CTOT (CS0 + CS1 + CS2 + CS3 + CS4)

__global__ __launch_bounds__(256)
void cvt_all(const float* __restrict__ hidden, const float* __restrict__ w_in,
             const float* __restrict__ w_out, const float* __restrict__ w_dt,
             const float* __restrict__ w_xp,
             __bf16* __restrict__ hid_bf, __bf16* __restrict__ w_in_bf,
             __bf16* __restrict__ w_out_bf, __bf16* __restrict__ dtw_bf,
             __bf16* __restrict__ w_xp_bf)
{
    const int i = blockIdx.x * 256 + threadIdx.x;
    const float* src; __bf16* dst; int off;
    if (i < CS0)                    { src = hidden; dst = hid_bf;  off = i; }
    else if (i < CS0 + CS1)         { src = w_in;   dst = w_in_bf; off = i - CS0; }
    else if (i < CS0 + CS1 + CS2)   { src = w_out;  dst = w_out_bf; off = i - (CS0 + CS1); }
    else if (i < CS0 + CS1 + CS2 + CS3) { src = w_dt; dst = dtw_bf; off = i - (CS0 + CS1 + CS2); }
    else {
        off = i - (CS0 + CS1 + CS2 + CS3);
        const int row = off >> 9;
        __align__(16) __bf16 o[8];
        if (row < 160) {
            const size_t base = (size_t)off * 8;
            const float4 a = *(const float4*)&w_xp[base];
            const float4 b = *(const float4*)&w_xp[base + 4];
            o[0] = f2bf(a.x); o[1] = f2bf(a.y); o[2] = f2bf(a.z); o[3] = f2bf(a.w);
            o[4] = f2bf(b.x); o[5] = f2bf(b.y); o[6] = f2bf(b.z); o[7] = f2bf(b.w);
        } else {
#pragma unroll
            for (int kk = 0; kk < 8; ++kk) o[kk] = f2bf(0.f);
        }
        *(bf16x8*)&w_xp_bf[(size_t)off * 8] = *(const bf16x8*)o;
        return;
    }
    const size_t base = (size_t)off * 8;
    const float4 a = *(const float4*)&src[base];
    const float4 b = *(const float4*)&src[base + 4];
    __align__(16) __bf16 o[8];
    o[0] = f2bf(a.x); o[1] = f2bf(a.y); o[2] = f2bf(a.z); o[3] = f2bf(a.w);
    o[4] = f2bf(b.x); o[5] = f2bf(b.y); o[6] = f2bf(b.z); o[7] = f2bf(b.w);
    *(bf16x8*)&dst[base] = *(const bf16x8*)o;
}

// ---------------------------------------------------------------------------
// Causal conv (width 4) + SiLU; x now bf16.
// ---------------------------------------------------------------------------
__global__ __launch_bounds__(256)
void conv_silu(const __bf16* __restrict__ x, const float* __restrict__ conv_w,
               __bf16* __restrict__ xact_bf)
{
    const size_t idx = (size_t)blockIdx.x * 256 + threadIdx.x;
    const int e = (int)(idx & (DINNER - 1));
    const int n = (int)(idx >> 12);

    const float4 w = *(const float4*)&conv_w[e * 4];
    float s = w.w * (float)x[idx];
    if (n >= 2) s += w.z * (float)x[idx - (size_t)2 * DINNER];
    if (n >= 4) s += w.y * (float)x[idx - (size_t)4 * DINNER];
    if (n >= 6) s += w.x * (float)x[idx - (size_t)6 * DINNER];
    const float v = s / (1.f + __expf(-s));
    xact_bf[idx] = f2bf(v);
}

// ---------------------------------------------------------------------------
// Chunked selective scan (delta bf16).
// ---------------------------------------------------------------------------
__global__ __launch_bounds__(256)
void scan_partial(const __bf16* __restrict__ delta, const __bf16* __restrict__ u,
                  const float* __restrict__ xbc, const float* __restrict__ A_log,
                  float2* __restrict__ PS)
{
    const int e     = blockIdx.x * 256 + threadIdx.x;
    const int chunk = blockIdx.y;
    const int b     = blockIdx.z;

    __shared__ float BC[CHUNK][32];
    for (int i = threadIdx.x; i < CHUNK * 32; i += 256) {
        const int ll = i >> 5, f = i & 31;
        BC[ll][f] = xbc[(size_t)((chunk * CHUNK + ll) * BATCH + b) * 32 + f];
    }

    float Av[16];
#pragma unroll
    for (int s = 0; s < 16; s += 4) {
        float4 tv = *(const float4*)&A_log[e * 16 + s];
        Av[s] = -__expf(tv.x); Av[s + 1] = -__expf(tv.y);
        Av[s + 2] = -__expf(tv.z); Av[s + 3] = -__expf(tv.w);
    }
    __syncthreads();

    float P[16], S[16];
#pragma unroll
    for (int s = 0; s < 16; ++s) { P[s] = 1.f; S[s] = 0.f; }

#pragma unroll 4
    for (int ll = 0; ll < CHUNK; ++ll) {
        const int tok = (chunk * CHUNK + ll) * BATCH + b;
        const size_t ce = (size_t)tok * DINNER + e;
        const float dl = (float)delta[ce];
        const float du = dl * (float)u[ce];
#pragma unroll
        for (int s = 0; s < 16; ++s) {
            const float dA = __expf(dl * Av[s]);
            S[s] = fmaf(dA, S[s], du * BC[ll][s]);
            P[s] *= dA;
        }
    }

    float2* outp = PS + ((size_t)(chunk * BATCH + b) * DINNER + e) * 16;
#pragma unroll
    for (int s = 0; s < 16; ++s) outp[s] = make_float2(P[s], S[s]);
}

__global__ __launch_bounds__(256)
void scan_combine(const float2* __restrict__ PS, float* __restrict__ Hinit)
{
    const size_t pos = (size_t)blockIdx.x * 256 + threadIdx.x;
    const size_t stride = (size_t)BATCH * DINNER * 16;
    float h = 0.f;
#pragma unroll
    for (int c = 0; c < NCHUNK; ++c) {
        Hinit[c * stride + pos] = h;
        const float2 ps = PS[c * stride + pos];
        h = fmaf(ps.x, h, ps.y);
    }
}

__global__ __launch_bounds__(256)
void scan_final(const __bf16* __restrict__ delta, const __bf16* __restrict__ u,
                const float* __restrict__ xbc, const float* __restrict__ Hinit,
                const __bf16* __restrict__ z_bf, __bf16* __restrict__ y_bf,
                const float* __restrict__ A_log, const float* __restrict__ Dvec)
{
    const int e     = blockIdx.x * 256 + threadIdx.x;
    const int chunk = blockIdx.y;
    const int b     = blockIdx.z;

    __shared__ float BC[CHUNK][32];
    for (int i = threadIdx.x; i < CHUNK * 32; i += 256) {
        const int ll = i >> 5, f = i & 31;
        BC[ll][f] = xbc[(size_t)((chunk * CHUNK + ll) * BATCH + b) * 32 + f];
    }

    float Av[16];
#pragma unroll
    for (int s = 0; s < 16; s += 4) {
        float4 tv = *(const float4*)&A_log[e * 16 + s];
        Av[s] = -__expf(tv.x); Av[s + 1] = -__expf(tv.y);
        Av[s + 2] = -__expf(tv.z); Av[s + 3] = -__expf(tv.w);
    }
    const float Dv = Dvec[e];

    float h[16];
    const float* hi = Hinit + (size_t)chunk * BATCH * DINNER * 16
                            + ((size_t)b * DINNER + e) * 16;
#pragma unroll
    for (int s = 0; s < 16; s += 4) *(float4*)&h[s] = *(const float4*)&hi[s];
    __syncthreads();

#pragma unroll 2
    for (int ll = 0; ll < CHUNK; ++ll) {
        const int tok = (chunk * CHUNK + ll) * BATCH + b;
        const size_t ce = (size_t)tok * DINNER + e;
        const float dl = (float)delta[ce];
        const float ul = (float)u[ce];
        const float du = dl * ul;
        float y = 0.f;
#pragma unroll
        for (int s = 0; s < 16; ++s) {
            const float dA = __expf(dl * Av[s]);
            h[s] = fmaf(dA, h[s], du * BC[ll][s]);
            y = fmaf(h[s], BC[ll][16 + s], y);
        }
        const float zl = (float)z_bf[ce];
        const float sig = 1.f / (1.f + __expf(-zl));
        y_bf[ce] = f2bf((y + ul * Dv) * (zl * sig));
    }
}

// ---------------------------------------------------------------------------
extern "C" void kernel_launch(void* const* d_in, const int* in_sizes, int n_in,
                              void* d_out, int out_size, void* d_ws, size_t ws_size,
                              hipStream_t stream)
{
    const float* hidden    = (const float*)d_in[0];
    const float* in_proj_w = (const float*)d_in[1];
    const float* conv_w    = (const float*)d_in[2];
    const float* x_proj_w  = (const float*)d_in[3];
    const float* dt_proj_w = (const float*)d_in[4];
    const float* dt_proj_b = (const float*)d_in[5];
    const float* A_log     = (const float*)d_in[6];
    const float* Dvec      = (const float*)d_in[7];
    const float* out_proj_w= (const float*)d_in[8];
    float* out = (float*)d_out;

    // -------- workspace (same region sizes/totals as R9's passing run;
    //          the old fp32 xbuf region now holds x_bf + delta_bf)
    char* p = (char*)d_ws;
    const size_t NBIG = (size_t)NTOK * DINNER;
    __bf16* x_bf    = (__bf16*)p;   p += NBIG * 2;                        // x (bf16)
    __bf16* delta_bf= (__bf16*)p;   p += NBIG * 2;                        // delta (bf16)
    __bf16* z_bf    = (__bf16*)p;   p += NBIG * 2;                        // z
    __bf16* xact_bf = (__bf16*)p;   p += NBIG * 2;                        // u
    __bf16* dtr_bf  = (__bf16*)p;   p += (size_t)NTOK * 128 * 2;         // dt_r (bf16)
    float*  xbc     = (float*)p;    p += (size_t)NTOK * 32 * 4;          // B|C (fp32)
    __bf16* w_xp_bf = (__bf16*)p;   p += (size_t)256 * DINNER * 2;
    __bf16* w_out_bf= (__bf16*)p;   p += (size_t)DMODEL * DINNER * 2;
    char*   G       = p;            p += (size_t)2 * DINNER * DMODEL * 2; // 33.5 MB, multi-use
    __bf16* hid_bf  = (__bf16*)p;   p += (size_t)NTOK * DMODEL * 2;
    __bf16* y_bf    = (__bf16*)p;   p += NBIG * 2;
    __bf16* dtw_bf  = (__bf16*)p;   p += (size_t)DINNER * DTRANK * 2;
    const size_t required = (size_t)(p - (char*)d_ws);
    if (ws_size < required) return;

    // G region lifetime: w_in_bf (steps 0-1) -> PS+Hinit (step 5) -> Cpart (step 6)
    __bf16* w_in_bf = (__bf16*)G;
    float2* PS      = (float2*)G;
    float*  Hinit   = (float*)(G + (size_t)NCHUNK * BATCH * DINNER * 16 * 8);
    float*  Cpart   = (float*)G;

    // 0) fused conversions
    cvt_all<<<CTOT / 256, 256, 0, stream>>>(
        hidden, in_proj_w, out_proj_w, dt_proj_w, x_proj_w,
        hid_bf, w_in_bf, w_out_bf, dtw_bf, w_xp_bf);

    // 1) in_proj (256^2, XCD-block swizzle): x (bf16) | z (bf16). grid 512
    gemm8<0><<<(2 * DINNER / 256) * (NTOK / 256), 512, 0, stream>>>(
        w_in_bf, hid_bf, nullptr, x_bf, z_bf, nullptr, DMODEL, DMODEL, DMODEL, DINNER,
        NTOK / 256, (2 * DINNER / 256) * (NTOK / 256));

    // 2) conv + silu -> u (bf16)
    conv_silu<<<(int)(NBIG / 256), 256, 0, stream>>>(x_bf, conv_w, xact_bf);

    // 3) x_proj (128^2): dt_r -> bf16, B|C -> fp32 compact
    gemm_bf16<3><<<dim3(NTOK / 128, 2), 256, 0, stream>>>(
        w_xp_bf, xact_bf, xbc, dtr_bf, nullptr, 160, DINNER, DINNER, DINNER, 0);

    // 4) dt_proj (128^2, K=128) + softplus -> delta (bf16)
    gemm_bf16<2><<<dim3(NTOK / 128, DINNER / 128), 256, 0, stream>>>(
        dtw_bf, dtr_bf, nullptr, delta_bf, dt_proj_b, DINNER, DTRANK, DTRANK, DTRANK, DINNER);

    // 5) chunked scan (PS/Hinit overwrite w_in_bf — dead after step 1)
    scan_partial<<<dim3(DINNER / 256, NCHUNK, BATCH), 256, 0, stream>>>(
        delta_bf, xact_bf, xbc, A_log, PS);
    scan_combine<<<(BATCH * DINNER * 16) / 256, 256, 0, stream>>>(PS, Hinit);
    scan_final<<<dim3(DINNER / 256, NCHUNK, BATCH), 256, 0, stream>>>(
        delta_bf, xact_bf, xbc, Hinit, z_bf, y_bf, A_log, Dvec);

    // 6) out_proj: deterministic split-K=2 + addout. grid 256, no atomics.
    gemm8<3><<<(DMODEL / 256) * (NTOK / 256) * 2, 512, 0, stream>>>(
        w_out_bf, y_bf, out, nullptr, nullptr, Cpart, DINNER / 2, DINNER, DINNER, DMODEL,
        NTOK / 256, (DMODEL / 256) * (NTOK / 256));
    addout<<<(NTOK * DMODEL / 4 + 255) / 256, 256, 0, stream>>>(
        out, Cpart, NTOK * DMODEL / 4);
}

// Round 11
// 610.574 us; speedup vs baseline: 1.4894x; 1.0916x over previous
//
#include <hip/hip_runtime.h>
#include <hip/hip_bf16.h>
#include <math.h>

#define L_SEQ   2048
#define BATCH   2
#define DMODEL  2048
#define DINNER  4096
#define DSTATE  16
#define DTRANK  128
#define NTOK    (L_SEQ * BATCH)   // 4096
#define CHUNK   128
#define NCHUNK  (L_SEQ / CHUNK)   // 16

typedef __attribute__((ext_vector_type(8))) __bf16 bf16x8;
typedef __attribute__((ext_vector_type(4))) __bf16 bf16x4;
typedef __attribute__((ext_vector_type(4))) float f32x4;

__device__ __forceinline__ __bf16 f2bf(float f) {
    unsigned u = __builtin_bit_cast(unsigned, f);
    unsigned r = (u + 0x7FFFu + ((u >> 16) & 1u)) >> 16;
    return __builtin_bit_cast(__bf16, (unsigned short)r);
}

__device__ __forceinline__ void load_lds16(const void* gsrc, void* lds) {
    __builtin_amdgcn_global_load_lds(
        (const __attribute__((address_space(1))) unsigned int*)gsrc,
        (__attribute__((address_space(3))) unsigned int*)lds, 16, 0, 0);
}

// Stage one 128x64 bf16 half-tile (16 KiB) with 512 threads x 2 loads.
// LDS dest LINEAR; SOURCE column inverse-swizzled (rule 21: both-sides).
__device__ __forceinline__ void stage_half(const __bf16* g, int ld,
                                           __bf16* lh, int trow, int tcol8, int scol)
{
    load_lds16(g + (size_t)trow        * ld + scol, lh +  trow       * 64 + tcol8);
    load_lds16(g + (size_t)(trow + 64) * ld + scol, lh + (trow + 64) * 64 + tcol8);
}

// ---------------------------------------------------------------------------
// 256x256 bf16 MFMA GEMM, 4-phase early-staged schedule + XCD-block swizzle
// (R10) + q3 B0-PREFETCH (new): the 4 B0 ds_reads for tile tt+1 are issued in
// tile tt's q3 (previously 0 reads), after a per-wave vmcnt(2) [guarantees own
// Bh0' stage: ops 1-6 of the 8 issued this tile] + s_barrier [collectivizes
// completion across waves].  q0 then reads only A-h0 (8) -> LDS-read bursts
// balanced 8/4/8/4+4, and q3/q0 MFMA clusters overlap the reads via register
// dependence (c0 regs consumed only at next tile's q0/q2).
// MODE 0: m<DINNER -> C0b bf16 (x); else C1b bf16 (z); ldc=DINNER   [in_proj]
// MODE 3: split-K deterministic: kslice0 -> C0, kslice1 -> Cpart    [out_proj]
// ---------------------------------------------------------------------------
template <int MODE>
__global__ __launch_bounds__(512, 1)
void gemm8(const __bf16* __restrict__ A, const __bf16* __restrict__ Bt,
           float* __restrict__ C0, __bf16* __restrict__ C0b, __bf16* __restrict__ C1b,
           float* __restrict__ Cpart,
           int Kper, int lda, int ldb, int ldc, int nbn, int ntile)
{
    __shared__ __align__(16) __bf16 lds8[2 * 4 * 8192];   // 128 KiB

    const int t = threadIdx.x;
    // ---- XCD-block decomposition: block = 8m x 4n = 32 wgs on ONE XCD
    const int bid = (int)blockIdx.x;
    const int x   = bid & 7;
    const int k   = bid >> 3;
    const int b   = (k >> 5) * 8 + x;
    const int sub = k & 31;
    const int pslice = ntile >> 5;
    const int kslice = b / pslice;
    const int bp     = b - kslice * pslice;
    const int nblkn  = nbn >> 2;
    const int mb = bp / nblkn, nb = bp - mb * nblkn;
    const int m0 = (mb * 8 + (sub >> 2)) * 256;
    const int n0 = (nb * 4 + (sub & 3)) * 256;
    const int kofs = kslice * Kper;

    const int l      = t & 63;
    const int w      = t >> 6;
    const int wm     = w >> 2;
    const int wn     = w & 3;
    const int lane15 = l & 15;
    const int lhi    = l >> 4;
    const int trow   = t >> 3;
    const int tcol8  = (t & 7) * 8;
    const int scol   = tcol8 ^ ((trow & 7) << 3);

    const __bf16* Ah0 = A  + (size_t)m0 * lda + kofs;
    const __bf16* Ah1 = A  + (size_t)(m0 + 128) * lda + kofs;
    const __bf16* Bh0 = Bt + (size_t)n0 * ldb + kofs;
    const __bf16* Bh1 = Bt + (size_t)(n0 + 128) * ldb + kofs;

    const int NT = Kper >> 6;

    f32x4 acc[8][4];
#pragma unroll
    for (int i = 0; i < 8; ++i)
#pragma unroll
        for (int j = 0; j < 4; ++j) acc[i][j] = (f32x4){0.f, 0.f, 0.f, 0.f};

    // ---- prologue: stage tile0's 4 halves (8 ops/thread)
    stage_half(Ah0, lda, lds8 + 0 * 8192, trow, tcol8, scol);
    stage_half(Ah1, lda, lds8 + 1 * 8192, trow, tcol8, scol);
    stage_half(Bh0, ldb, lds8 + 2 * 8192, trow, tcol8, scol);
    stage_half(Bh1, ldb, lds8 + 3 * 8192, trow, tcol8, scol);
    asm volatile("s_waitcnt vmcnt(0)" ::: "memory");
    __builtin_amdgcn_s_barrier();
    asm volatile("" ::: "memory");

    // ---- pre-read tile0's B0 fragments (held in regs across each tile)
    bf16x8 c0K0[2], c0K1[2];
    {
        const __bf16* LB0p = lds8 + 2 * 8192;
#pragma unroll
        for (int j = 0; j < 2; ++j) {
            const int lr = wn * 32 + j * 16 + lane15;
            const int sw = (lr & 7) << 3;
            c0K0[j] = *(const bf16x8*)&LB0p[lr * 64 + ((lhi * 8) ^ sw)];
            c0K1[j] = *(const bf16x8*)&LB0p[lr * 64 + ((32 + lhi * 8) ^ sw)];
        }
    }

    for (int tt = 0; tt < NT; ++tt) {
        const int cur = tt & 1;
        const __bf16* LA  = lds8 + (cur * 4 + wm) * 8192;
        const __bf16* LB1 = lds8 + (cur * 4 + 3) * 8192;
        __bf16* nxt = lds8 + ((1 - cur) * 4) * 8192;
        const bool stg = (tt + 1 < NT);
        const int  knx = (tt + 1) << 6;

        bf16x8 aK0[4], aK1[4], bK0[2], bK1[2];   // B1 fragments

        // ---------- phase 0: A rows-half0 (B0 pre-read) -> acc[0..3][0..1]
#pragma unroll
        for (int i = 0; i < 4; ++i) {
            const int lr = i * 16 + lane15;
            const int sw = (lr & 7) << 3;
            aK0[i] = *(const bf16x8*)&LA[lr * 64 + ((lhi * 8) ^ sw)];
            aK1[i] = *(const bf16x8*)&LA[lr * 64 + ((32 + lhi * 8) ^ sw)];
        }
        if (stg) {   // EARLY: tile tt+1's A-halves
            stage_half(Ah0 + knx, lda, nxt + 0 * 8192, trow, tcol8, scol);
            stage_half(Ah1 + knx, lda, nxt + 1 * 8192, trow, tcol8, scol);
        }
        __builtin_amdgcn_s_setprio(1);
#pragma unroll
        for (int i = 0; i < 4; ++i)
#pragma unroll
            for (int j = 0; j < 2; ++j) {
                acc[i][j] = __builtin_amdgcn_mfma_f32_16x16x32_bf16(
                    aK0[i], c0K0[j], acc[i][j], 0, 0, 0);
                acc[i][j] = __builtin_amdgcn_mfma_f32_16x16x32_bf16(
                    aK1[i], c0K1[j], acc[i][j], 0, 0, 0);
            }
        __builtin_amdgcn_s_setprio(0);

        // ---------- phase 1: B-half1 -> acc[0..3][2..3]
        __builtin_amdgcn_s_barrier();
        asm volatile("" ::: "memory");
#pragma unroll
        for (int j = 0; j < 2; ++j) {
            const int lr = wn * 32 + j * 16 + lane15;
            const int sw = (lr & 7) << 3;
            bK0[j] = *(const bf16x8*)&LB1[lr * 64 + ((lhi * 8) ^ sw)];
            bK1[j] = *(const bf16x8*)&LB1[lr * 64 + ((32 + lhi * 8) ^ sw)];
        }
        if (stg) {   // EARLY: tile tt+1's B-halves
            stage_half(Bh0 + knx, ldb, nxt + 2 * 8192, trow, tcol8, scol);
            stage_half(Bh1 + knx, ldb, nxt + 3 * 8192, trow, tcol8, scol);
        }
        __builtin_amdgcn_s_setprio(1);
#pragma unroll
        for (int i = 0; i < 4; ++i)
#pragma unroll
            for (int j = 0; j < 2; ++j) {
                acc[i][2 + j] = __builtin_amdgcn_mfma_f32_16x16x32_bf16(
                    aK0[i], bK0[j], acc[i][2 + j], 0, 0, 0);
                acc[i][2 + j] = __builtin_amdgcn_mfma_f32_16x16x32_bf16(
                    aK1[i], bK1[j], acc[i][2 + j], 0, 0, 0);
            }
        __builtin_amdgcn_s_setprio(0);

        // ---------- phase 2: A rows-half1 (B0 held) -> acc[4..7][0..1]
        __builtin_amdgcn_s_barrier();
        asm volatile("" ::: "memory");
#pragma unroll
        for (int i = 0; i < 4; ++i) {
            const int lr = 64 + i * 16 + lane15;
            const int sw = (lr & 7) << 3;
            aK0[i] = *(const bf16x8*)&LA[lr * 64 + ((lhi * 8) ^ sw)];
            aK1[i] = *(const bf16x8*)&LA[lr * 64 + ((32 + lhi * 8) ^ sw)];
        }
        __builtin_amdgcn_s_setprio(1);
#pragma unroll
        for (int i = 0; i < 4; ++i)
#pragma unroll
            for (int j = 0; j < 2; ++j) {
                acc[4 + i][j] = __builtin_amdgcn_mfma_f32_16x16x32_bf16(
                    aK0[i], c0K0[j], acc[4 + i][j], 0, 0, 0);
                acc[4 + i][j] = __builtin_amdgcn_mfma_f32_16x16x32_bf16(
                    aK1[i], c0K1[j], acc[4 + i][j], 0, 0, 0);
            }
        __builtin_amdgcn_s_setprio(0);

        // ---------- phase 3: prefetch next-B0 regs; MFMA uses B1 only
        __builtin_amdgcn_s_barrier();
        asm volatile("" ::: "memory");
        if (stg) {
            // own-stage drain to ops<=2 (Bh0' = ops 5-6 of 8) + collectivize
            asm volatile("s_waitcnt vmcnt(2)" ::: "memory");
            __builtin_amdgcn_s_barrier();
            asm volatile("" ::: "memory");
            const __bf16* NB0 = nxt + 2 * 8192;
#pragma unroll
            for (int j = 0; j < 2; ++j) {
                const int lr = wn * 32 + j * 16 + lane15;
                const int sw = (lr & 7) << 3;
                c0K0[j] = *(const bf16x8*)&NB0[lr * 64 + ((lhi * 8) ^ sw)];
                c0K1[j] = *(const bf16x8*)&NB0[lr * 64 + ((32 + lhi * 8) ^ sw)];
            }
        }
        __builtin_amdgcn_s_setprio(1);
#pragma unroll
        for (int i = 0; i < 4; ++i)
#pragma unroll
            for (int j = 0; j < 2; ++j) {
                acc[4 + i][2 + j] = __builtin_amdgcn_mfma_f32_16x16x32_bf16(
                    aK0[i], bK0[j], acc[4 + i][2 + j], 0, 0, 0);
                acc[4 + i][2 + j] = __builtin_amdgcn_mfma_f32_16x16x32_bf16(
                    aK1[i], bK1[j], acc[4 + i][2 + j], 0, 0, 0);
            }
        __builtin_amdgcn_s_setprio(0);

        // ---------- tile boundary
        if (stg) {
            asm volatile("s_waitcnt vmcnt(0)" ::: "memory");
            __builtin_amdgcn_s_barrier();
            asm volatile("" ::: "memory");
        }
    }

    // ---- epilogue, vectorized: r-dim (4 consecutive m) per store
    const int rbase = lhi * 4;
    float* const dst = (MODE == 3) ? (kslice ? Cpart : C0) : C0;
#pragma unroll
    for (int fi = 0; fi < 8; ++fi) {
#pragma unroll
        for (int fj = 0; fj < 4; ++fj) {
            const int n = n0 + (fj >> 1) * 128 + wn * 32 + (fj & 1) * 16 + lane15;
            const int m = m0 + wm * 128 + fi * 16 + rbase;
            if constexpr (MODE == 0) {
                __align__(8) __bf16 ob[4];
#pragma unroll
                for (int r = 0; r < 4; ++r) ob[r] = f2bf(acc[fi][fj][r]);
                if (m < DINNER)
                    *(bf16x4*)&C0b[(size_t)n * DINNER + m] = *(const bf16x4*)ob;
                else
                    *(bf16x4*)&C1b[(size_t)n * DINNER + (m - DINNER)] = *(const bf16x4*)ob;
            } else {
                *(float4*)&dst[(size_t)n * ldc + m] = *(const float4*)&acc[fi][fj];
            }
        }
    }
}

// out += part  (split-K reduction, no atomics)
__global__ __launch_bounds__(256)
void addout(float* __restrict__ out, const float* __restrict__ part, int n4)
{
    const int i = blockIdx.x * 256 + threadIdx.x;
    if (i >= n4) return;
    float4 a = *(const float4*)&out[(size_t)i * 4];
    const float4 b = *(const float4*)&part[(size_t)i * 4];
    a.x += b.x; a.y += b.y; a.z += b.z; a.w += b.w;
    *(float4*)&out[(size_t)i * 4] = a;
}

// ---------------------------------------------------------------------------
// m97-style 128x128 bf16 MFMA GEMM (small GEMMs: x_proj, dt_proj).
// blockIdx.z selects a K-slice (kz = z*K); grids with gridDim.z==1 get kz=0.
// MODE 2: softplus(v + bias[m]) -> C1b bf16 [n*ldc+m]        [dt_proj]
// MODE 4: fp32 partial C0[z*NTOK*256 + n*256 + m]            [x_proj splitK]
// ---------------------------------------------------------------------------
template <int MODE>
__global__ __launch_bounds__(256)
void gemm_bf16(const __bf16* __restrict__ A, const __bf16* __restrict__ Bt,
               float* __restrict__ C0, __bf16* __restrict__ C1b,
               const float* __restrict__ bias,
               int Mvalid, int K, int lda, int ldb, int ldc)
{
    __shared__ __align__(16) __bf16 As[128 * 64];
    __shared__ __align__(16) __bf16 Bs[128 * 64];

    const int t  = threadIdx.x;
    const int m0 = blockIdx.y * 128;
    const int n0 = blockIdx.x * 128;
    const int kz = blockIdx.z * K;
    const int l  = t & 63;
    const int w  = t >> 6;
    const int wr = (w >> 1) * 64;
    const int wc = (w & 1) * 64;
    const int lrow = t >> 3;
    const int lk   = (t & 7) * 8;

    f32x4 acc[4][4];
#pragma unroll
    for (int i = 0; i < 4; ++i)
#pragma unroll
        for (int j = 0; j < 4; ++j) acc[i][j] = (f32x4){0.f, 0.f, 0.f, 0.f};

    for (int k0 = 0; k0 < K; k0 += 64) {
#pragma unroll
        for (int q = 0; q < 4; ++q) {
            const int row = q * 32 + lrow;
            load_lds16(A  + (size_t)(m0 + row) * lda + kz + k0 + lk, &As[row * 64 + lk]);
            load_lds16(Bt + (size_t)(n0 + row) * ldb + kz + k0 + lk, &Bs[row * 64 + lk]);
        }
        __syncthreads();

#pragma unroll
        for (int kk = 0; kk < 2; ++kk) {
            const int krd = kk * 32 + (l >> 4) * 8;
            bf16x8 a[4], b[4];
#pragma unroll
            for (int i = 0; i < 4; ++i) {
                a[i] = *(const bf16x8*)&As[(wr + i * 16 + (l & 15)) * 64 + krd];
                b[i] = *(const bf16x8*)&Bs[(wc + i * 16 + (l & 15)) * 64 + krd];
            }
#pragma unroll
            for (int i = 0; i < 4; ++i)
#pragma unroll
                for (int j = 0; j < 4; ++j)
                    acc[i][j] = __builtin_amdgcn_mfma_f32_16x16x32_bf16(
                        a[i], b[j], acc[i][j], 0, 0, 0);
        }
        __syncthreads();
    }

    const int rbase = (l >> 4) * 4;
    const int cbase = l & 15;
    float* const C0z = (MODE == 4) ? C0 + (size_t)blockIdx.z * NTOK * 256 : C0;
#pragma unroll
    for (int i = 0; i < 4; ++i) {
#pragma unroll
        for (int j = 0; j < 4; ++j) {
#pragma unroll
            for (int r = 0; r < 4; ++r) {
                const int m = m0 + wr + i * 16 + rbase + r;
                const int n = n0 + wc + j * 16 + cbase;
                const float v = acc[i][j][r];
                if constexpr (MODE == 2) {
                    const float vb = v + bias[m];
                    const float sp = (vb > 20.f) ? vb : log1pf(__expf(vb));
                    C1b[(size_t)n * ldc + m] = f2bf(sp);
                } else {   // MODE 4
                    C0z[(size_t)n * 256 + m] = v;
                }
            }
        }
    }
}

// x_proj split-K combine: sum 4 fp32 partials -> dtr_bf (m<128) | xbc (128..159)
__global__ __launch_bounds__(256)
void xp_combine(const float* __restrict__ xpart, __bf16* __restrict__ dtr_bf,
                float* __restrict__ xbc)
{
    const int i = blockIdx.x * 256 + threadIdx.x;
    if (i >= NTOK * 160) return;
    const int n = i / 160;
    const int m = i - n * 160;
    const size_t stride = (size_t)NTOK * 256;
    const size_t base = (size_t)n * 256 + m;
    float s = xpart[base] + xpart[stride + base]
            + xpart[2 * stride + base] + xpart[3 * stride + base];
    if (m < 128) dtr_bf[(size_t)n * 128 + m] = f2bf(s);
    else         xbc[(size_t)n * 32 + (m - 128)] = s;
}

// ---------------------------------------------------------------------------
// Fused fp32->bf16 conversions for all 5 buffers (one launch).
// ---------------------------------------------------------------------------
#define CS0 (NTOK * DMODEL / 8)        // hidden      1048576
#define CS1 (2 * DINNER * DMODEL / 8)  // in_proj_w   2097152
#define CS2 (DMODEL * DINNER / 8)      // out_proj_w  1048576
#define CS3 (DINNER * DTRANK / 8)      // dt_proj_w     65536
#define CS4 (256 * DINNER / 8)         // x_proj pad   131072
#define CTOT (CS0 + CS1 + CS2 + CS3 + CS4)

__global__ __launch_bounds__(256)
void cvt_all(const float* __restrict__ hidden, const float* __restrict__ w_in,
             const float* __restrict__ w_out, const float* __restrict__ w_dt,
             const float* __restrict__ w_xp,
             __bf16* __restrict__ hid_bf, __bf16* __restrict__ w_in_bf,
             __bf16* __restrict__ w_out_bf, __bf16* __restrict__ dtw_bf,
             __bf16* __restrict__ w_xp_bf)
{
    const int i = blockIdx.x * 256 + threadIdx.x;
    const float* src; __bf16* dst; int off;
    if (i < CS0)                    { src = hidden; dst = hid_bf;  off = i; }
    else if (i < CS0 + CS1)         { src = w_in;   dst = w_in_bf; off = i - CS0; }
    else if (i < CS0 + CS1 + CS2)   { src = w_out;  dst = w_out_bf; off = i - (CS0 + CS1); }
    else if (i < CS0 + CS1 + CS2 + CS3) { src = w_dt; dst = dtw_bf; off = i - (CS0 + CS1 + CS2); }
    else {
        off = i - (CS0 + CS1 + CS2 + CS3);
        const int row = off >> 9;
        __align__(16) __bf16 o[8];
        if (row < 160) {
            const size_t base = (size_t)off * 8;
            const float4 a = *(const float4*)&w_xp[base];
            const float4 b = *(const float4*)&w_xp[base + 4];
            o[0] = f2bf(a.x); o[1] = f2bf(a.y); o[2] = f2bf(a.z); o[3] = f2bf(a.w);
            o[4] = f2bf(b.x); o[5] = f2bf(b.y); o[6] = f2bf(b.z); o[7] = f2bf(b.w);
        } else {
#pragma unroll
            for (int kk = 0; kk < 8; ++kk) o[kk] = f2bf(0.f);
        }
        *(bf16x8*)&w_xp_bf[(size_t)off * 8] = *(const bf16x8*)o;
        return;
    }
    const size_t base = (size_t)off * 8;
    const float4 a = *(const float4*)&src[base];
    const float4 b = *(const float4*)&src[base + 4];
    __align__(16) __bf16 o[8];
    o[0] = f2bf(a.x); o[1] = f2bf(a.y); o[2] = f2bf(a.z); o[3] = f2bf(a.w);
    o[4] = f2bf(b.x); o[5] = f2bf(b.y); o[6] = f2bf(b.z); o[7] = f2bf(b.w);
    *(bf16x8*)&dst[base] = *(const bf16x8*)o;
}

// ---------------------------------------------------------------------------
// Causal conv (width 4) + SiLU; x bf16.
// ---------------------------------------------------------------------------
__global__ __launch_bounds__(256)
void conv_silu(const __bf16* __restrict__ x, const float* __restrict__ conv_w,
               __bf16* __restrict__ xact_bf)
{
    const size_t idx = (size_t)blockIdx.x * 256 + threadIdx.x;
    const int e = (int)(idx & (DINNER - 1));
    const int n = (int)(idx >> 12);

    const float4 w = *(const float4*)&conv_w[e * 4];
    float s = w.w * (float)x[idx];
    if (n >= 2) s += w.z * (float)x[idx - (size_t)2 * DINNER];
    if (n >= 4) s += w.y * (float)x[idx - (size_t)4 * DINNER];
    if (n >= 6) s += w.x * (float)x[idx - (size_t)6 * DINNER];
    const float v = s / (1.f + __expf(-s));
    xact_bf[idx] = f2bf(v);
}

// ---------------------------------------------------------------------------
// Chunked selective scan (delta bf16).
// ---------------------------------------------------------------------------
__global__ __launch_bounds__(256)
void scan_partial(const __bf16* __restrict__ delta, const __bf16* __restrict__ u,
                  const float* __restrict__ xbc, const float* __restrict__ A_log,
                  float2* __restrict__ PS)
{
    const int e     = blockIdx.x * 256 + threadIdx.x;
    const int chunk = blockIdx.y;
    const int b     = blockIdx.z;

    __shared__ float BC[CHUNK][32];
    for (int i = threadIdx.x; i < CHUNK * 32; i += 256) {
        const int ll = i >> 5, f = i & 31;
        BC[ll][f] = xbc[(size_t)((chunk * CHUNK + ll) * BATCH + b) * 32 + f];
    }

    float Av[16];
#pragma unroll
    for (int s = 0; s < 16; s += 4) {
        float4 tv = *(const float4*)&A_log[e * 16 + s];
        Av[s] = -__expf(tv.x); Av[s + 1] = -__expf(tv.y);
        Av[s + 2] = -__expf(tv.z); Av[s + 3] = -__expf(tv.w);
    }
    __syncthreads();

    float P[16], S[16];
#pragma unroll
    for (int s = 0; s < 16; ++s) { P[s] = 1.f; S[s] = 0.f; }

#pragma unroll 4
    for (int ll = 0; ll < CHUNK; ++ll) {
        const int tok = (chunk * CHUNK + ll) * BATCH + b;
        const size_t ce = (size_t)tok * DINNER + e;
        const float dl = (float)delta[ce];
        const float du = dl * (float)u[ce];
#pragma unroll
        for (int s = 0; s < 16; ++s) {
            const float dA = __expf(dl * Av[s]);
            S[s] = fmaf(dA, S[s], du * BC[ll][s]);
            P[s] *= dA;
        }
    }

    float2* outp = PS + ((size_t)(chunk * BATCH + b) * DINNER + e) * 16;
#pragma unroll
    for (int s = 0; s < 16; ++s) outp[s] = make_float2(P[s], S[s]);
}

__global__ __launch_bounds__(256)
void scan_combine(const float2* __restrict__ PS, float* __restrict__ Hinit)
{
    const size_t pos = (size_t)blockIdx.x * 256 + threadIdx.x;
    const size_t stride = (size_t)BATCH * DINNER * 16;
    float h = 0.f;
#pragma unroll
    for (int c = 0; c < NCHUNK; ++c) {
        Hinit[c * stride + pos] = h;
        const float2 ps = PS[c * stride + pos];
        h = fmaf(ps.x, h, ps.y);
    }
}

__global__ __launch_bounds__(256)
void scan_final(const __bf16* __restrict__ delta, const __bf16* __restrict__ u,
                const float* __restrict__ xbc, const float* __restrict__ Hinit,
                const __bf16* __restrict__ z_bf, __bf16* __restrict__ y_bf,
                const float* __restrict__ A_log, const float* __restrict__ Dvec)
{
    const int e     = blockIdx.x * 256 + threadIdx.x;
    const int chunk = blockIdx.y;
    const int b     = blockIdx.z;

    __shared__ float BC[CHUNK][32];
    for (int i = threadIdx.x; i < CHUNK * 32; i += 256) {
        const int ll = i >> 5, f = i & 31;
        BC[ll][f] = xbc[(size_t)((chunk * CHUNK + ll) * BATCH + b) * 32 + f];
    }

    float Av[16];
#pragma unroll
    for (int s = 0; s < 16; s += 4) {
        float4 tv = *(const float4*)&A_log[e * 16 + s];
        Av[s] = -__expf(tv.x); Av[s + 1] = -__expf(tv.y);
        Av[s + 2] = -__expf(tv.z); Av[s + 3] = -__expf(tv.w);
    }
    const float Dv = Dvec[e];

    float h[16];
    const float* hi = Hinit + (size_t)chunk * BATCH * DINNER * 16
                            + ((size_t)b * DINNER + e) * 16;
#pragma unroll
    for (int s = 0; s < 16; s += 4) *(float4*)&h[s] = *(const float4*)&hi[s];
    __syncthreads();

#pragma unroll 2
    for (int ll = 0; ll < CHUNK; ++ll) {
        const int tok = (chunk * CHUNK + ll) * BATCH + b;
        const size_t ce = (size_t)tok * DINNER + e;
        const float dl = (float)delta[ce];
        const float ul = (float)u[ce];
        const float du = dl * ul;
        float y = 0.f;
#pragma unroll
        for (int s = 0; s < 16; ++s) {
            const float dA = __expf(dl * Av[s]);
            h[s] = fmaf(dA, h[s], du * BC[ll][s]);
            y = fmaf(h[s], BC[ll][16 + s], y);
        }
        const float zl = (float)z_bf[ce];
        const float sig = 1.f / (1.f + __expf(-zl));
        y_bf[ce] = f2bf((y + ul * Dv) * (zl * sig));
    }
}

// ---------------------------------------------------------------------------
extern "C" void kernel_launch(void* const* d_in, const int* in_sizes, int n_in,
                              void* d_out, int out_size, void* d_ws, size_t ws_size,
                              hipStream_t stream)
{
    const float* hidden    = (const float*)d_in[0];
    const float* in_proj_w = (const float*)d_in[1];
    const float* conv_w    = (const float*)d_in[2];
    const float* x_proj_w  = (const float*)d_in[3];
    const float* dt_proj_w = (const float*)d_in[4];
    const float* dt_proj_b = (const float*)d_in[5];
    const float* A_log     = (const float*)d_in[6];
    const float* Dvec      = (const float*)d_in[7];
    const float* out_proj_w= (const float*)d_in[8];
    float* out = (float*)d_out;

    // -------- workspace (same region sizes/totals as R10's passing run)
    char* p = (char*)d_ws;
    const size_t NBIG = (size_t)NTOK * DINNER;
    __bf16* x_bf    = (__bf16*)p;   p += NBIG * 2;                        // x (bf16)
    __bf16* delta_bf= (__bf16*)p;   p += NBIG * 2;                        // delta (bf16)
    __bf16* z_bf    = (__bf16*)p;   p += NBIG * 2;                        // z
    __bf16* xact_bf = (__bf16*)p;   p += NBIG * 2;                        // u
    __bf16* dtr_bf  = (__bf16*)p;   p += (size_t)NTOK * 128 * 2;         // dt_r (bf16)
    float*  xbc     = (float*)p;    p += (size_t)NTOK * 32 * 4;          // B|C (fp32)
    __bf16* w_xp_bf = (__bf16*)p;   p += (size_t)256 * DINNER * 2;
    __bf16* w_out_bf= (__bf16*)p;   p += (size_t)DMODEL * DINNER * 2;
    char*   G       = p;            p += (size_t)2 * DINNER * DMODEL * 2; // 33.5 MB, multi-use
    __bf16* hid_bf  = (__bf16*)p;   p += (size_t)NTOK * DMODEL * 2;
    __bf16* y_bf    = (__bf16*)p;   p += NBIG * 2;
    __bf16* dtw_bf  = (__bf16*)p;   p += (size_t)DINNER * DTRANK * 2;
    const size_t required = (size_t)(p - (char*)d_ws);
    if (ws_size < required) return;

    // G lifetime: w_in_bf (0-1) -> xpart (3) -> PS+Hinit (5) -> Cpart (6)
    __bf16* w_in_bf = (__bf16*)G;
    float*  xpart   = (float*)G;                                         // 16.8 MB
    float2* PS      = (float2*)G;
    float*  Hinit   = (float*)(G + (size_t)NCHUNK * BATCH * DINNER * 16 * 8);
    float*  Cpart   = (float*)G;

    // 0) fused conversions
    cvt_all<<<CTOT / 256, 256, 0, stream>>>(
        hidden, in_proj_w, out_proj_w, dt_proj_w, x_proj_w,
        hid_bf, w_in_bf, w_out_bf, dtw_bf, w_xp_bf);

    // 1) in_proj (256^2, XCD-block + q3-prefetch): x | z (both bf16). grid 512
    gemm8<0><<<(2 * DINNER / 256) * (NTOK / 256), 512, 0, stream>>>(
        w_in_bf, hid_bf, nullptr, x_bf, z_bf, nullptr, DMODEL, DMODEL, DMODEL, DINNER,
        NTOK / 256, (2 * DINNER / 256) * (NTOK / 256));

    // 2) conv + silu -> u (bf16)
    conv_silu<<<(int)(NBIG / 256), 256, 0, stream>>>(x_bf, conv_w, xact_bf);

    // 3) x_proj split-K=4 (grid 64*4=256 wgs) -> fp32 partials, then combine
    gemm_bf16<4><<<dim3(NTOK / 128, 2, 4), 256, 0, stream>>>(
        w_xp_bf, xact_bf, xpart, nullptr, nullptr, 256, DINNER / 4, DINNER, DINNER, 256);
    xp_combine<<<(NTOK * 160 + 255) / 256, 256, 0, stream>>>(xpart, dtr_bf, xbc);

    // 4) dt_proj (128^2, K=128) + softplus -> delta (bf16)
    gemm_bf16<2><<<dim3(NTOK / 128, DINNER / 128, 1), 256, 0, stream>>>(
        dtw_bf, dtr_bf, nullptr, delta_bf, dt_proj_b, DINNER, DTRANK, DTRANK, DTRANK, DINNER);

    // 5) chunked scan (PS/Hinit overwrite G — xpart dead after combine)
    scan_partial<<<dim3(DINNER / 256, NCHUNK, BATCH), 256, 0, stream>>>(
        delta_bf, xact_bf, xbc, A_log, PS);
    scan_combine<<<(BATCH * DINNER * 16) / 256, 256, 0, stream>>>(PS, Hinit);
    scan_final<<<dim3(DINNER / 256, NCHUNK, BATCH), 256, 0, stream>>>(
        delta_bf, xact_bf, xbc, Hinit, z_bf, y_bf, A_log, Dvec);

    // 6) out_proj: deterministic split-K=2 + addout. grid 256, no atomics.
    gemm8<3><<<(DMODEL / 256) * (NTOK / 256) * 2, 512, 0, stream>>>(
        w_out_bf, y_bf, out, nullptr, nullptr, Cpart, DINNER / 2, DINNER, DINNER, DMODEL,
        NTOK / 256, (DMODEL / 256) * (NTOK / 256));
    addout<<<(NTOK * DMODEL / 4 + 255) / 256, 256, 0, stream>>>(
        out, Cpart, NTOK * DMODEL / 4);
}

// Round 13
// 592.369 us; speedup vs baseline: 1.5352x; 1.0307x over previous
//
#include <hip/hip_runtime.h>
#include <hip/hip_bf16.h>
#include <math.h>

#define L_SEQ   2048
#define BATCH   2
#define DMODEL  2048
#define DINNER  4096
#define DSTATE  16
#define DTRANK  128
#define NTOK    (L_SEQ * BATCH)   // 4096
#define CHUNK   128
#define NCHUNK  (L_SEQ / CHUNK)   // 16

typedef __attribute__((ext_vector_type(8))) __bf16 bf16x8;
typedef __attribute__((ext_vector_type(4))) __bf16 bf16x4;
typedef __attribute__((ext_vector_type(4))) float f32x4;

__device__ __forceinline__ __bf16 f2bf(float f) {
    unsigned u = __builtin_bit_cast(unsigned, f);
    unsigned r = (u + 0x7FFFu + ((u >> 16) & 1u)) >> 16;
    return __builtin_bit_cast(__bf16, (unsigned short)r);
}

__device__ __forceinline__ void load_lds16(const void* gsrc, void* lds) {
    __builtin_amdgcn_global_load_lds(
        (const __attribute__((address_space(1))) unsigned int*)gsrc,
        (__attribute__((address_space(3))) unsigned int*)lds, 16, 0, 0);
}

// Stage one 128x64 bf16 half-tile (16 KiB) with 512 threads x 2 loads.
// LDS dest LINEAR; SOURCE column inverse-swizzled (rule 21: both-sides).
__device__ __forceinline__ void stage_half(const __bf16* g, int ld,
                                           __bf16* lh, int trow, int tcol8, int scol)
{
    load_lds16(g + (size_t)trow        * ld + scol, lh +  trow       * 64 + tcol8);
    load_lds16(g + (size_t)(trow + 64) * ld + scol, lh + (trow + 64) * 64 + tcol8);
}

// ---------------------------------------------------------------------------
// 256x256 bf16 MFMA GEMM, 4-phase + XCD-block swizzle + CORRECTED counted-
// vmcnt ladder.  R12 ERRATUM: A slots are WAVE-split (wave wm reads slot wm
// from p0 on), not phase-split -> {Ah0,Ah1,Bh0} must all land before p0;
// only Bh1 may lag to p1.  Corrected stage order (tile t stages t+1):
//   p0 -> Ah0' (slot 0), p1 -> Ah1' (slot 1), p2 -> Bh0' (slot 2),
//   p3 -> Bh1' (slot 3)
// Wait ladder (2 loads/stage; outstanding-set tracking, per wave):
//   prologue: issue Ah0,Ah1,Bh0,Bh1 (8); vmcnt(2) -> Ah0,Ah1,Bh0 land.
//   enter t.p0: outstanding {Bh1(t)}=2.
//   p0: +Ah0' (4) -> stg ? vmcnt(2) [Bh1(t) lands, Ah0' stays]
//                       : vmcnt(0)
//   p1: reads Bh1(t) ok; +Ah1' (4); no wait
//   p2: reads A rows 64-127 (landed pre-p0); +Bh0' (6); no wait
//   p3: +Bh1' (8) -> vmcnt(2): Ah0',Ah1',Bh0' land -> t+1.p0 ok. [steady]
// Never drains mid-loop.  Stage-write hazards: each slot's last reader is
// tile t-1, >=2 barriers before the overwriting stage.
// MODE 0: m<DINNER -> C0b bf16 (x); else C1b bf16 (z); ldc=DINNER   [in_proj]
// MODE 3: split-K deterministic: kslice0 -> C0, kslice1 -> Cpart    [out_proj]
// Requires NT >= 2 (all call sites: NT=32).
// ---------------------------------------------------------------------------
template <int MODE>
__global__ __launch_bounds__(512, 1)
void gemm8(const __bf16* __restrict__ A, const __bf16* __restrict__ Bt,
           float* __restrict__ C0, __bf16* __restrict__ C0b, __bf16* __restrict__ C1b,
           float* __restrict__ Cpart,
           int Kper, int lda, int ldb, int ldc, int nbn, int ntile)
{
    __shared__ __align__(16) __bf16 lds8[2 * 4 * 8192];   // 128 KiB

    const int t = threadIdx.x;
    // ---- XCD-block decomposition: block = 8m x 4n = 32 wgs on ONE XCD
    const int bid = (int)blockIdx.x;
    const int x   = bid & 7;
    const int k   = bid >> 3;
    const int b   = (k >> 5) * 8 + x;
    const int sub = k & 31;
    const int pslice = ntile >> 5;
    const int kslice = b / pslice;
    const int bp     = b - kslice * pslice;
    const int nblkn  = nbn >> 2;
    const int mb = bp / nblkn, nb = bp - mb * nblkn;
    const int m0 = (mb * 8 + (sub >> 2)) * 256;
    const int n0 = (nb * 4 + (sub & 3)) * 256;
    const int kofs = kslice * Kper;

    const int l      = t & 63;
    const int w      = t >> 6;
    const int wm     = w >> 2;
    const int wn     = w & 3;
    const int lane15 = l & 15;
    const int lhi    = l >> 4;
    const int trow   = t >> 3;
    const int tcol8  = (t & 7) * 8;
    const int scol   = tcol8 ^ ((trow & 7) << 3);

    const __bf16* Ah0 = A  + (size_t)m0 * lda + kofs;
    const __bf16* Ah1 = A  + (size_t)(m0 + 128) * lda + kofs;
    const __bf16* Bh0 = Bt + (size_t)n0 * ldb + kofs;
    const __bf16* Bh1 = Bt + (size_t)(n0 + 128) * ldb + kofs;

    const int NT = Kper >> 6;

    f32x4 acc[8][4];
#pragma unroll
    for (int i = 0; i < 8; ++i)
#pragma unroll
        for (int j = 0; j < 4; ++j) acc[i][j] = (f32x4){0.f, 0.f, 0.f, 0.f};

    // ---- prologue: all 4 halves of tile0; Bh1 may lag
    stage_half(Ah0, lda, lds8 + 0 * 8192, trow, tcol8, scol);
    stage_half(Ah1, lda, lds8 + 1 * 8192, trow, tcol8, scol);
    stage_half(Bh0, ldb, lds8 + 2 * 8192, trow, tcol8, scol);
    stage_half(Bh1, ldb, lds8 + 3 * 8192, trow, tcol8, scol);
    asm volatile("s_waitcnt vmcnt(2)" ::: "memory");   // Ah0,Ah1,Bh0 landed
    __builtin_amdgcn_s_barrier();
    asm volatile("" ::: "memory");

    for (int tt = 0; tt < NT; ++tt) {
        const int cur = tt & 1;
        const __bf16* LA  = lds8 + (cur * 4 + wm) * 8192;
        const __bf16* LB0 = lds8 + (cur * 4 + 2) * 8192;
        const __bf16* LB1 = lds8 + (cur * 4 + 3) * 8192;
        __bf16* nxt = lds8 + ((1 - cur) * 4) * 8192;
        const bool stg = (tt + 1 < NT);
        const int  knx = (tt + 1) << 6;

        bf16x8 aK0[4], aK1[4], b0K0[2], b0K1[2], b1K0[2], b1K1[2];

        // ---------- p0: read A rows 0-63 (own slot) + B-h0; stage Ah0'
#pragma unroll
        for (int i = 0; i < 4; ++i) {
            const int lr = i * 16 + lane15;
            const int sw = (lr & 7) << 3;
            aK0[i] = *(const bf16x8*)&LA[lr * 64 + ((lhi * 8) ^ sw)];
            aK1[i] = *(const bf16x8*)&LA[lr * 64 + ((32 + lhi * 8) ^ sw)];
        }
#pragma unroll
        for (int j = 0; j < 2; ++j) {
            const int lr = wn * 32 + j * 16 + lane15;
            const int sw = (lr & 7) << 3;
            b0K0[j] = *(const bf16x8*)&LB0[lr * 64 + ((lhi * 8) ^ sw)];
            b0K1[j] = *(const bf16x8*)&LB0[lr * 64 + ((32 + lhi * 8) ^ sw)];
        }
        if (stg) {
            stage_half(Ah0 + knx, lda, nxt + 0 * 8192, trow, tcol8, scol);
            asm volatile("s_waitcnt vmcnt(2)" ::: "memory");   // Bh1(t) lands
        } else {
            asm volatile("s_waitcnt vmcnt(0)" ::: "memory");
        }
        __builtin_amdgcn_s_barrier();
        asm volatile("" ::: "memory");
        __builtin_amdgcn_s_setprio(1);
#pragma unroll
        for (int i = 0; i < 4; ++i)
#pragma unroll
            for (int j = 0; j < 2; ++j) {
                acc[i][j] = __builtin_amdgcn_mfma_f32_16x16x32_bf16(
                    aK0[i], b0K0[j], acc[i][j], 0, 0, 0);
                acc[i][j] = __builtin_amdgcn_mfma_f32_16x16x32_bf16(
                    aK1[i], b0K1[j], acc[i][j], 0, 0, 0);
            }
        __builtin_amdgcn_s_setprio(0);

        // ---------- p1: read B-h1 (landed via p0 wait); stage Ah1'; no wait
#pragma unroll
        for (int j = 0; j < 2; ++j) {
            const int lr = wn * 32 + j * 16 + lane15;
            const int sw = (lr & 7) << 3;
            b1K0[j] = *(const bf16x8*)&LB1[lr * 64 + ((lhi * 8) ^ sw)];
            b1K1[j] = *(const bf16x8*)&LB1[lr * 64 + ((32 + lhi * 8) ^ sw)];
        }
        if (stg) stage_half(Ah1 + knx, lda, nxt + 1 * 8192, trow, tcol8, scol);
        __builtin_amdgcn_s_barrier();
        asm volatile("" ::: "memory");
        __builtin_amdgcn_s_setprio(1);
#pragma unroll
        for (int i = 0; i < 4; ++i)
#pragma unroll
            for (int j = 0; j < 2; ++j) {
                acc[i][2 + j] = __builtin_amdgcn_mfma_f32_16x16x32_bf16(
                    aK0[i], b1K0[j], acc[i][2 + j], 0, 0, 0);
                acc[i][2 + j] = __builtin_amdgcn_mfma_f32_16x16x32_bf16(
                    aK1[i], b1K1[j], acc[i][2 + j], 0, 0, 0);
            }
        __builtin_amdgcn_s_setprio(0);

        // ---------- p2: read A rows 64-127 (own slot, landed pre-p0); stage Bh0'
#pragma unroll
        for (int i = 0; i < 4; ++i) {
            const int lr = 64 + i * 16 + lane15;
            const int sw = (lr & 7) << 3;
            aK0[i] = *(const bf16x8*)&LA[lr * 64 + ((lhi * 8) ^ sw)];
            aK1[i] = *(const bf16x8*)&LA[lr * 64 + ((32 + lhi * 8) ^ sw)];
        }
        if (stg) stage_half(Bh0 + knx, ldb, nxt + 2 * 8192, trow, tcol8, scol);
        __builtin_amdgcn_s_barrier();
        asm volatile("" ::: "memory");
        __builtin_amdgcn_s_setprio(1);
#pragma unroll
        for (int i = 0; i < 4; ++i)
#pragma unroll
            for (int j = 0; j < 2; ++j) {
                acc[4 + i][j] = __builtin_amdgcn_mfma_f32_16x16x32_bf16(
                    aK0[i], b0K0[j], acc[4 + i][j], 0, 0, 0);
                acc[4 + i][j] = __builtin_amdgcn_mfma_f32_16x16x32_bf16(
                    aK1[i], b0K1[j], acc[4 + i][j], 0, 0, 0);
            }
        __builtin_amdgcn_s_setprio(0);

        // ---------- p3: stage Bh1'; vmcnt(2) lands Ah0',Ah1',Bh0' for t+1.p0
        if (stg) {
            stage_half(Bh1 + knx, ldb, nxt + 3 * 8192, trow, tcol8, scol);
            asm volatile("s_waitcnt vmcnt(2)" ::: "memory");
        }
        __builtin_amdgcn_s_barrier();
        asm volatile("" ::: "memory");
        __builtin_amdgcn_s_setprio(1);
#pragma unroll
        for (int i = 0; i < 4; ++i)
#pragma unroll
            for (int j = 0; j < 2; ++j) {
                acc[4 + i][2 + j] = __builtin_amdgcn_mfma_f32_16x16x32_bf16(
                    aK0[i], b1K0[j], acc[4 + i][2 + j], 0, 0, 0);
                acc[4 + i][2 + j] = __builtin_amdgcn_mfma_f32_16x16x32_bf16(
                    aK1[i], b1K1[j], acc[4 + i][2 + j], 0, 0, 0);
            }
        __builtin_amdgcn_s_setprio(0);
    }

    // ---- epilogue, vectorized: r-dim (4 consecutive m) per store
    const int rbase = lhi * 4;
    float* const dst = (MODE == 3) ? (kslice ? Cpart : C0) : C0;
#pragma unroll
    for (int fi = 0; fi < 8; ++fi) {
#pragma unroll
        for (int fj = 0; fj < 4; ++fj) {
            const int n = n0 + (fj >> 1) * 128 + wn * 32 + (fj & 1) * 16 + lane15;
            const int m = m0 + wm * 128 + fi * 16 + rbase;
            if constexpr (MODE == 0) {
                __align__(8) __bf16 ob[4];
#pragma unroll
                for (int r = 0; r < 4; ++r) ob[r] = f2bf(acc[fi][fj][r]);
                if (m < DINNER)
                    *(bf16x4*)&C0b[(size_t)n * DINNER + m] = *(const bf16x4*)ob;
                else
                    *(bf16x4*)&C1b[(size_t)n * DINNER + (m - DINNER)] = *(const bf16x4*)ob;
            } else {
                *(float4*)&dst[(size_t)n * ldc + m] = *(const float4*)&acc[fi][fj];
            }
        }
    }
}

// out += part  (split-K reduction, no atomics)
__global__ __launch_bounds__(256)
void addout(float* __restrict__ out, const float* __restrict__ part, int n4)
{
    const int i = blockIdx.x * 256 + threadIdx.x;
    if (i >= n4) return;
    float4 a = *(const float4*)&out[(size_t)i * 4];
    const float4 b = *(const float4*)&part[(size_t)i * 4];
    a.x += b.x; a.y += b.y; a.z += b.z; a.w += b.w;
    *(float4*)&out[(size_t)i * 4] = a;
}

// ---------------------------------------------------------------------------
// m97-style 128x128 bf16 MFMA GEMM (small GEMMs: x_proj, dt_proj).
// blockIdx.z selects a K-slice (kz = z*K); grids with gridDim.z==1 get kz=0.
// MODE 2: softplus(v + bias[m]) -> C1b bf16 [n*ldc+m]        [dt_proj]
// MODE 4: fp32 partial C0[z*NTOK*256 + n*256 + m]            [x_proj splitK]
// ---------------------------------------------------------------------------
template <int MODE>
__global__ __launch_bounds__(256)
void gemm_bf16(const __bf16* __restrict__ A, const __bf16* __restrict__ Bt,
               float* __restrict__ C0, __bf16* __restrict__ C1b,
               const float* __restrict__ bias,
               int Mvalid, int K, int lda, int ldb, int ldc)
{
    __shared__ __align__(16) __bf16 As[128 * 64];
    __shared__ __align__(16) __bf16 Bs[128 * 64];

    const int t  = threadIdx.x;
    const int m0 = blockIdx.y * 128;
    const int n0 = blockIdx.x * 128;
    const int kz = blockIdx.z * K;
    const int l  = t & 63;
    const int w  = t >> 6;
    const int wr = (w >> 1) * 64;
    const int wc = (w & 1) * 64;
    const int lrow = t >> 3;
    const int lk   = (t & 7) * 8;

    f32x4 acc[4][4];
#pragma unroll
    for (int i = 0; i < 4; ++i)
#pragma unroll
        for (int j = 0; j < 4; ++j) acc[i][j] = (f32x4){0.f, 0.f, 0.f, 0.f};

    for (int k0 = 0; k0 < K; k0 += 64) {
#pragma unroll
        for (int q = 0; q < 4; ++q) {
            const int row = q * 32 + lrow;
            load_lds16(A  + (size_t)(m0 + row) * lda + kz + k0 + lk, &As[row * 64 + lk]);
            load_lds16(Bt + (size_t)(n0 + row) * ldb + kz + k0 + lk, &Bs[row * 64 + lk]);
        }
        __syncthreads();

#pragma unroll
        for (int kk = 0; kk < 2; ++kk) {
            const int krd = kk * 32 + (l >> 4) * 8;
            bf16x8 a[4], bb[4];
#pragma unroll
            for (int i = 0; i < 4; ++i) {
                a[i]  = *(const bf16x8*)&As[(wr + i * 16 + (l & 15)) * 64 + krd];
                bb[i] = *(const bf16x8*)&Bs[(wc + i * 16 + (l & 15)) * 64 + krd];
            }
#pragma unroll
            for (int i = 0; i < 4; ++i)
#pragma unroll
                for (int j = 0; j < 4; ++j)
                    acc[i][j] = __builtin_amdgcn_mfma_f32_16x16x32_bf16(
                        a[i], bb[j], acc[i][j], 0, 0, 0);
        }
        __syncthreads();
    }

    const int rbase = (l >> 4) * 4;
    const int cbase = l & 15;
    float* const C0z = (MODE == 4) ? C0 + (size_t)blockIdx.z * NTOK * 256 : C0;
#pragma unroll
    for (int i = 0; i < 4; ++i) {
#pragma unroll
        for (int j = 0; j < 4; ++j) {
#pragma unroll
            for (int r = 0; r < 4; ++r) {
                const int m = m0 + wr + i * 16 + rbase + r;
                const int n = n0 + wc + j * 16 + cbase;
                const float v = acc[i][j][r];
                if constexpr (MODE == 2) {
                    const float vb = v + bias[m];
                    const float sp = (vb > 20.f) ? vb : log1pf(__expf(vb));
                    C1b[(size_t)n * ldc + m] = f2bf(sp);
                } else {   // MODE 4
                    C0z[(size_t)n * 256 + m] = v;
                }
            }
        }
    }
}

// x_proj split-K combine: sum 4 fp32 partials -> dtr_bf (m<128) | xbc (128..159)
__global__ __launch_bounds__(256)
void xp_combine(const float* __restrict__ xpart, __bf16* __restrict__ dtr_bf,
                float* __restrict__ xbc)
{
    const int i = blockIdx.x * 256 + threadIdx.x;
    if (i >= NTOK * 160) return;
    const int n = i / 160;
    const int m = i - n * 160;
    const size_t stride = (size_t)NTOK * 256;
    const size_t base = (size_t)n * 256 + m;
    float s = xpart[base] + xpart[stride + base]
            + xpart[2 * stride + base] + xpart[3 * stride + base];
    if (m < 128) dtr_bf[(size_t)n * 128 + m] = f2bf(s);
    else         xbc[(size_t)n * 32 + (m - 128)] = s;
}

// ---------------------------------------------------------------------------
// Fused fp32->bf16 conversions for all 5 buffers (one launch).
// ---------------------------------------------------------------------------
#define CS0 (NTOK * DMODEL / 8)        // hidden      1048576
#define CS1 (2 * DINNER * DMODEL / 8)  // in_proj_w   2097152
#define CS2 (DMODEL * DINNER / 8)      // out_proj_w  1048576
#define CS3 (DINNER * DTRANK / 8)      // dt_proj_w     65536
#define CS4 (256 * DINNER / 8)         // x_proj pad   131072
#define CTOT (CS0 + CS1 + CS2 + CS3 + CS4)

__global__ __launch_bounds__(256)
void cvt_all(const float* __restrict__ hidden, const float* __restrict__ w_in,
             const float* __restrict__ w_out, const float* __restrict__ w_dt,
             const float* __restrict__ w_xp,
             __bf16* __restrict__ hid_bf, __bf16* __restrict__ w_in_bf,
             __bf16* __restrict__ w_out_bf, __bf16* __restrict__ dtw_bf,
             __bf16* __restrict__ w_xp_bf)
{
    const int i = blockIdx.x * 256 + threadIdx.x;
    const float* src; __bf16* dst; int off;
    if (i < CS0)                    { src = hidden; dst = hid_bf;  off = i; }
    else if (i < CS0 + CS1)         { src = w_in;   dst = w_in_bf; off = i - CS0; }
    else if (i < CS0 + CS1 + CS2)   { src = w_out;  dst = w_out_bf; off = i - (CS0 + CS1); }
    else if (i < CS0 + CS1 + CS2 + CS3) { src = w_dt; dst = dtw_bf; off = i - (CS0 + CS1 + CS2); }
    else {
        off = i - (CS0 + CS1 + CS2 + CS3);
        const int row = off >> 9;
        __align__(16) __bf16 o[8];
        if (row < 160) {
            const size_t base = (size_t)off * 8;
            const float4 a = *(const float4*)&w_xp[base];
            const float4 b = *(const float4*)&w_xp[base + 4];
            o[0] = f2bf(a.x); o[1] = f2bf(a.y); o[2] = f2bf(a.z); o[3] = f2bf(a.w);
            o[4] = f2bf(b.x); o[5] = f2bf(b.y); o[6] = f2bf(b.z); o[7] = f2bf(b.w);
        } else {
#pragma unroll
            for (int kk = 0; kk < 8; ++kk) o[kk] = f2bf(0.f);
        }
        *(bf16x8*)&w_xp_bf[(size_t)off * 8] = *(const bf16x8*)o;
        return;
    }
    const size_t base = (size_t)off * 8;
    const float4 a = *(const float4*)&src[base];
    const float4 b = *(const float4*)&src[base + 4];
    __align__(16) __bf16 o[8];
    o[0] = f2bf(a.x); o[1] = f2bf(a.y); o[2] = f2bf(a.z); o[3] = f2bf(a.w);
    o[4] = f2bf(b.x); o[5] = f2bf(b.y); o[6] = f2bf(b.z); o[7] = f2bf(b.w);
    *(bf16x8*)&dst[base] = *(const bf16x8*)o;
}

// ---------------------------------------------------------------------------
// Causal conv (width 4) + SiLU — VECTORIZED: 8 elems/thread (bf16x8).
// All taps are at e-aligned offsets (idx - k*2*DINNER) -> same vector lanes.
// ---------------------------------------------------------------------------
__global__ __launch_bounds__(256)
void conv_silu(const __bf16* __restrict__ x, const float* __restrict__ conv_w,
               __bf16* __restrict__ xact_bf)
{
    const size_t i8 = ((size_t)blockIdx.x * 256 + threadIdx.x) * 8;
    const int e0 = (int)(i8 & (DINNER - 1));
    const int n  = (int)(i8 >> 12);

    bf16x8 zer;
#pragma unroll
    for (int kk = 0; kk < 8; ++kk) zer[kk] = (__bf16)0.f;

    const bf16x8 x3 = *(const bf16x8*)&x[i8];
    const bf16x8 x2 = (n >= 2) ? *(const bf16x8*)&x[i8 - (size_t)2 * DINNER] : zer;
    const bf16x8 x1 = (n >= 4) ? *(const bf16x8*)&x[i8 - (size_t)4 * DINNER] : zer;
    const bf16x8 x0 = (n >= 6) ? *(const bf16x8*)&x[i8 - (size_t)6 * DINNER] : zer;

    __align__(16) __bf16 o[8];
#pragma unroll
    for (int kk = 0; kk < 8; ++kk) {
        const float4 wv = *(const float4*)&conv_w[(e0 + kk) * 4];
        float s = wv.w * (float)x3[kk] + wv.z * (float)x2[kk]
                + wv.y * (float)x1[kk] + wv.x * (float)x0[kk];
        o[kk] = f2bf(s / (1.f + __expf(-s)));
    }
    *(bf16x8*)&xact_bf[i8] = *(const bf16x8*)o;
}

// ---------------------------------------------------------------------------
// Chunked selective scan (delta bf16).
// ---------------------------------------------------------------------------
__global__ __launch_bounds__(256)
void scan_partial(const __bf16* __restrict__ delta, const __bf16* __restrict__ u,
                  const float* __restrict__ xbc, const float* __restrict__ A_log,
                  float2* __restrict__ PS)
{
    const int e     = blockIdx.x * 256 + threadIdx.x;
    const int chunk = blockIdx.y;
    const int b     = blockIdx.z;

    __shared__ float BC[CHUNK][32];
    for (int i = threadIdx.x; i < CHUNK * 32; i += 256) {
        const int ll = i >> 5, f = i & 31;
        BC[ll][f] = xbc[(size_t)((chunk * CHUNK + ll) * BATCH + b) * 32 + f];
    }

    float Av[16];
#pragma unroll
    for (int s = 0; s < 16; s += 4) {
        float4 tv = *(const float4*)&A_log[e * 16 + s];
        Av[s] = -__expf(tv.x); Av[s + 1] = -__expf(tv.y);
        Av[s + 2] = -__expf(tv.z); Av[s + 3] = -__expf(tv.w);
    }
    __syncthreads();

    float P[16], S[16];
#pragma unroll
    for (int s = 0; s < 16; ++s) { P[s] = 1.f; S[s] = 0.f; }

#pragma unroll 4
    for (int ll = 0; ll < CHUNK; ++ll) {
        const int tok = (chunk * CHUNK + ll) * BATCH + b;
        const size_t ce = (size_t)tok * DINNER + e;
        const float dl = (float)delta[ce];
        const float du = dl * (float)u[ce];
#pragma unroll
        for (int s = 0; s < 16; ++s) {
            const float dA = __expf(dl * Av[s]);
            S[s] = fmaf(dA, S[s], du * BC[ll][s]);
            P[s] *= dA;
        }
    }

    float2* outp = PS + ((size_t)(chunk * BATCH + b) * DINNER + e) * 16;
#pragma unroll
    for (int s = 0; s < 16; ++s) outp[s] = make_float2(P[s], S[s]);
}

__global__ __launch_bounds__(256)
void scan_combine(const float2* __restrict__ PS, float* __restrict__ Hinit)
{
    const size_t pos = (size_t)blockIdx.x * 256 + threadIdx.x;
    const size_t stride = (size_t)BATCH * DINNER * 16;
    float h = 0.f;
#pragma unroll
    for (int c = 0; c < NCHUNK; ++c) {
        Hinit[c * stride + pos] = h;
        const float2 ps = PS[c * stride + pos];
        h = fmaf(ps.x, h, ps.y);
    }
}

__global__ __launch_bounds__(256)
void scan_final(const __bf16* __restrict__ delta, const __bf16* __restrict__ u,
                const float* __restrict__ xbc, const float* __restrict__ Hinit,
                const __bf16* __restrict__ z_bf, __bf16* __restrict__ y_bf,
                const float* __restrict__ A_log, const float* __restrict__ Dvec)
{
    const int e     = blockIdx.x * 256 + threadIdx.x;
    const int chunk = blockIdx.y;
    const int b     = blockIdx.z;

    __shared__ float BC[CHUNK][32];
    for (int i = threadIdx.x; i < CHUNK * 32; i += 256) {
        const int ll = i >> 5, f = i & 31;
        BC[ll][f] = xbc[(size_t)((chunk * CHUNK + ll) * BATCH + b) * 32 + f];
    }

    float Av[16];
#pragma unroll
    for (int s = 0; s < 16; s += 4) {
        float4 tv = *(const float4*)&A_log[e * 16 + s];
        Av[s] = -__expf(tv.x); Av[s + 1] = -__expf(tv.y);
        Av[s + 2] = -__expf(tv.z); Av[s + 3] = -__expf(tv.w);
    }
    const float Dv = Dvec[e];

    float h[16];
    const float* hi = Hinit + (size_t)chunk * BATCH * DINNER * 16
                            + ((size_t)b * DINNER + e) * 16;
#pragma unroll
    for (int s = 0; s < 16; s += 4) *(float4*)&h[s] = *(const float4*)&hi[s];
    __syncthreads();

#pragma unroll 2
    for (int ll = 0; ll < CHUNK; ++ll) {
        const int tok = (chunk * CHUNK + ll) * BATCH + b;
        const size_t ce = (size_t)tok * DINNER + e;
        const float dl = (float)delta[ce];
        const float ul = (float)u[ce];
        const float du = dl * ul;
        float y = 0.f;
#pragma unroll
        for (int s = 0; s < 16; ++s) {
            const float dA = __expf(dl * Av[s]);
            h[s] = fmaf(dA, h[s], du * BC[ll][s]);
            y = fmaf(h[s], BC[ll][16 + s], y);
        }
        const float zl = (float)z_bf[ce];
        const float sig = 1.f / (1.f + __expf(-zl));
        y_bf[ce] = f2bf((y + ul * Dv) * (zl * sig));
    }
}

// ---------------------------------------------------------------------------
extern "C" void kernel_launch(void* const* d_in, const int* in_sizes, int n_in,
                              void* d_out, int out_size, void* d_ws, size_t ws_size,
                              hipStream_t stream)
{
    const float* hidden    = (const float*)d_in[0];
    const float* in_proj_w = (const float*)d_in[1];
    const float* conv_w    = (const float*)d_in[2];
    const float* x_proj_w  = (const float*)d_in[3];
    const float* dt_proj_w = (const float*)d_in[4];
    const float* dt_proj_b = (const float*)d_in[5];
    const float* A_log     = (const float*)d_in[6];
    const float* Dvec      = (const float*)d_in[7];
    const float* out_proj_w= (const float*)d_in[8];
    float* out = (float*)d_out;

    // -------- workspace (same region sizes/totals as R10/R11 passing runs)
    char* p = (char*)d_ws;
    const size_t NBIG = (size_t)NTOK * DINNER;
    __bf16* x_bf    = (__bf16*)p;   p += NBIG * 2;                        // x (bf16)
    __bf16* delta_bf= (__bf16*)p;   p += NBIG * 2;                        // delta (bf16)
    __bf16* z_bf    = (__bf16*)p;   p += NBIG * 2;                        // z
    __bf16* xact_bf = (__bf16*)p;   p += NBIG * 2;                        // u
    __bf16* dtr_bf  = (__bf16*)p;   p += (size_t)NTOK * 128 * 2;         // dt_r (bf16)
    float*  xbc     = (float*)p;    p += (size_t)NTOK * 32 * 4;          // B|C (fp32)
    __bf16* w_xp_bf = (__bf16*)p;   p += (size_t)256 * DINNER * 2;
    __bf16* w_out_bf= (__bf16*)p;   p += (size_t)DMODEL * DINNER * 2;
    char*   G       = p;            p += (size_t)2 * DINNER * DMODEL * 2; // 33.5 MB, multi-use
    __bf16* hid_bf  = (__bf16*)p;   p += (size_t)NTOK * DMODEL * 2;
    __bf16* y_bf    = (__bf16*)p;   p += NBIG * 2;
    __bf16* dtw_bf  = (__bf16*)p;   p += (size_t)DINNER * DTRANK * 2;
    const size_t required = (size_t)(p - (char*)d_ws);
    if (ws_size < required) return;

    // G lifetime: w_in_bf (0-1) -> xpart (3) -> PS+Hinit (5) -> Cpart (6)
    __bf16* w_in_bf = (__bf16*)G;
    float*  xpart   = (float*)G;                                         // 16.8 MB
    float2* PS      = (float2*)G;
    float*  Hinit   = (float*)(G + (size_t)NCHUNK * BATCH * DINNER * 16 * 8);
    float*  Cpart   = (float*)G;

    // 0) fused conversions
    cvt_all<<<CTOT / 256, 256, 0, stream>>>(
        hidden, in_proj_w, out_proj_w, dt_proj_w, x_proj_w,
        hid_bf, w_in_bf, w_out_bf, dtw_bf, w_xp_bf);

    // 1) in_proj (256^2, XCD-block + corrected counted-vmcnt): x | z. grid 512
    gemm8<0><<<(2 * DINNER / 256) * (NTOK / 256), 512, 0, stream>>>(
        w_in_bf, hid_bf, nullptr, x_bf, z_bf, nullptr, DMODEL, DMODEL, DMODEL, DINNER,
        NTOK / 256, (2 * DINNER / 256) * (NTOK / 256));

    // 2) conv + silu -> u (bf16), vectorized x8
    conv_silu<<<(int)(NBIG / 2048), 256, 0, stream>>>(x_bf, conv_w, xact_bf);

    // 3) x_proj split-K=4 (grid 64*4=256 wgs) -> fp32 partials, then combine
    gemm_bf16<4><<<dim3(NTOK / 128, 2, 4), 256, 0, stream>>>(
        w_xp_bf, xact_bf, xpart, nullptr, nullptr, 256, DINNER / 4, DINNER, DINNER, 256);
    xp_combine<<<(NTOK * 160 + 255) / 256, 256, 0, stream>>>(xpart, dtr_bf, xbc);

    // 4) dt_proj (128^2, K=128) + softplus -> delta (bf16)
    gemm_bf16<2><<<dim3(NTOK / 128, DINNER / 128, 1), 256, 0, stream>>>(
        dtw_bf, dtr_bf, nullptr, delta_bf, dt_proj_b, DINNER, DTRANK, DTRANK, DTRANK, DINNER);

    // 5) chunked scan (PS/Hinit overwrite G — xpart dead after combine)
    scan_partial<<<dim3(DINNER / 256, NCHUNK, BATCH), 256, 0, stream>>>(
        delta_bf, xact_bf, xbc, A_log, PS);
    scan_combine<<<(BATCH * DINNER * 16) / 256, 256, 0, stream>>>(PS, Hinit);
    scan_final<<<dim3(DINNER / 256, NCHUNK, BATCH), 256, 0, stream>>>(
        delta_bf, xact_bf, xbc, Hinit, z_bf, y_bf, A_log, Dvec);

    // 6) out_proj: deterministic split-K=2 + addout. grid 256, no atomics.
    gemm8<3><<<(DMODEL / 256) * (NTOK / 256) * 2, 512, 0, stream>>>(
        w_out_bf, y_bf, out, nullptr, nullptr, Cpart, DINNER / 2, DINNER, DINNER, DMODEL,
        NTOK / 256, (DMODEL / 256) * (NTOK / 256));
    addout<<<(NTOK * DMODEL / 4 + 255) / 256, 256, 0, stream>>>(
        out, Cpart, NTOK * DMODEL / 4);
}